// Round 2
// baseline (14090.808 us; speedup 1.0000x reference)
//
#include <hip/hip_runtime.h>

#define DIMC 2240
#define STOK 3584
#define ENCT 300
#define NH   20
#define HDIM 112
#define HID1 6720
#define HID2 13440
#define DD   (2240*2240)
#define SD   (3584*2240)

typedef short bf16x8 __attribute__((ext_vector_type(8)));   // guide-verified operand type
typedef float f32x4  __attribute__((ext_vector_type(4)));

__device__ __forceinline__ unsigned short f2bf(float f){
  unsigned int u = __float_as_uint(f);
  u += 0x7fffu + ((u >> 16) & 1u);          // RNE
  return (unsigned short)(u >> 16);
}
__device__ __forceinline__ float bf2f(unsigned short h){
  return __uint_as_float(((unsigned int)h) << 16);
}

// ---------------- fp32 -> bf16 convert (flat) ----------------
__global__ void cvt_k(const float4* __restrict__ src, ushort4* __restrict__ dst, int n4){
  int i = blockIdx.x*256 + threadIdx.x;
  if (i < n4){
    float4 v = src[i];
    ushort4 o; o.x = f2bf(v.x); o.y = f2bf(v.y); o.z = f2bf(v.z); o.w = f2bf(v.w);
    dst[i] = o;
  }
}
// ---------------- fp32 -> bf16 convert (column slice, packed dst) ----------------
__global__ void cvt_cols_k(const float* __restrict__ src, unsigned short* __restrict__ dst,
                           int rows, int ldsrc, int c0, int nc){
  int nc4 = nc >> 2;
  int i = blockIdx.x*256 + threadIdx.x;
  if (i >= rows*nc4) return;
  int r = i / nc4, c4 = i % nc4;
  float4 v = *reinterpret_cast<const float4*>(src + (size_t)r*ldsrc + c0 + c4*4);
  ushort4 o; o.x = f2bf(v.x); o.y = f2bf(v.y); o.z = f2bf(v.z); o.w = f2bf(v.w);
  *reinterpret_cast<ushort4*>(dst + (size_t)r*nc + c4*4) = o;
}

// ---------------- mods = scale_shift_table + timestep ----------------
__global__ void mods_k(const float* __restrict__ sst, const float* __restrict__ ts, float* __restrict__ mods){
  int i = blockIdx.x*256 + threadIdx.x;
  if (i < 6*DIMC) mods[i] = sst[i] + ts[i];
}

// ---------------- LayerNorm * (1+sc) + sh -> bf16 ----------------
__global__ __launch_bounds__(256) void ln_mod_k(const float* __restrict__ x,
    const float* __restrict__ mods, int shj, int scj, unsigned short* __restrict__ out)
{
  const int s = blockIdx.x;
  const float* row = x + (size_t)s*DIMC;
  const float* sh = mods + shj*DIMC;
  const float* sc = mods + scj*DIMC;
  float sum = 0.f, sq = 0.f;
  for (int d = threadIdx.x; d < DIMC; d += 256){ float v = row[d]; sum += v; sq += v*v; }
  #pragma unroll
  for (int o = 32; o; o >>= 1){ sum += __shfl_down(sum, o); sq += __shfl_down(sq, o); }
  __shared__ float sA[4], sB[4];
  int w = threadIdx.x >> 6, l = threadIdx.x & 63;
  if (!l){ sA[w] = sum; sB[w] = sq; }
  __syncthreads();
  sum = sA[0]+sA[1]+sA[2]+sA[3];
  sq  = sB[0]+sB[1]+sB[2]+sB[3];
  float mean = sum * (1.f/DIMC);
  float rs = rsqrtf(sq*(1.f/DIMC) - mean*mean + 1e-6f);
  unsigned short* orow = out + (size_t)s*DIMC;
  for (int d = threadIdx.x; d < DIMC; d += 256){
    float v = (row[d]-mean)*rs*(1.f + sc[d]) + sh[d];
    orow[d] = f2bf(v);
  }
}

// ---------------- RMS on bf16 rows (optional ReLU / RoPE) ----------------
template<int RELU, int ROPE>
__global__ __launch_bounds__(256) void rms_bf_k(unsigned short* __restrict__ x, const float* __restrict__ nw,
    const float* __restrict__ cosb, const float* __restrict__ sinb, unsigned short* __restrict__ xr)
{
  const int s = blockIdx.x;
  unsigned short* row = x + (size_t)s*DIMC;
  float sq = 0.f;
  for (int d = threadIdx.x; d < DIMC; d += 256){ float v = bf2f(row[d]); sq += v*v; }
  #pragma unroll
  for (int o = 32; o; o >>= 1) sq += __shfl_down(sq, o);
  __shared__ float sB[4];
  int w = threadIdx.x >> 6, l = threadIdx.x & 63;
  if (!l) sB[w] = sq;
  __syncthreads();
  sq = sB[0]+sB[1]+sB[2]+sB[3];
  float rs = rsqrtf(sq*(1.f/DIMC) + 1e-5f);
  if constexpr (!ROPE){
    for (int d = threadIdx.x; d < DIMC; d += 256){
      float v = bf2f(row[d])*rs*nw[d];
      if (RELU) v = fmaxf(v, 0.f);
      row[d] = f2bf(v);
    }
  } else {
    for (int p = threadIdx.x; p < DIMC/2; p += 256){
      int d0 = 2*p, d1 = d0+1;
      float v0 = bf2f(row[d0])*rs*nw[d0];
      float v1 = bf2f(row[d1])*rs*nw[d1];
      if (RELU){ v0 = fmaxf(v0,0.f); v1 = fmaxf(v1,0.f); }
      row[d0] = f2bf(v0); row[d1] = f2bf(v1);
      int j0 = d0 % HDIM;                       // pairs stay within a head (112 even)
      float c  = cosb[(size_t)s*HDIM + j0];     // cos[0::2]
      float sn = sinb[(size_t)s*HDIM + j0 + 1]; // sin[1::2]
      xr[(size_t)s*DIMC + d0] = f2bf(v0*c - v1*sn);
      xr[(size_t)s*DIMC + d1] = f2bf(v0*sn + v1*c);
    }
  }
}
// ---------------- RMS on fp32 rows (in place, no relu/rope) ----------------
__global__ __launch_bounds__(256) void rms_f32_k(float* __restrict__ x, const float* __restrict__ nw)
{
  const int s = blockIdx.x;
  float* row = x + (size_t)s*DIMC;
  float sq = 0.f;
  for (int d = threadIdx.x; d < DIMC; d += 256){ float v = row[d]; sq += v*v; }
  #pragma unroll
  for (int o = 32; o; o >>= 1) sq += __shfl_down(sq, o);
  __shared__ float sB[4];
  int w = threadIdx.x >> 6, l = threadIdx.x & 63;
  if (!l) sB[w] = sq;
  __syncthreads();
  sq = sB[0]+sB[1]+sB[2]+sB[3];
  float rs = rsqrtf(sq*(1.f/DIMC) + 1e-5f);
  for (int d = threadIdx.x; d < DIMC; d += 256) row[d] = row[d]*rs*nw[d];
}

// ---------------- generic bf16 MFMA GEMM: C = A(MxK) @ B(KxN), C has leading dim ldc ---
// EPI: 0 Cf=acc+bias | 1 Cb=bf16(silu(acc+bias)) | 2 Cb=bf16(acc+bias)
//      3 u=res+gate*(acc+bias); Cf=u; Cb=bf16(u) | 4 Cf=res+acc+bias | 5 Cf+=acc
template<int EPI>
__global__ __launch_bounds__(256) void gemm_k(
  const unsigned short* __restrict__ A, const unsigned short* __restrict__ B,
  const float* __restrict__ bias, float* __restrict__ Cf, unsigned short* __restrict__ Cb,
  const float* __restrict__ res, const float* __restrict__ gate,
  int M, int N, int K, int ldc)
{
  __shared__ __align__(16) unsigned short Al[128][40];  // +8 pad breaks bank conflicts
  __shared__ __align__(16) unsigned short Bl[128][40];  // stored transposed: [n][k]
  const int m0 = blockIdx.y*128, n0 = blockIdx.x*128;
  const int t = threadIdx.x;
  const int l = t & 63, w = t >> 6;
  const int wr = w >> 1, wc = w & 1;
  const int l16 = l & 15, lk = l >> 4;
  f32x4 acc[4][4] = {};

  for (int k0 = 0; k0 < K; k0 += 32){
    __syncthreads();
    #pragma unroll
    for (int i = 0; i < 2; ++i){            // A tile 128x32
      int li = i*256 + t;
      int r = li >> 2, c8 = (li & 3) << 3;
      uint4 val = make_uint4(0u,0u,0u,0u);
      if (m0 + r < M)
        val = *reinterpret_cast<const uint4*>(A + (size_t)(m0+r)*K + k0 + c8);
      *reinterpret_cast<uint4*>(&Al[r][c8]) = val;
    }
    #pragma unroll
    for (int i = 0; i < 2; ++i){            // B tile 32x128, transpose into LDS
      int li = i*256 + t;
      int kr = li >> 4, c8 = (li & 15) << 3;
      uint4 val = make_uint4(0u,0u,0u,0u);
      if (n0 + c8 < N)                      // N % 8 == 0 for all our shapes
        val = *reinterpret_cast<const uint4*>(B + (size_t)(k0+kr)*N + n0 + c8);
      unsigned int uu[4] = {val.x, val.y, val.z, val.w};
      #pragma unroll
      for (int j = 0; j < 4; ++j){
        Bl[c8 + 2*j    ][kr] = (unsigned short)(uu[j] & 0xffffu);
        Bl[c8 + 2*j + 1][kr] = (unsigned short)(uu[j] >> 16);
      }
    }
    __syncthreads();
    bf16x8 af[4], bfr[4];
    #pragma unroll
    for (int m = 0; m < 4; ++m)
      af[m] = *reinterpret_cast<const bf16x8*>(&Al[wr*64 + m*16 + l16][lk*8]);
    #pragma unroll
    for (int n = 0; n < 4; ++n)
      bfr[n] = *reinterpret_cast<const bf16x8*>(&Bl[wc*64 + n*16 + l16][lk*8]);
    #pragma unroll
    for (int m = 0; m < 4; ++m)
      #pragma unroll
      for (int n = 0; n < 4; ++n)
        acc[m][n] = __builtin_amdgcn_mfma_f32_16x16x32_bf16(af[m], bfr[n], acc[m][n], 0, 0, 0);
  }

  const int rb = m0 + wr*64 + lk*4;   // C/D: col = lane&15, row = (lane>>4)*4 + reg
  const int cb = n0 + wc*64 + l16;
  #pragma unroll
  for (int m = 0; m < 4; ++m){
    #pragma unroll
    for (int r = 0; r < 4; ++r){
      int row = rb + m*16 + r;
      if (row >= M) continue;
      #pragma unroll
      for (int n = 0; n < 4; ++n){
        int col = cb + n*16;
        if (col >= N) continue;
        float v = acc[m][n][r];
        size_t idx = (size_t)row*ldc + col;
        float bv = bias ? bias[col] : 0.f;
        if constexpr (EPI == 0){ Cf[idx] = v + bv; }
        else if constexpr (EPI == 1){ float u = v + bv; Cb[idx] = f2bf(u / (1.f + __expf(-u))); }
        else if constexpr (EPI == 2){ Cb[idx] = f2bf(v + bv); }
        else if constexpr (EPI == 3){ float u = res[idx] + gate[col]*(v + bv); Cf[idx] = u; Cb[idx] = f2bf(u); }
        else if constexpr (EPI == 4){ Cf[idx] = res[idx] + v + bv; }
        else { Cf[idx] += v; }
      }
    }
  }
}

// ---------------- linear attention helpers ----------------
// deterministic ksum: per-chunk partial colsum, then reduce
__global__ void colsum_k(const unsigned short* __restrict__ k, float* __restrict__ kpart){
  int d = blockIdx.x*256 + threadIdx.x;
  if (d >= DIMC) return;
  int ch = blockIdx.y, s0 = ch*128;
  float acc = 0.f;
  for (int s = s0; s < s0+128; ++s) acc += bf2f(k[(size_t)s*DIMC + d]);
  kpart[(size_t)ch*DIMC + d] = acc;
}
__global__ void ksumred_k(const float* __restrict__ kpart, float* __restrict__ ksum){
  int d = blockIdx.x*256 + threadIdx.x;
  if (d >= DIMC) return;
  float a = 0.f;
  for (int c = 0; c < 28; ++c) a += kpart[(size_t)c*DIMC + d];
  ksum[d] = a;
}
__global__ __launch_bounds__(256) void denom_k(const unsigned short* __restrict__ q,
    const float* __restrict__ ksum, float* __restrict__ denom)
{
  int s = blockIdx.x; int w = threadIdx.x >> 6, l = threadIdx.x & 63;
  for (int h = w; h < NH; h += 4){
    const unsigned short* qb = q + (size_t)s*DIMC + h*HDIM;
    const float* kb = ksum + h*HDIM;
    float v = bf2f(qb[l])*kb[l];
    if (l < 48) v += bf2f(qb[64+l])*kb[64+l];
    #pragma unroll
    for (int o = 32; o; o >>= 1) v += __shfl_down(v, o);
    if (!l) denom[s*NH + h] = v + 1e-15f;
  }
}
// scores_part[ch][h][e][d] = sum_{s in chunk} v[s,h,e]*kr[s,h,d]
__global__ __launch_bounds__(256) void scores_k(const unsigned short* __restrict__ v,
    const unsigned short* __restrict__ kr, float* __restrict__ part)
{
  const int h = blockIdx.x, ch = blockIdx.y;
  __shared__ float vl[8][113], kl[8][113];
  const int te = threadIdx.x >> 4, td = threadIdx.x & 15;
  float acc[7][7] = {};
  const int sbase = ch*448;
  for (int so = 0; so < 448; so += 8){
    __syncthreads();
    for (int li = threadIdx.x; li < 1792; li += 256){
      int si = li/224, r = li%224;
      if (r < HDIM) vl[si][r]      = bf2f(v [(size_t)(sbase+so+si)*DIMC + h*HDIM + r]);
      else          kl[si][r-HDIM] = bf2f(kr[(size_t)(sbase+so+si)*DIMC + h*HDIM + (r-HDIM)]);
    }
    __syncthreads();
    #pragma unroll
    for (int si = 0; si < 8; ++si){
      float vv[7], kk[7];
      #pragma unroll
      for (int a = 0; a < 7; ++a) vv[a] = vl[si][te*7+a];
      #pragma unroll
      for (int b = 0; b < 7; ++b) kk[b] = kl[si][td*7+b];
      #pragma unroll
      for (int a = 0; a < 7; ++a)
        #pragma unroll
        for (int b = 0; b < 7; ++b) acc[a][b] += vv[a]*kk[b];
    }
  }
  #pragma unroll
  for (int a = 0; a < 7; ++a)
    #pragma unroll
    for (int b = 0; b < 7; ++b)
      part[((size_t)(ch*NH + h)*HDIM + te*7+a)*HDIM + td*7+b] = acc[a][b];
}
__global__ void scred_k(const float* __restrict__ part, unsigned short* __restrict__ sc){
  int i = blockIdx.x*256 + threadIdx.x;
  if (i >= NH*HDIM*HDIM) return;
  float a = 0.f;
  #pragma unroll
  for (int c = 0; c < 8; ++c) a += part[(size_t)c*(NH*HDIM*HDIM) + i];
  sc[i] = f2bf(a);
}
// out[s, h*112+e] = (sum_d scores[h,e,d]*qr[s,h,d]) / denom[s,h]  -> bf16
__global__ __launch_bounds__(256) void linout_k(const unsigned short* __restrict__ qr,
    const unsigned short* __restrict__ scores, const float* __restrict__ denom,
    unsigned short* __restrict__ out)
{
  const int s0 = blockIdx.x*64, h = blockIdx.y;
  __shared__ unsigned short sc[112][120];
  __shared__ unsigned short qt[64][120];
  for (int li = threadIdx.x; li < 12544; li += 256)
    sc[li/112][li%112] = scores[(size_t)h*12544 + li];
  for (int li = threadIdx.x; li < 7168; li += 256)
    qt[li/112][li%112] = qr[(size_t)(s0 + li/112)*DIMC + h*HDIM + li%112];
  __syncthreads();
  const int ts = threadIdx.x >> 4, te = threadIdx.x & 15;
  float acc[4][7] = {};
  for (int d = 0; d < HDIM; ++d){
    float qv[4], sv[7];
    #pragma unroll
    for (int a = 0; a < 4; ++a) qv[a] = bf2f(qt[ts*4+a][d]);
    #pragma unroll
    for (int b = 0; b < 7; ++b) sv[b] = bf2f(sc[te*7+b][d]);
    #pragma unroll
    for (int a = 0; a < 4; ++a)
      #pragma unroll
      for (int b = 0; b < 7; ++b) acc[a][b] += qv[a]*sv[b];
  }
  #pragma unroll
  for (int a = 0; a < 4; ++a){
    int sl = s0 + ts*4 + a;
    float dn = 1.f / denom[(size_t)sl*NH + h];
    #pragma unroll
    for (int b = 0; b < 7; ++b)
      out[(size_t)sl*DIMC + h*HDIM + te*7+b] = f2bf(acc[a][b]*dn);
  }
}

// ---------------- fused cross-attention (300 keys) ----------------
__global__ __launch_bounds__(256) void cross_k(const unsigned short* __restrict__ q,
    const float* __restrict__ k2, const float* __restrict__ v2, unsigned short* __restrict__ out)
{
  const int s0 = blockIdx.x*16, h = blockIdx.y;
  __shared__ float ql[16][113];
  __shared__ float kv[64][113];
  __shared__ float p[16][301];
  __shared__ float inv[16];
  for (int li = threadIdx.x; li < 1792; li += 256)
    ql[li/112][li%112] = bf2f(q[(size_t)(s0 + li/112)*DIMC + h*HDIM + li%112]);
  const float scale = 0.09449111825230679f;  // 1/sqrt(112)
  const int ts = threadIdx.x >> 4, tx = threadIdx.x & 15;
  for (int kc = 0; kc < 5; ++kc){
    int k0 = kc*64, nk = min(64, ENCT - k0);
    __syncthreads();
    for (int li = threadIdx.x; li < 7168; li += 256){
      int kk = li/112, d = li%112;
      kv[kk][d] = (kk < nk) ? k2[(size_t)(k0+kk)*DIMC + h*HDIM + d] : 0.f;
    }
    __syncthreads();
    float a4[4] = {};
    for (int d = 0; d < HDIM; ++d){
      float qv = ql[ts][d];
      #pragma unroll
      for (int j = 0; j < 4; ++j) a4[j] += qv * kv[tx*4+j][d];
    }
    #pragma unroll
    for (int j = 0; j < 4; ++j){
      int kg = k0 + tx*4 + j;
      if (kg < ENCT) p[ts][kg] = a4[j]*scale;
    }
  }
  __syncthreads();
  { // softmax per row over 300
    int w = threadIdx.x >> 6, l = threadIdx.x & 63;
    for (int r = w; r < 16; r += 4){
      float m = -1e30f;
      for (int j = l; j < ENCT; j += 64) m = fmaxf(m, p[r][j]);
      #pragma unroll
      for (int o = 32; o; o >>= 1) m = fmaxf(m, __shfl_xor(m, o));
      float sm = 0.f;
      for (int j = l; j < ENCT; j += 64){ float e = __expf(p[r][j]-m); p[r][j] = e; sm += e; }
      #pragma unroll
      for (int o = 32; o; o >>= 1) sm += __shfl_xor(sm, o);
      if (!l) inv[r] = 1.f/sm;
    }
  }
  float acc[7] = {};
  for (int kc = 0; kc < 5; ++kc){
    int k0 = kc*64, nk = min(64, ENCT - k0);
    __syncthreads();
    for (int li = threadIdx.x; li < 7168; li += 256){
      int kk = li/112, d = li%112;
      kv[kk][d] = (kk < nk) ? v2[(size_t)(k0+kk)*DIMC + h*HDIM + d] : 0.f;
    }
    __syncthreads();
    for (int kk = 0; kk < nk; ++kk){
      float pj = p[ts][k0+kk];
      #pragma unroll
      for (int j = 0; j < 7; ++j) acc[j] += pj * kv[kk][tx*7+j];
    }
  }
  float iv = inv[ts];
  #pragma unroll
  for (int j = 0; j < 7; ++j)
    out[(size_t)(s0+ts)*DIMC + h*HDIM + tx*7+j] = f2bf(acc[j]*iv);
}

// ---------------- depthwise 3x3 + bias + GLU(silu) ----------------
__global__ __launch_bounds__(256) void dw_k(const unsigned short* __restrict__ y1,
    const float* __restrict__ dw, const float* __restrict__ db, unsigned short* __restrict__ y2)
{
  int c = blockIdx.y*256 + threadIdx.x;
  if (c >= HID1) return;
  int pos = blockIdx.x;
  int f = pos/448, r = pos%448, hh = r/28, ww = r%28;
  float da = db[c], dg = db[c+HID1];
  #pragma unroll
  for (int dy = 0; dy < 3; ++dy){
    int y = hh+dy-1; if ((unsigned)y >= 16u) continue;
    #pragma unroll
    for (int dx = 0; dx < 3; ++dx){
      int x = ww+dx-1; if ((unsigned)x >= 28u) continue;
      size_t base = ((size_t)(f*16+y)*28 + x)*HID2;
      int widx = (dy*3+dx)*HID2;
      da += bf2f(y1[base + c       ]) * dw[widx + c];
      dg += bf2f(y1[base + c + HID1]) * dw[widx + c + HID1];
    }
  }
  float sg = dg / (1.f + __expf(-dg));
  y2[(size_t)pos*HID1 + c] = f2bf(da * sg);
}

// ---------------- final: out = x2 + g_mlp*(y3 + tc) ----------------
__global__ void final_k(const float* __restrict__ x2, const unsigned short* __restrict__ y3,
    const float* __restrict__ tc, const float* __restrict__ mods, float* __restrict__ out)
{
  int i = blockIdx.x*256 + threadIdx.x;
  if (i >= SD) return;
  int d = i % DIMC;
  out[i] = x2[i] + mods[5*DIMC + d]*(bf2f(y3[i]) + tc[i]);
}

extern "C" void kernel_launch(void* const* d_in, const int* in_sizes, int n_in,
                              void* d_out, int out_size, void* d_ws, size_t ws_size,
                              hipStream_t stream)
{
  const float* hid   = (const float*)d_in[0];
  const float* enc   = (const float*)d_in[1];
  const float* tstep = (const float*)d_in[2];
  const float* fcos  = (const float*)d_in[3];
  const float* fsin  = (const float*)d_in[4];
  const float* sst   = (const float*)d_in[5];
  const float *a1_qw=(const float*)d_in[6],  *a1_qb=(const float*)d_in[7];
  const float *a1_kw=(const float*)d_in[8],  *a1_kb=(const float*)d_in[9];
  const float *a1_vw=(const float*)d_in[10], *a1_vb=(const float*)d_in[11];
  const float *a1_nq=(const float*)d_in[12], *a1_nk=(const float*)d_in[13];
  const float *a1_ow=(const float*)d_in[14], *a1_ob=(const float*)d_in[15];
  const float *a2_qw=(const float*)d_in[16], *a2_qb=(const float*)d_in[17];
  const float *a2_kw=(const float*)d_in[18], *a2_kb=(const float*)d_in[19];
  const float *a2_vw=(const float*)d_in[20], *a2_vb=(const float*)d_in[21];
  const float *a2_nq=(const float*)d_in[22], *a2_nk=(const float*)d_in[23];
  const float *a2_ow=(const float*)d_in[24], *a2_ob=(const float*)d_in[25];
  const float *ff_inv_w=(const float*)d_in[26], *ff_inv_b=(const float*)d_in[27];
  const float *ff_dw=(const float*)d_in[28], *ff_db=(const float*)d_in[29];
  const float *ff_pw=(const float*)d_in[30];
  const float *ff_tw=(const float*)d_in[31];
  float* out = (float*)d_out;

  // ---- workspace plan (~208 MB total; all sizes 256-multiple) ----
  const size_t SLOTB = (size_t)SD*2;        // 16,056,320 B  (one bf16 S x DIM slot)
  char* ws = (char*)d_ws;
  size_t off = 0;
  auto alloc = [&](size_t n){ void* p = ws + off; off += (n + 255) & ~(size_t)255; return p; };

  char* P = (char*)alloc(7*SLOTB);          // 7 bf16 activation slots (112.4 MB)
  float* x1    = (float*)alloc((size_t)SD*4);     // fp32 residual (32.1 MB)
  unsigned short* nh2b = (unsigned short*)alloc(SLOTB); // MUST follow x1 (y2b spans both)
  float* x2    = (float*)alloc((size_t)SD*4);
  float* k2lin = (float*)alloc((size_t)ENCT*DIMC*4);
  float* v2lin = (float*)alloc((size_t)ENCT*DIMC*4);
  unsigned short* encb = (unsigned short*)alloc((size_t)ENCT*DIMC*2);
  float* modsb = (float*)alloc(6*DIMC*4);
  float* ksum  = (float*)alloc(DIMC*4);
  float* kpart = (float*)alloc((size_t)28*DIMC*4);
  float* denom = (float*)alloc((size_t)STOK*NH*4);
  float* spart = (float*)alloc((size_t)8*NH*HDIM*HDIM*4);
  unsigned short* scorb = (unsigned short*)alloc((size_t)NH*HDIM*HDIM*2);

  // P-slot aliases (lifetimes verified disjoint)
  unsigned short* P0 = (unsigned short*)P;                 // nhb | y1b[0:] | y3b
  unsigned short* P1 = (unsigned short*)(P + 1*SLOTB);     // qb | lob | y1b | tc[0:]
  unsigned short* P2 = (unsigned short*)(P + 2*SLOTB);     // kb | x1b | y1b | tc[1:]
  unsigned short* P3 = (unsigned short*)(P + 3*SLOTB);     // vb | q2b | y1b
  unsigned short* P4 = (unsigned short*)(P + 4*SLOTB);     // qrb | crb | y1b
  unsigned short* P5 = (unsigned short*)(P + 5*SLOTB);     // krb | y1b
  unsigned short* W  = (unsigned short*)(P + 6*SLOTB);     // serial weight staging (16 MB)
  unsigned short* nhb = P0;
  unsigned short* y1b = P0;                                // 96.34 MB = slots 0..5 exactly
  unsigned short* y2b = (unsigned short*)x1;               // 48.17 MB = x1 + nh2b exactly
  unsigned short* y3b = P0;
  float* tc = (float*)(P + 1*SLOTB);                       // 32.1 MB = slots 1..2

  auto cvt = [&](const float* s, unsigned short* d, size_t n){
    int n4 = (int)(n/4);
    cvt_k<<<dim3((n4+255)/256), 256, 0, stream>>>((const float4*)s, (ushort4*)d, n4);
  };
  auto gemm_dims = [&](int M, int N){ return dim3((N+127)/128, (M+127)/128); };

  mods_k<<<dim3((6*DIMC+255)/256), 256, 0, stream>>>(sst, tstep, modsb);
  cvt(enc, encb, (size_t)ENCT*DIMC);

  // ---- attn1 ----
  ln_mod_k<<<dim3(STOK), 256, 0, stream>>>(hid, modsb, 0, 1, nhb);
  dim3 gMN = gemm_dims(STOK, DIMC);
  cvt(a1_qw, W, DD);
  gemm_k<2><<<gMN, 256, 0, stream>>>(nhb, W, a1_qb, nullptr, P1, nullptr, nullptr, STOK, DIMC, DIMC, DIMC);
  cvt(a1_kw, W, DD);
  gemm_k<2><<<gMN, 256, 0, stream>>>(nhb, W, a1_kb, nullptr, P2, nullptr, nullptr, STOK, DIMC, DIMC, DIMC);
  cvt(a1_vw, W, DD);
  gemm_k<2><<<gMN, 256, 0, stream>>>(nhb, W, a1_vb, nullptr, P3, nullptr, nullptr, STOK, DIMC, DIMC, DIMC);
  rms_bf_k<1,1><<<dim3(STOK), 256, 0, stream>>>(P1, a1_nq, fcos, fsin, P4);
  rms_bf_k<1,1><<<dim3(STOK), 256, 0, stream>>>(P2, a1_nk, fcos, fsin, P5);
  colsum_k<<<dim3(9, 28), 256, 0, stream>>>(P2, kpart);
  ksumred_k<<<dim3(9), 256, 0, stream>>>(kpart, ksum);
  denom_k<<<dim3(STOK), 256, 0, stream>>>(P1, ksum, denom);
  scores_k<<<dim3(NH, 8), 256, 0, stream>>>(P3, P5, spart);
  scred_k<<<dim3((NH*HDIM*HDIM+255)/256), 256, 0, stream>>>(spart, scorb);
  linout_k<<<dim3(56, NH), 256, 0, stream>>>(P4, scorb, denom, P1);   // lob -> P1
  cvt(a1_ow, W, DD);
  gemm_k<3><<<gMN, 256, 0, stream>>>(P1, W, a1_ob, x1, P2, hid, modsb + 2*DIMC, STOK, DIMC, DIMC, DIMC); // x1 + x1b

  // ---- cross attn ----
  cvt(a2_qw, W, DD);
  gemm_k<2><<<gMN, 256, 0, stream>>>(P2, W, a2_qb, nullptr, P3, nullptr, nullptr, STOK, DIMC, DIMC, DIMC); // q2b
  dim3 gENC = gemm_dims(ENCT, DIMC);
  cvt(a2_kw, W, DD);
  gemm_k<0><<<gENC, 256, 0, stream>>>(encb, W, a2_kb, k2lin, nullptr, nullptr, nullptr, ENCT, DIMC, DIMC, DIMC);
  cvt(a2_vw, W, DD);
  gemm_k<0><<<gENC, 256, 0, stream>>>(encb, W, a2_vb, v2lin, nullptr, nullptr, nullptr, ENCT, DIMC, DIMC, DIMC);
  rms_bf_k<0,0><<<dim3(STOK), 256, 0, stream>>>(P3, a2_nq, nullptr, nullptr, nullptr);
  rms_f32_k<<<dim3(ENCT), 256, 0, stream>>>(k2lin, a2_nk);
  cross_k<<<dim3(224, NH), 256, 0, stream>>>(P3, k2lin, v2lin, P4);   // crb -> P4
  cvt(a2_ow, W, DD);
  gemm_k<4><<<gMN, 256, 0, stream>>>(P4, W, a2_ob, x2, nullptr, x1, nullptr, STOK, DIMC, DIMC, DIMC);

  // ---- FF ----
  ln_mod_k<<<dim3(STOK), 256, 0, stream>>>(x2, modsb, 3, 4, nh2b);
  for (int q = 0; q < 4; ++q){                 // ff_inv in 4 column slices of 3360
    int c0 = q*3360;
    int nel = 2240*840;                        // rows * nc/4
    cvt_cols_k<<<dim3((nel+255)/256), 256, 0, stream>>>(ff_inv_w, W, 2240, HID2, c0, 3360);
    gemm_k<1><<<gemm_dims(STOK, 3360), 256, 0, stream>>>(nh2b, W, ff_inv_b + c0, nullptr, y1b + c0,
                                                         nullptr, nullptr, STOK, 3360, DIMC, HID2);
  }
  dw_k<<<dim3(STOK, 27), 256, 0, stream>>>(y1b, ff_dw, ff_db, y2b);
  for (int hh = 0; hh < 2; ++hh){              // point conv in 2 column slices of 1120
    int c0 = hh*1120;
    int nel = 6720*280;
    cvt_cols_k<<<dim3((nel+255)/256), 256, 0, stream>>>(ff_pw, W, HID1, DIMC, c0, 1120);
    gemm_k<2><<<gemm_dims(STOK, 1120), 256, 0, stream>>>(y2b, W, nullptr, nullptr, y3b + c0,
                                                         nullptr, nullptr, STOK, 1120, HID1, DIMC);
  }
  // temporal conv: tc = y3 @ W1 (center) then shifted accumulates
  cvt(ff_tw + (size_t)DD, W, DD);
  gemm_k<0><<<gMN, 256, 0, stream>>>(y3b, W, nullptr, tc, nullptr, nullptr, nullptr, STOK, DIMC, DIMC, DIMC);
  dim3 gT = gemm_dims(3136, DIMC);
  cvt(ff_tw, W, DD);
  gemm_k<5><<<gT, 256, 0, stream>>>(y3b, W, nullptr, tc + (size_t)448*DIMC, nullptr, nullptr, nullptr, 3136, DIMC, DIMC, DIMC);
  cvt(ff_tw + (size_t)2*DD, W, DD);
  gemm_k<5><<<gT, 256, 0, stream>>>(y3b + (size_t)448*DIMC, W, nullptr, tc, nullptr, nullptr, nullptr, 3136, DIMC, DIMC, DIMC);

  // out = x2 + g_mlp*(y3 + tc)
  final_k<<<dim3((SD+255)/256), 256, 0, stream>>>(x2, y3b, tc, modsb, out);
}

// Round 3
// 4636.779 us; speedup vs baseline: 3.0389x; 3.0389x over previous
//
#include <hip/hip_runtime.h>

#define DIMC 2240
#define STOK 3584
#define ENCT 300
#define NH   20
#define HDIM 112
#define HID1 6720
#define HID2 13440
#define DD   (2240*2240)
#define SD   (3584*2240)

typedef short bf16x8 __attribute__((ext_vector_type(8)));   // guide-verified operand type
typedef float f32x4  __attribute__((ext_vector_type(4)));

__device__ __forceinline__ unsigned short f2bf(float f){
  unsigned int u = __float_as_uint(f);
  u += 0x7fffu + ((u >> 16) & 1u);          // RNE
  return (unsigned short)(u >> 16);
}
__device__ __forceinline__ float bf2f(unsigned short h){
  return __uint_as_float(((unsigned int)h) << 16);
}

// ---------------- fp32 -> bf16 convert (flat) ----------------
__global__ void cvt_k(const float4* __restrict__ src, ushort4* __restrict__ dst, int n4){
  int i = blockIdx.x*256 + threadIdx.x;
  if (i < n4){
    float4 v = src[i];
    ushort4 o; o.x = f2bf(v.x); o.y = f2bf(v.y); o.z = f2bf(v.z); o.w = f2bf(v.w);
    dst[i] = o;
  }
}
// ---------------- fp32 -> bf16 convert (column slice, packed dst) ----------------
__global__ void cvt_cols_k(const float* __restrict__ src, unsigned short* __restrict__ dst,
                           int rows, int ldsrc, int c0, int nc){
  int nc4 = nc >> 2;
  int i = blockIdx.x*256 + threadIdx.x;
  if (i >= rows*nc4) return;
  int r = i / nc4, c4 = i % nc4;
  float4 v = *reinterpret_cast<const float4*>(src + (size_t)r*ldsrc + c0 + c4*4);
  ushort4 o; o.x = f2bf(v.x); o.y = f2bf(v.y); o.z = f2bf(v.z); o.w = f2bf(v.w);
  *reinterpret_cast<ushort4*>(dst + (size_t)r*nc + c4*4) = o;
}

// ---------------- mods = scale_shift_table + timestep ----------------
__global__ void mods_k(const float* __restrict__ sst, const float* __restrict__ ts, float* __restrict__ mods){
  int i = blockIdx.x*256 + threadIdx.x;
  if (i < 6*DIMC) mods[i] = sst[i] + ts[i];
}

// ---------------- LayerNorm * (1+sc) + sh -> bf16 ----------------
__global__ __launch_bounds__(256) void ln_mod_k(const float* __restrict__ x,
    const float* __restrict__ mods, int shj, int scj, unsigned short* __restrict__ out)
{
  const int s = blockIdx.x;
  const float* row = x + (size_t)s*DIMC;
  const float* sh = mods + shj*DIMC;
  const float* sc = mods + scj*DIMC;
  float sum = 0.f, sq = 0.f;
  for (int d = threadIdx.x; d < DIMC; d += 256){ float v = row[d]; sum += v; sq += v*v; }
  #pragma unroll
  for (int o = 32; o; o >>= 1){ sum += __shfl_down(sum, o); sq += __shfl_down(sq, o); }
  __shared__ float sA[4], sB[4];
  int w = threadIdx.x >> 6, l = threadIdx.x & 63;
  if (!l){ sA[w] = sum; sB[w] = sq; }
  __syncthreads();
  sum = sA[0]+sA[1]+sA[2]+sA[3];
  sq  = sB[0]+sB[1]+sB[2]+sB[3];
  float mean = sum * (1.f/DIMC);
  float rs = rsqrtf(sq*(1.f/DIMC) - mean*mean + 1e-6f);
  unsigned short* orow = out + (size_t)s*DIMC;
  for (int d = threadIdx.x; d < DIMC; d += 256){
    float v = (row[d]-mean)*rs*(1.f + sc[d]) + sh[d];
    orow[d] = f2bf(v);
  }
}

// ---------------- RMS on bf16 rows (optional ReLU / RoPE) ----------------
template<int RELU, int ROPE>
__global__ __launch_bounds__(256) void rms_bf_k(unsigned short* __restrict__ x, const float* __restrict__ nw,
    const float* __restrict__ cosb, const float* __restrict__ sinb, unsigned short* __restrict__ xr)
{
  const int s = blockIdx.x;
  unsigned short* row = x + (size_t)s*DIMC;
  float sq = 0.f;
  for (int d = threadIdx.x; d < DIMC; d += 256){ float v = bf2f(row[d]); sq += v*v; }
  #pragma unroll
  for (int o = 32; o; o >>= 1) sq += __shfl_down(sq, o);
  __shared__ float sB[4];
  int w = threadIdx.x >> 6, l = threadIdx.x & 63;
  if (!l) sB[w] = sq;
  __syncthreads();
  sq = sB[0]+sB[1]+sB[2]+sB[3];
  float rs = rsqrtf(sq*(1.f/DIMC) + 1e-5f);
  if constexpr (!ROPE){
    for (int d = threadIdx.x; d < DIMC; d += 256){
      float v = bf2f(row[d])*rs*nw[d];
      if (RELU) v = fmaxf(v, 0.f);
      row[d] = f2bf(v);
    }
  } else {
    for (int p = threadIdx.x; p < DIMC/2; p += 256){
      int d0 = 2*p, d1 = d0+1;
      float v0 = bf2f(row[d0])*rs*nw[d0];
      float v1 = bf2f(row[d1])*rs*nw[d1];
      if (RELU){ v0 = fmaxf(v0,0.f); v1 = fmaxf(v1,0.f); }
      row[d0] = f2bf(v0); row[d1] = f2bf(v1);
      int j0 = d0 % HDIM;                       // pairs stay within a head (112 even)
      float c  = cosb[(size_t)s*HDIM + j0];     // cos[0::2]
      float sn = sinb[(size_t)s*HDIM + j0 + 1]; // sin[1::2]
      xr[(size_t)s*DIMC + d0] = f2bf(v0*c - v1*sn);
      xr[(size_t)s*DIMC + d1] = f2bf(v0*sn + v1*c);
    }
  }
}
// ---------------- RMS on fp32 rows (in place, no relu/rope) ----------------
__global__ __launch_bounds__(256) void rms_f32_k(float* __restrict__ x, const float* __restrict__ nw)
{
  const int s = blockIdx.x;
  float* row = x + (size_t)s*DIMC;
  float sq = 0.f;
  for (int d = threadIdx.x; d < DIMC; d += 256){ float v = row[d]; sq += v*v; }
  #pragma unroll
  for (int o = 32; o; o >>= 1) sq += __shfl_down(sq, o);
  __shared__ float sB[4];
  int w = threadIdx.x >> 6, l = threadIdx.x & 63;
  if (!l) sB[w] = sq;
  __syncthreads();
  sq = sB[0]+sB[1]+sB[2]+sB[3];
  float rs = rsqrtf(sq*(1.f/DIMC) + 1e-5f);
  for (int d = threadIdx.x; d < DIMC; d += 256) row[d] = row[d]*rs*nw[d];
}

// ---------------- generic bf16 MFMA GEMM: C = A(MxK) @ B(KxN), C has leading dim ldc ---
// EPI: 0 Cf=acc+bias | 1 Cb=bf16(silu(acc+bias)) | 2 Cb=bf16(acc+bias)
//      3 u=res+gate*(acc+bias); Cf=u; Cb=bf16(u) | 4 Cf=res+acc+bias | 5 Cf+=acc
template<int EPI>
__global__ __launch_bounds__(256) void gemm_k(
  const unsigned short* __restrict__ A, const unsigned short* __restrict__ B,
  const float* __restrict__ bias, float* __restrict__ Cf, unsigned short* __restrict__ Cb,
  const float* __restrict__ res, const float* __restrict__ gate,
  int M, int N, int K, int ldc)
{
  __shared__ __align__(16) unsigned short Al[128][40];  // +8 pad breaks bank conflicts
  __shared__ __align__(16) unsigned short Bl[128][40];  // stored transposed: [n][k]
  const int m0 = blockIdx.y*128, n0 = blockIdx.x*128;
  const int t = threadIdx.x;
  const int l = t & 63, w = t >> 6;
  const int wr = w >> 1, wc = w & 1;
  const int l16 = l & 15, lk = l >> 4;
  f32x4 acc[4][4] = {};

  for (int k0 = 0; k0 < K; k0 += 32){
    __syncthreads();
    #pragma unroll
    for (int i = 0; i < 2; ++i){            // A tile 128x32
      int li = i*256 + t;
      int r = li >> 2, c8 = (li & 3) << 3;
      uint4 val = make_uint4(0u,0u,0u,0u);
      if (m0 + r < M)
        val = *reinterpret_cast<const uint4*>(A + (size_t)(m0+r)*K + k0 + c8);
      *reinterpret_cast<uint4*>(&Al[r][c8]) = val;
    }
    #pragma unroll
    for (int i = 0; i < 2; ++i){            // B tile 32x128, transpose into LDS
      int li = i*256 + t;
      int kr = li >> 4, c8 = (li & 15) << 3;
      uint4 val = make_uint4(0u,0u,0u,0u);
      if (n0 + c8 < N)                      // N % 8 == 0 for all our shapes
        val = *reinterpret_cast<const uint4*>(B + (size_t)(k0+kr)*N + n0 + c8);
      unsigned int uu[4] = {val.x, val.y, val.z, val.w};
      #pragma unroll
      for (int j = 0; j < 4; ++j){
        Bl[c8 + 2*j    ][kr] = (unsigned short)(uu[j] & 0xffffu);
        Bl[c8 + 2*j + 1][kr] = (unsigned short)(uu[j] >> 16);
      }
    }
    __syncthreads();
    bf16x8 af[4], bfr[4];
    #pragma unroll
    for (int m = 0; m < 4; ++m)
      af[m] = *reinterpret_cast<const bf16x8*>(&Al[wr*64 + m*16 + l16][lk*8]);
    #pragma unroll
    for (int n = 0; n < 4; ++n)
      bfr[n] = *reinterpret_cast<const bf16x8*>(&Bl[wc*64 + n*16 + l16][lk*8]);
    #pragma unroll
    for (int m = 0; m < 4; ++m)
      #pragma unroll
      for (int n = 0; n < 4; ++n)
        acc[m][n] = __builtin_amdgcn_mfma_f32_16x16x32_bf16(af[m], bfr[n], acc[m][n], 0, 0, 0);
  }

  const int rb = m0 + wr*64 + lk*4;   // C/D: col = lane&15, row = (lane>>4)*4 + reg
  const int cb = n0 + wc*64 + l16;
  #pragma unroll
  for (int m = 0; m < 4; ++m){
    #pragma unroll
    for (int r = 0; r < 4; ++r){
      int row = rb + m*16 + r;
      if (row >= M) continue;
      #pragma unroll
      for (int n = 0; n < 4; ++n){
        int col = cb + n*16;
        if (col >= N) continue;
        float v = acc[m][n][r];
        size_t idx = (size_t)row*ldc + col;
        float bv = bias ? bias[col] : 0.f;
        if constexpr (EPI == 0){ Cf[idx] = v + bv; }
        else if constexpr (EPI == 1){ float u = v + bv; Cb[idx] = f2bf(u / (1.f + __expf(-u))); }
        else if constexpr (EPI == 2){ Cb[idx] = f2bf(v + bv); }
        else if constexpr (EPI == 3){ float u = res[idx] + gate[col]*(v + bv); Cf[idx] = u; Cb[idx] = f2bf(u); }
        else if constexpr (EPI == 4){ Cf[idx] = res[idx] + v + bv; }
        else { Cf[idx] += v; }
      }
    }
  }
}

// ---------------- linear attention helpers ----------------
// deterministic ksum: per-chunk partial colsum, then reduce
__global__ void colsum_k(const unsigned short* __restrict__ k, float* __restrict__ kpart){
  int d = blockIdx.x*256 + threadIdx.x;
  if (d >= DIMC) return;
  int ch = blockIdx.y, s0 = ch*128;
  float acc = 0.f;
  for (int s = s0; s < s0+128; ++s) acc += bf2f(k[(size_t)s*DIMC + d]);
  kpart[(size_t)ch*DIMC + d] = acc;
}
__global__ void ksumred_k(const float* __restrict__ kpart, float* __restrict__ ksum){
  int d = blockIdx.x*256 + threadIdx.x;
  if (d >= DIMC) return;
  float a = 0.f;
  for (int c = 0; c < 28; ++c) a += kpart[(size_t)c*DIMC + d];
  ksum[d] = a;
}
__global__ __launch_bounds__(256) void denom_k(const unsigned short* __restrict__ q,
    const float* __restrict__ ksum, float* __restrict__ denom)
{
  int s = blockIdx.x; int w = threadIdx.x >> 6, l = threadIdx.x & 63;
  for (int h = w; h < NH; h += 4){
    const unsigned short* qb = q + (size_t)s*DIMC + h*HDIM;
    const float* kb = ksum + h*HDIM;
    float v = bf2f(qb[l])*kb[l];
    if (l < 48) v += bf2f(qb[64+l])*kb[64+l];
    #pragma unroll
    for (int o = 32; o; o >>= 1) v += __shfl_down(v, o);
    if (!l) denom[s*NH + h] = v + 1e-15f;
  }
}
// scores_part[ch][h][e][d] = sum_{s in chunk} v[s,h,e]*kr[s,h,d]
__global__ __launch_bounds__(256) void scores_k(const unsigned short* __restrict__ v,
    const unsigned short* __restrict__ kr, float* __restrict__ part)
{
  const int h = blockIdx.x, ch = blockIdx.y;
  __shared__ float vl[8][113], kl[8][113];
  const int te = threadIdx.x >> 4, td = threadIdx.x & 15;
  float acc[7][7] = {};
  const int sbase = ch*448;
  for (int so = 0; so < 448; so += 8){
    __syncthreads();
    for (int li = threadIdx.x; li < 1792; li += 256){
      int si = li/224, r = li%224;
      if (r < HDIM) vl[si][r]      = bf2f(v [(size_t)(sbase+so+si)*DIMC + h*HDIM + r]);
      else          kl[si][r-HDIM] = bf2f(kr[(size_t)(sbase+so+si)*DIMC + h*HDIM + (r-HDIM)]);
    }
    __syncthreads();
    #pragma unroll
    for (int si = 0; si < 8; ++si){
      float vv[7], kk[7];
      #pragma unroll
      for (int a = 0; a < 7; ++a) vv[a] = vl[si][te*7+a];
      #pragma unroll
      for (int b = 0; b < 7; ++b) kk[b] = kl[si][td*7+b];
      #pragma unroll
      for (int a = 0; a < 7; ++a)
        #pragma unroll
        for (int b = 0; b < 7; ++b) acc[a][b] += vv[a]*kk[b];
    }
  }
  #pragma unroll
  for (int a = 0; a < 7; ++a)
    #pragma unroll
    for (int b = 0; b < 7; ++b)
      part[((size_t)(ch*NH + h)*HDIM + te*7+a)*HDIM + td*7+b] = acc[a][b];
}
__global__ void scred_k(const float* __restrict__ part, unsigned short* __restrict__ sc){
  int i = blockIdx.x*256 + threadIdx.x;
  if (i >= NH*HDIM*HDIM) return;
  float a = 0.f;
  #pragma unroll
  for (int c = 0; c < 8; ++c) a += part[(size_t)c*(NH*HDIM*HDIM) + i];
  sc[i] = f2bf(a);
}
// out[s, h*112+e] = (sum_d scores[h,e,d]*qr[s,h,d]) / denom[s,h]  -> bf16
__global__ __launch_bounds__(256) void linout_k(const unsigned short* __restrict__ qr,
    const unsigned short* __restrict__ scores, const float* __restrict__ denom,
    unsigned short* __restrict__ out)
{
  const int s0 = blockIdx.x*64, h = blockIdx.y;
  __shared__ unsigned short sc[112][120];
  __shared__ unsigned short qt[64][120];
  for (int li = threadIdx.x; li < 12544; li += 256)
    sc[li/112][li%112] = scores[(size_t)h*12544 + li];
  for (int li = threadIdx.x; li < 7168; li += 256)
    qt[li/112][li%112] = qr[(size_t)(s0 + li/112)*DIMC + h*HDIM + li%112];
  __syncthreads();
  const int ts = threadIdx.x >> 4, te = threadIdx.x & 15;
  float acc[4][7] = {};
  for (int d = 0; d < HDIM; ++d){
    float qv[4], sv[7];
    #pragma unroll
    for (int a = 0; a < 4; ++a) qv[a] = bf2f(qt[ts*4+a][d]);
    #pragma unroll
    for (int b = 0; b < 7; ++b) sv[b] = bf2f(sc[te*7+b][d]);
    #pragma unroll
    for (int a = 0; a < 4; ++a)
      #pragma unroll
      for (int b = 0; b < 7; ++b) acc[a][b] += qv[a]*sv[b];
  }
  #pragma unroll
  for (int a = 0; a < 4; ++a){
    int sl = s0 + ts*4 + a;
    float dn = 1.f / denom[(size_t)sl*NH + h];
    #pragma unroll
    for (int b = 0; b < 7; ++b)
      out[(size_t)sl*DIMC + h*HDIM + te*7+b] = f2bf(acc[a][b]*dn);
  }
}

// ---------------- fused cross-attention, MFMA (300 keys, head dim 112 padded to 128) ----
// grid (STOK/64, NH), 256 thr = 4 waves; wave w owns q rows block*64+w*16..+15.
// Logits (16x320) held in registers (20 f32x4/lane); softmax via shfl within row groups.
__global__ __launch_bounds__(256) void xattn_k(
    const unsigned short* __restrict__ q,   // S x DIM bf16 (rms-normed)
    const unsigned short* __restrict__ k2,  // ENCT x DIM bf16 (rms-normed)
    const unsigned short* __restrict__ v2,  // ENCT x DIM bf16
    unsigned short* __restrict__ outb)      // S x DIM bf16
{
  const int h = blockIdx.y;
  const int w = threadIdx.x >> 6, lane = threadIdx.x & 63;
  const int l16 = lane & 15, lk = lane >> 4;
  const float scale = 0.09449111825230679f;   // 1/sqrt(112)

  __shared__ __align__(16) unsigned short Kl[64][136];   // K chunk [key][d], 2-way-free
  __shared__ __align__(16) unsigned short Vl[112][72];   // V chunk transposed [d][key]
  __shared__ __align__(16) unsigned short Pl[4][16][72]; // per-wave P chunk [row][key]

  // Q fragments: row = l16 (A-operand row), k = c*32 + lk*8 + j
  bf16x8 qf[4];
  const unsigned short* qbase = q + (size_t)(blockIdx.x*64 + w*16 + l16)*DIMC + h*HDIM;
  #pragma unroll
  for (int c = 0; c < 4; ++c){
    int d0 = c*32 + lk*8;
    bf16x8 z = {};
    qf[c] = (d0 < HDIM) ? *reinterpret_cast<const bf16x8*>(qbase + d0) : z;
  }

  f32x4 lg[5][4] = {};   // logits: 5 key-chunks x 4 n-tiles

  #pragma unroll
  for (int c = 0; c < 5; ++c){
    const int kbase = c*64;
    const int nk = (c == 4) ? (ENCT - 256) : 64;
    __syncthreads();
    #pragma unroll
    for (int it = 0; it < 4; ++it){          // stage K chunk: 64 keys x 128 cols (zero pad)
      int li = it*256 + threadIdx.x;
      int key = li >> 4, d0 = (li & 15) << 3;
      uint4 val = make_uint4(0u,0u,0u,0u);
      if (key < nk && d0 < HDIM)
        val = *reinterpret_cast<const uint4*>(k2 + (size_t)(kbase+key)*DIMC + h*HDIM + d0);
      *reinterpret_cast<uint4*>(&Kl[key][d0]) = val;
    }
    __syncthreads();
    #pragma unroll
    for (int nt = 0; nt < 4; ++nt){
      #pragma unroll
      for (int ks = 0; ks < 4; ++ks){
        bf16x8 kf = *reinterpret_cast<const bf16x8*>(&Kl[nt*16 + l16][ks*32 + lk*8]);
        lg[c][nt] = __builtin_amdgcn_mfma_f32_16x16x32_bf16(qf[ks], kf, lg[c][nt], 0, 0, 0);
      }
    }
  }

  // softmax over 300 valid cols; lane holds rows lk*4+r, cols c*64+nt*16+l16
  float mx[4] = {-3e38f, -3e38f, -3e38f, -3e38f};
  #pragma unroll
  for (int c = 0; c < 5; ++c)
    #pragma unroll
    for (int nt = 0; nt < 4; ++nt){
      bool valid = (c*64 + nt*16 + l16) < ENCT;
      #pragma unroll
      for (int r = 0; r < 4; ++r){
        float v = valid ? lg[c][nt][r]*scale : -3e38f;
        lg[c][nt][r] = v;
        mx[r] = fmaxf(mx[r], v);
      }
    }
  #pragma unroll
  for (int o = 1; o < 16; o <<= 1)
    #pragma unroll
    for (int r = 0; r < 4; ++r) mx[r] = fmaxf(mx[r], __shfl_xor(mx[r], o));
  float sm[4] = {0.f, 0.f, 0.f, 0.f};
  #pragma unroll
  for (int c = 0; c < 5; ++c)
    #pragma unroll
    for (int nt = 0; nt < 4; ++nt)
      #pragma unroll
      for (int r = 0; r < 4; ++r){
        float e = __expf(lg[c][nt][r] - mx[r]);
        lg[c][nt][r] = e;
        sm[r] += e;
      }
  #pragma unroll
  for (int o = 1; o < 16; o <<= 1)
    #pragma unroll
    for (int r = 0; r < 4; ++r) sm[r] += __shfl_xor(sm[r], o);
  float inv[4];
  #pragma unroll
  for (int r = 0; r < 4; ++r) inv[r] = 1.f / sm[r];

  // PV: per chunk, stage V transposed + write P chunk, then mfma
  f32x4 oacc[7] = {};
  #pragma unroll
  for (int c = 0; c < 5; ++c){
    const int kbase = c*64;
    const int nk = (c == 4) ? (ENCT - 256) : 64;
    __syncthreads();
    #pragma unroll
    for (int it = 0; it < 4; ++it){          // 64 keys x 14 d-groups of 8
      int li = it*256 + threadIdx.x;
      if (li < 896){
        int key = li/14, d0 = (li%14)*8;
        if (key < nk){
          bf16x8 vv = *reinterpret_cast<const bf16x8*>(v2 + (size_t)(kbase+key)*DIMC + h*HDIM + d0);
          #pragma unroll
          for (int j = 0; j < 8; ++j) Vl[d0+j][key] = (unsigned short)vv[j];
        } else {
          #pragma unroll
          for (int j = 0; j < 8; ++j) Vl[d0+j][key] = 0;
        }
      }
    }
    #pragma unroll
    for (int nt = 0; nt < 4; ++nt)
      #pragma unroll
      for (int r = 0; r < 4; ++r)
        Pl[w][lk*4 + r][nt*16 + l16] = f2bf(lg[c][nt][r]);
    __syncthreads();
    #pragma unroll
    for (int ks = 0; ks < 2; ++ks){
      bf16x8 pf = *reinterpret_cast<const bf16x8*>(&Pl[w][l16][ks*32 + lk*8]);
      #pragma unroll
      for (int n = 0; n < 7; ++n){
        bf16x8 vf = *reinterpret_cast<const bf16x8*>(&Vl[n*16 + l16][ks*32 + lk*8]);
        oacc[n] = __builtin_amdgcn_mfma_f32_16x16x32_bf16(pf, vf, oacc[n], 0, 0, 0);
      }
    }
  }

  // C layout: col = l16 (d within n-tile), row = lk*4 + r (q row within wave tile)
  const int orow = blockIdx.x*64 + w*16 + lk*4;
  #pragma unroll
  for (int n = 0; n < 7; ++n)
    #pragma unroll
    for (int r = 0; r < 4; ++r)
      outb[(size_t)(orow + r)*DIMC + h*HDIM + n*16 + l16] = f2bf(oacc[n][r]*inv[r]);
}

// ---------------- depthwise 3x3 + bias + GLU(silu) ----------------
__global__ __launch_bounds__(256) void dw_k(const unsigned short* __restrict__ y1,
    const float* __restrict__ dw, const float* __restrict__ db, unsigned short* __restrict__ y2)
{
  int c = blockIdx.y*256 + threadIdx.x;
  if (c >= HID1) return;
  int pos = blockIdx.x;
  int f = pos/448, r = pos%448, hh = r/28, ww = r%28;
  float da = db[c], dg = db[c+HID1];
  #pragma unroll
  for (int dy = 0; dy < 3; ++dy){
    int y = hh+dy-1; if ((unsigned)y >= 16u) continue;
    #pragma unroll
    for (int dx = 0; dx < 3; ++dx){
      int x = ww+dx-1; if ((unsigned)x >= 28u) continue;
      size_t base = ((size_t)(f*16+y)*28 + x)*HID2;
      int widx = (dy*3+dx)*HID2;
      da += bf2f(y1[base + c       ]) * dw[widx + c];
      dg += bf2f(y1[base + c + HID1]) * dw[widx + c + HID1];
    }
  }
  float sg = dg / (1.f + __expf(-dg));
  y2[(size_t)pos*HID1 + c] = f2bf(da * sg);
}

// ---------------- final: out = x2 + g_mlp*(y3 + tc) ----------------
__global__ void final_k(const float* __restrict__ x2, const unsigned short* __restrict__ y3,
    const float* __restrict__ tc, const float* __restrict__ mods, float* __restrict__ out)
{
  int i = blockIdx.x*256 + threadIdx.x;
  if (i >= SD) return;
  int d = i % DIMC;
  out[i] = x2[i] + mods[5*DIMC + d]*(bf2f(y3[i]) + tc[i]);
}

extern "C" void kernel_launch(void* const* d_in, const int* in_sizes, int n_in,
                              void* d_out, int out_size, void* d_ws, size_t ws_size,
                              hipStream_t stream)
{
  const float* hid   = (const float*)d_in[0];
  const float* enc   = (const float*)d_in[1];
  const float* tstep = (const float*)d_in[2];
  const float* fcos  = (const float*)d_in[3];
  const float* fsin  = (const float*)d_in[4];
  const float* sst   = (const float*)d_in[5];
  const float *a1_qw=(const float*)d_in[6],  *a1_qb=(const float*)d_in[7];
  const float *a1_kw=(const float*)d_in[8],  *a1_kb=(const float*)d_in[9];
  const float *a1_vw=(const float*)d_in[10], *a1_vb=(const float*)d_in[11];
  const float *a1_nq=(const float*)d_in[12], *a1_nk=(const float*)d_in[13];
  const float *a1_ow=(const float*)d_in[14], *a1_ob=(const float*)d_in[15];
  const float *a2_qw=(const float*)d_in[16], *a2_qb=(const float*)d_in[17];
  const float *a2_kw=(const float*)d_in[18], *a2_kb=(const float*)d_in[19];
  const float *a2_vw=(const float*)d_in[20], *a2_vb=(const float*)d_in[21];
  const float *a2_nq=(const float*)d_in[22], *a2_nk=(const float*)d_in[23];
  const float *a2_ow=(const float*)d_in[24], *a2_ob=(const float*)d_in[25];
  const float *ff_inv_w=(const float*)d_in[26], *ff_inv_b=(const float*)d_in[27];
  const float *ff_dw=(const float*)d_in[28], *ff_db=(const float*)d_in[29];
  const float *ff_pw=(const float*)d_in[30];
  const float *ff_tw=(const float*)d_in[31];
  float* out = (float*)d_out;

  // ---- workspace plan (~211 MB total; all sizes 256-multiple) ----
  const size_t SLOTB = (size_t)SD*2;        // 16,056,320 B  (one bf16 S x DIM slot)
  char* ws = (char*)d_ws;
  size_t off = 0;
  auto alloc = [&](size_t n){ void* p = ws + off; off += (n + 255) & ~(size_t)255; return p; };

  char* P = (char*)alloc(7*SLOTB);          // 7 bf16 activation slots (112.4 MB)
  float* x1    = (float*)alloc((size_t)SD*4);     // fp32 residual (32.1 MB)
  unsigned short* nh2b = (unsigned short*)alloc(SLOTB); // MUST follow x1 (y2b spans both)
  float* x2    = (float*)alloc((size_t)SD*4);
  float* k2lin = (float*)alloc((size_t)ENCT*DIMC*4);
  unsigned short* k2b = (unsigned short*)alloc((size_t)ENCT*DIMC*2);
  unsigned short* v2b = (unsigned short*)alloc((size_t)ENCT*DIMC*2);
  unsigned short* encb = (unsigned short*)alloc((size_t)ENCT*DIMC*2);
  float* modsb = (float*)alloc(6*DIMC*4);
  float* ksum  = (float*)alloc(DIMC*4);
  float* kpart = (float*)alloc((size_t)28*DIMC*4);
  float* denom = (float*)alloc((size_t)STOK*NH*4);
  float* spart = (float*)alloc((size_t)8*NH*HDIM*HDIM*4);
  unsigned short* scorb = (unsigned short*)alloc((size_t)NH*HDIM*HDIM*2);

  // P-slot aliases (lifetimes verified disjoint)
  unsigned short* P0 = (unsigned short*)P;                 // nhb | y1b[0:] | y3b
  unsigned short* P1 = (unsigned short*)(P + 1*SLOTB);     // qb | lob | y1b | tc[0:]
  unsigned short* P2 = (unsigned short*)(P + 2*SLOTB);     // kb | x1b | y1b | tc[1:]
  unsigned short* P3 = (unsigned short*)(P + 3*SLOTB);     // vb | q2b | y1b
  unsigned short* P4 = (unsigned short*)(P + 4*SLOTB);     // qrb | crb | y1b
  unsigned short* P5 = (unsigned short*)(P + 5*SLOTB);     // krb | y1b
  unsigned short* W  = (unsigned short*)(P + 6*SLOTB);     // serial weight staging (16 MB)
  unsigned short* nhb = P0;
  unsigned short* y1b = P0;                                // 96.34 MB = slots 0..5 exactly
  unsigned short* y2b = (unsigned short*)x1;               // 48.17 MB = x1 + nh2b exactly
  unsigned short* y3b = P0;
  float* tc = (float*)(P + 1*SLOTB);                       // 32.1 MB = slots 1..2

  auto cvt = [&](const float* s, unsigned short* d, size_t n){
    int n4 = (int)(n/4);
    cvt_k<<<dim3((n4+255)/256), 256, 0, stream>>>((const float4*)s, (ushort4*)d, n4);
  };
  auto gemm_dims = [&](int M, int N){ return dim3((N+127)/128, (M+127)/128); };

  mods_k<<<dim3((6*DIMC+255)/256), 256, 0, stream>>>(sst, tstep, modsb);
  cvt(enc, encb, (size_t)ENCT*DIMC);

  // ---- attn1 ----
  ln_mod_k<<<dim3(STOK), 256, 0, stream>>>(hid, modsb, 0, 1, nhb);
  dim3 gMN = gemm_dims(STOK, DIMC);
  cvt(a1_qw, W, DD);
  gemm_k<2><<<gMN, 256, 0, stream>>>(nhb, W, a1_qb, nullptr, P1, nullptr, nullptr, STOK, DIMC, DIMC, DIMC);
  cvt(a1_kw, W, DD);
  gemm_k<2><<<gMN, 256, 0, stream>>>(nhb, W, a1_kb, nullptr, P2, nullptr, nullptr, STOK, DIMC, DIMC, DIMC);
  cvt(a1_vw, W, DD);
  gemm_k<2><<<gMN, 256, 0, stream>>>(nhb, W, a1_vb, nullptr, P3, nullptr, nullptr, STOK, DIMC, DIMC, DIMC);
  rms_bf_k<1,1><<<dim3(STOK), 256, 0, stream>>>(P1, a1_nq, fcos, fsin, P4);
  rms_bf_k<1,1><<<dim3(STOK), 256, 0, stream>>>(P2, a1_nk, fcos, fsin, P5);
  colsum_k<<<dim3(9, 28), 256, 0, stream>>>(P2, kpart);
  ksumred_k<<<dim3(9), 256, 0, stream>>>(kpart, ksum);
  denom_k<<<dim3(STOK), 256, 0, stream>>>(P1, ksum, denom);
  scores_k<<<dim3(NH, 8), 256, 0, stream>>>(P3, P5, spart);
  scred_k<<<dim3((NH*HDIM*HDIM+255)/256), 256, 0, stream>>>(spart, scorb);
  linout_k<<<dim3(56, NH), 256, 0, stream>>>(P4, scorb, denom, P1);   // lob -> P1
  cvt(a1_ow, W, DD);
  gemm_k<3><<<gMN, 256, 0, stream>>>(P1, W, a1_ob, x1, P2, hid, modsb + 2*DIMC, STOK, DIMC, DIMC, DIMC); // x1 + x1b

  // ---- cross attn ----
  cvt(a2_qw, W, DD);
  gemm_k<2><<<gMN, 256, 0, stream>>>(P2, W, a2_qb, nullptr, P3, nullptr, nullptr, STOK, DIMC, DIMC, DIMC); // q2b
  dim3 gENC = gemm_dims(ENCT, DIMC);
  cvt(a2_kw, W, DD);
  gemm_k<0><<<gENC, 256, 0, stream>>>(encb, W, a2_kb, k2lin, nullptr, nullptr, nullptr, ENCT, DIMC, DIMC, DIMC);
  cvt(a2_vw, W, DD);
  gemm_k<2><<<gENC, 256, 0, stream>>>(encb, W, a2_vb, nullptr, v2b, nullptr, nullptr, ENCT, DIMC, DIMC, DIMC);
  rms_bf_k<0,0><<<dim3(STOK), 256, 0, stream>>>(P3, a2_nq, nullptr, nullptr, nullptr);
  rms_f32_k<<<dim3(ENCT), 256, 0, stream>>>(k2lin, a2_nk);
  cvt(k2lin, k2b, (size_t)ENCT*DIMC);
  xattn_k<<<dim3(STOK/64, NH), 256, 0, stream>>>(P3, k2b, v2b, P4);   // crb -> P4
  cvt(a2_ow, W, DD);
  gemm_k<4><<<gMN, 256, 0, stream>>>(P4, W, a2_ob, x2, nullptr, x1, nullptr, STOK, DIMC, DIMC, DIMC);

  // ---- FF ----
  ln_mod_k<<<dim3(STOK), 256, 0, stream>>>(x2, modsb, 3, 4, nh2b);
  for (int q = 0; q < 4; ++q){                 // ff_inv in 4 column slices of 3360
    int c0 = q*3360;
    int nel = 2240*840;                        // rows * nc/4
    cvt_cols_k<<<dim3((nel+255)/256), 256, 0, stream>>>(ff_inv_w, W, 2240, HID2, c0, 3360);
    gemm_k<1><<<gemm_dims(STOK, 3360), 256, 0, stream>>>(nh2b, W, ff_inv_b + c0, nullptr, y1b + c0,
                                                         nullptr, nullptr, STOK, 3360, DIMC, HID2);
  }
  dw_k<<<dim3(STOK, 27), 256, 0, stream>>>(y1b, ff_dw, ff_db, y2b);
  for (int hh = 0; hh < 2; ++hh){              // point conv in 2 column slices of 1120
    int c0 = hh*1120;
    int nel = 6720*280;
    cvt_cols_k<<<dim3((nel+255)/256), 256, 0, stream>>>(ff_pw, W, HID1, DIMC, c0, 1120);
    gemm_k<2><<<gemm_dims(STOK, 1120), 256, 0, stream>>>(y2b, W, nullptr, nullptr, y3b + c0,
                                                         nullptr, nullptr, STOK, 1120, HID1, DIMC);
  }
  // temporal conv: tc = y3 @ W1 (center) then shifted accumulates
  cvt(ff_tw + (size_t)DD, W, DD);
  gemm_k<0><<<gMN, 256, 0, stream>>>(y3b, W, nullptr, tc, nullptr, nullptr, nullptr, STOK, DIMC, DIMC, DIMC);
  dim3 gT = gemm_dims(3136, DIMC);
  cvt(ff_tw, W, DD);
  gemm_k<5><<<gT, 256, 0, stream>>>(y3b, W, nullptr, tc + (size_t)448*DIMC, nullptr, nullptr, nullptr, 3136, DIMC, DIMC, DIMC);
  cvt(ff_tw + (size_t)2*DD, W, DD);
  gemm_k<5><<<gT, 256, 0, stream>>>(y3b + (size_t)448*DIMC, W, nullptr, tc, nullptr, nullptr, nullptr, 3136, DIMC, DIMC, DIMC);

  // out = x2 + g_mlp*(y3 + tc)
  final_k<<<dim3((SD+255)/256), 256, 0, stream>>>(x2, y3b, tc, modsb, out);
}

// Round 4
// 2275.790 us; speedup vs baseline: 6.1916x; 2.0374x over previous
//
#include <hip/hip_runtime.h>

#define DIMC 2240
#define STOK 3584
#define ENCT 300
#define NH   20
#define HDIM 112
#define HID1 6720
#define HID2 13440
#define DD   (2240*2240)
#define SD   (3584*2240)

typedef short bf16x8 __attribute__((ext_vector_type(8)));   // guide-verified operand type
typedef float f32x4  __attribute__((ext_vector_type(4)));

__device__ __forceinline__ unsigned short f2bf(float f){
  unsigned int u = __float_as_uint(f);
  u += 0x7fffu + ((u >> 16) & 1u);          // RNE
  return (unsigned short)(u >> 16);
}
__device__ __forceinline__ float bf2f(unsigned short h){
  return __uint_as_float(((unsigned int)h) << 16);
}
__device__ __forceinline__ void gl_lds16(const unsigned short* g, unsigned short* l){
  __builtin_amdgcn_global_load_lds(
      (const __attribute__((address_space(1))) unsigned int*)(const void*)g,
      (__attribute__((address_space(3))) unsigned int*)(void*)l, 16, 0, 0);
}

// ---------------- fp32 -> bf16 convert (flat) ----------------
__global__ void cvt_k(const float4* __restrict__ src, ushort4* __restrict__ dst, int n4){
  int i = blockIdx.x*256 + threadIdx.x;
  if (i < n4){
    float4 v = src[i];
    ushort4 o; o.x = f2bf(v.x); o.y = f2bf(v.y); o.z = f2bf(v.z); o.w = f2bf(v.w);
    dst[i] = o;
  }
}

// ------- fp32 (rows x cols slice) -> bf16 TRANSPOSED [ncPad][rows], zero-padded -------
__global__ __launch_bounds__(256) void cvt_t_k(const float* __restrict__ src,
    unsigned short* __restrict__ dst, int rows, int ldsrc, int c0, int nc){
  __shared__ float tile[32][33];
  const int tx = threadIdx.x & 31, ty = threadIdx.x >> 5;   // ty 0..7
  const int colBase = blockIdx.x*32;
  #pragma unroll
  for (int i = 0; i < 4; ++i){
    int rr = blockIdx.y*32 + ty + i*8;
    int cc = colBase + tx;
    tile[ty + i*8][tx] = (cc < nc) ? src[(size_t)rr*ldsrc + c0 + cc] : 0.f;
  }
  __syncthreads();
  #pragma unroll
  for (int i = 0; i < 4; ++i){
    int n = colBase + ty + i*8;          // < ncPad by grid
    int k = blockIdx.y*32 + tx;
    dst[(size_t)n*rows + k] = f2bf(tile[tx][ty + i*8]);
  }
}

// ---------------- mods = scale_shift_table + timestep ----------------
__global__ void mods_k(const float* __restrict__ sst, const float* __restrict__ ts, float* __restrict__ mods){
  int i = blockIdx.x*256 + threadIdx.x;
  if (i < 6*DIMC) mods[i] = sst[i] + ts[i];
}

// ---------------- LayerNorm * (1+sc) + sh -> bf16 ----------------
__global__ __launch_bounds__(256) void ln_mod_k(const float* __restrict__ x,
    const float* __restrict__ mods, int shj, int scj, unsigned short* __restrict__ out)
{
  const int s = blockIdx.x;
  const float* row = x + (size_t)s*DIMC;
  const float* sh = mods + shj*DIMC;
  const float* sc = mods + scj*DIMC;
  float sum = 0.f, sq = 0.f;
  for (int d = threadIdx.x; d < DIMC; d += 256){ float v = row[d]; sum += v; sq += v*v; }
  #pragma unroll
  for (int o = 32; o; o >>= 1){ sum += __shfl_down(sum, o); sq += __shfl_down(sq, o); }
  __shared__ float sA[4], sB[4];
  int w = threadIdx.x >> 6, l = threadIdx.x & 63;
  if (!l){ sA[w] = sum; sB[w] = sq; }
  __syncthreads();
  sum = sA[0]+sA[1]+sA[2]+sA[3];
  sq  = sB[0]+sB[1]+sB[2]+sB[3];
  float mean = sum * (1.f/DIMC);
  float rs = rsqrtf(sq*(1.f/DIMC) - mean*mean + 1e-6f);
  unsigned short* orow = out + (size_t)s*DIMC;
  for (int d = threadIdx.x; d < DIMC; d += 256){
    float v = (row[d]-mean)*rs*(1.f + sc[d]) + sh[d];
    orow[d] = f2bf(v);
  }
}

// ---------------- RMS on bf16 rows (optional ReLU / RoPE) ----------------
template<int RELU, int ROPE>
__global__ __launch_bounds__(256) void rms_bf_k(unsigned short* __restrict__ x, const float* __restrict__ nw,
    const float* __restrict__ cosb, const float* __restrict__ sinb, unsigned short* __restrict__ xr)
{
  const int s = blockIdx.x;
  unsigned short* row = x + (size_t)s*DIMC;
  float sq = 0.f;
  for (int d = threadIdx.x; d < DIMC; d += 256){ float v = bf2f(row[d]); sq += v*v; }
  #pragma unroll
  for (int o = 32; o; o >>= 1) sq += __shfl_down(sq, o);
  __shared__ float sB[4];
  int w = threadIdx.x >> 6, l = threadIdx.x & 63;
  if (!l) sB[w] = sq;
  __syncthreads();
  sq = sB[0]+sB[1]+sB[2]+sB[3];
  float rs = rsqrtf(sq*(1.f/DIMC) + 1e-5f);
  if constexpr (!ROPE){
    for (int d = threadIdx.x; d < DIMC; d += 256){
      float v = bf2f(row[d])*rs*nw[d];
      if (RELU) v = fmaxf(v, 0.f);
      row[d] = f2bf(v);
    }
  } else {
    for (int p = threadIdx.x; p < DIMC/2; p += 256){
      int d0 = 2*p, d1 = d0+1;
      float v0 = bf2f(row[d0])*rs*nw[d0];
      float v1 = bf2f(row[d1])*rs*nw[d1];
      if (RELU){ v0 = fmaxf(v0,0.f); v1 = fmaxf(v1,0.f); }
      row[d0] = f2bf(v0); row[d1] = f2bf(v1);
      int j0 = d0 % HDIM;                       // pairs stay within a head (112 even)
      float c  = cosb[(size_t)s*HDIM + j0];     // cos[0::2]
      float sn = sinb[(size_t)s*HDIM + j0 + 1]; // sin[1::2]
      xr[(size_t)s*DIMC + d0] = f2bf(v0*c - v1*sn);
      xr[(size_t)s*DIMC + d1] = f2bf(v0*sn + v1*c);
    }
  }
}
// ---------------- RMS on fp32 rows (in place, no relu/rope) ----------------
__global__ __launch_bounds__(256) void rms_f32_k(float* __restrict__ x, const float* __restrict__ nw)
{
  const int s = blockIdx.x;
  float* row = x + (size_t)s*DIMC;
  float sq = 0.f;
  for (int d = threadIdx.x; d < DIMC; d += 256){ float v = row[d]; sq += v*v; }
  #pragma unroll
  for (int o = 32; o; o >>= 1) sq += __shfl_down(sq, o);
  __shared__ float sB[4];
  int w = threadIdx.x >> 6, l = threadIdx.x & 63;
  if (!l) sB[w] = sq;
  __syncthreads();
  sq = sB[0]+sB[1]+sB[2]+sB[3];
  float rs = rsqrtf(sq*(1.f/DIMC) + 1e-5f);
  for (int d = threadIdx.x; d < DIMC; d += 256) row[d] = row[d]*rs*nw[d];
}

// ------- m97-structure bf16 MFMA GEMM: C = A(MxK) @ Bt^T, Bt is [Npad][K] (N-major) -----
// Requires: K % 32 == 0; Bt padded to Npad = gridDim.x*128 rows (zeros beyond N).
// EPI: 0 Cf=acc+bias | 1 Cb=bf16(silu(acc+bias)) | 2 Cb=bf16(acc+bias)
//      3 u=res+gate*(acc+bias); Cf=u; Cb=bf16(u) | 4 Cf=res+acc+bias | 5 Cf+=acc
template<int EPI>
__global__ __launch_bounds__(256) void gemm_bt(
  const unsigned short* __restrict__ A, const unsigned short* __restrict__ Bt,
  const float* __restrict__ bias, float* __restrict__ Cf, unsigned short* __restrict__ Cb,
  const float* __restrict__ res, const float* __restrict__ gate,
  int M, int N, int K, int ldc)
{
  __shared__ __align__(16) unsigned short Al[128*32];
  __shared__ __align__(16) unsigned short Bl[128*32];
  // bijective XCD-aware swizzle (m204)
  const int gx = gridDim.x;
  const int nwg = gx*gridDim.y;
  const int orig = blockIdx.y*gx + blockIdx.x;
  const int qq = nwg >> 3, rr = nwg & 7;
  const int xcd = orig & 7, li = orig >> 3;
  const int wg = (xcd < rr ? xcd*(qq+1) : rr*(qq+1) + (xcd-rr)*qq) + li;
  const int m0 = (wg / gx)*128, n0 = (wg % gx)*128;

  const int t = threadIdx.x;
  const int lane = t & 63, w = t >> 6;
  const int wr = w >> 1, wc = w & 1;
  const int l16 = lane & 15, lk = lane >> 4;

  // staging: wave w owns LDS chunks {2w, 2w+1} (1 KiB each = 16 rows of [128][32])
  const int lrow = lane >> 2;          // 0..15
  const int lcol = (lane & 3) << 3;    // 0,8,16,24
  const int arow0 = m0 + w*32 + lrow;
  const int brow0 = n0 + w*32 + lrow;
  const unsigned short* Ap0 = A + (size_t)min(arow0,      M-1)*K + lcol;
  const unsigned short* Ap1 = A + (size_t)min(arow0 + 16, M-1)*K + lcol;
  const unsigned short* Bp0 = Bt + (size_t)(brow0     )*K + lcol;
  const unsigned short* Bp1 = Bt + (size_t)(brow0 + 16)*K + lcol;
  unsigned short* Ad0 = Al + (w*2+0)*512;
  unsigned short* Ad1 = Al + (w*2+1)*512;
  unsigned short* Bd0 = Bl + (w*2+0)*512;
  unsigned short* Bd1 = Bl + (w*2+1)*512;

  f32x4 acc[4][4] = {};
  for (int k0 = 0; k0 < K; k0 += 32){
    __syncthreads();                       // previous tile fully consumed
    gl_lds16(Ap0 + k0, Ad0);
    gl_lds16(Ap1 + k0, Ad1);
    gl_lds16(Bp0 + k0, Bd0);
    gl_lds16(Bp1 + k0, Bd1);
    __syncthreads();                       // drains vmcnt -> tile ready
    bf16x8 af[4], bfr[4];
    #pragma unroll
    for (int m = 0; m < 4; ++m)
      af[m] = *reinterpret_cast<const bf16x8*>(Al + (wr*64 + m*16 + l16)*32 + lk*8);
    #pragma unroll
    for (int n = 0; n < 4; ++n)
      bfr[n] = *reinterpret_cast<const bf16x8*>(Bl + (wc*64 + n*16 + l16)*32 + lk*8);
    #pragma unroll
    for (int m = 0; m < 4; ++m)
      #pragma unroll
      for (int n = 0; n < 4; ++n)
        acc[m][n] = __builtin_amdgcn_mfma_f32_16x16x32_bf16(af[m], bfr[n], acc[m][n], 0, 0, 0);
  }

  const int rb = m0 + wr*64 + lk*4;   // C/D: col = lane&15, row = (lane>>4)*4 + reg
  const int cb = n0 + wc*64 + l16;
  #pragma unroll
  for (int m = 0; m < 4; ++m){
    #pragma unroll
    for (int r = 0; r < 4; ++r){
      int row = rb + m*16 + r;
      if (row >= M) continue;
      #pragma unroll
      for (int n = 0; n < 4; ++n){
        int col = cb + n*16;
        if (col >= N) continue;
        float v = acc[m][n][r];
        size_t idx = (size_t)row*ldc + col;
        float bv = bias ? bias[col] : 0.f;
        if constexpr (EPI == 0){ Cf[idx] = v + bv; }
        else if constexpr (EPI == 1){ float u = v + bv; Cb[idx] = f2bf(u / (1.f + __expf(-u))); }
        else if constexpr (EPI == 2){ Cb[idx] = f2bf(v + bv); }
        else if constexpr (EPI == 3){ float u = res[idx] + gate[col]*(v + bv); Cf[idx] = u; Cb[idx] = f2bf(u); }
        else if constexpr (EPI == 4){ Cf[idx] = res[idx] + v + bv; }
        else { Cf[idx] += v; }
      }
    }
  }
}

// ---------------- linear attention helpers ----------------
__global__ void colsum_k(const unsigned short* __restrict__ k, float* __restrict__ kpart){
  int d = blockIdx.x*256 + threadIdx.x;
  if (d >= DIMC) return;
  int ch = blockIdx.y, s0 = ch*128;
  float acc = 0.f;
  for (int s = s0; s < s0+128; ++s) acc += bf2f(k[(size_t)s*DIMC + d]);
  kpart[(size_t)ch*DIMC + d] = acc;
}
__global__ void ksumred_k(const float* __restrict__ kpart, float* __restrict__ ksum){
  int d = blockIdx.x*256 + threadIdx.x;
  if (d >= DIMC) return;
  float a = 0.f;
  for (int c = 0; c < 28; ++c) a += kpart[(size_t)c*DIMC + d];
  ksum[d] = a;
}
__global__ __launch_bounds__(256) void denom_k(const unsigned short* __restrict__ q,
    const float* __restrict__ ksum, float* __restrict__ denom)
{
  int s = blockIdx.x; int w = threadIdx.x >> 6, l = threadIdx.x & 63;
  for (int h = w; h < NH; h += 4){
    const unsigned short* qb = q + (size_t)s*DIMC + h*HDIM;
    const float* kb = ksum + h*HDIM;
    float v = bf2f(qb[l])*kb[l];
    if (l < 48) v += bf2f(qb[64+l])*kb[64+l];
    #pragma unroll
    for (int o = 32; o; o >>= 1) v += __shfl_down(v, o);
    if (!l) denom[s*NH + h] = v + 1e-15f;
  }
}
// scores_part[ch][h][e][d] = sum_{s in chunk} v[s,h,e]*kr[s,h,d]
__global__ __launch_bounds__(256) void scores_k(const unsigned short* __restrict__ v,
    const unsigned short* __restrict__ kr, float* __restrict__ part)
{
  const int h = blockIdx.x, ch = blockIdx.y;
  __shared__ float vl[8][113], kl[8][113];
  const int te = threadIdx.x >> 4, td = threadIdx.x & 15;
  float acc[7][7] = {};
  const int sbase = ch*448;
  for (int so = 0; so < 448; so += 8){
    __syncthreads();
    for (int li = threadIdx.x; li < 1792; li += 256){
      int si = li/224, r = li%224;
      if (r < HDIM) vl[si][r]      = bf2f(v [(size_t)(sbase+so+si)*DIMC + h*HDIM + r]);
      else          kl[si][r-HDIM] = bf2f(kr[(size_t)(sbase+so+si)*DIMC + h*HDIM + (r-HDIM)]);
    }
    __syncthreads();
    #pragma unroll
    for (int si = 0; si < 8; ++si){
      float vv[7], kk[7];
      #pragma unroll
      for (int a = 0; a < 7; ++a) vv[a] = vl[si][te*7+a];
      #pragma unroll
      for (int b = 0; b < 7; ++b) kk[b] = kl[si][td*7+b];
      #pragma unroll
      for (int a = 0; a < 7; ++a)
        #pragma unroll
        for (int b = 0; b < 7; ++b) acc[a][b] += vv[a]*kk[b];
    }
  }
  #pragma unroll
  for (int a = 0; a < 7; ++a)
    #pragma unroll
    for (int b = 0; b < 7; ++b)
      part[((size_t)(ch*NH + h)*HDIM + te*7+a)*HDIM + td*7+b] = acc[a][b];
}
__global__ void scred_k(const float* __restrict__ part, unsigned short* __restrict__ sc){
  int i = blockIdx.x*256 + threadIdx.x;
  if (i >= NH*HDIM*HDIM) return;
  float a = 0.f;
  #pragma unroll
  for (int c = 0; c < 8; ++c) a += part[(size_t)c*(NH*HDIM*HDIM) + i];
  sc[i] = f2bf(a);
}
// out[s, h*112+e] = (sum_d scores[h,e,d]*qr[s,h,d]) / denom[s,h]  -> bf16
__global__ __launch_bounds__(256) void linout_k(const unsigned short* __restrict__ qr,
    const unsigned short* __restrict__ scores, const float* __restrict__ denom,
    unsigned short* __restrict__ out)
{
  const int s0 = blockIdx.x*64, h = blockIdx.y;
  __shared__ unsigned short sc[112][120];
  __shared__ unsigned short qt[64][120];
  for (int li = threadIdx.x; li < 12544; li += 256)
    sc[li/112][li%112] = scores[(size_t)h*12544 + li];
  for (int li = threadIdx.x; li < 7168; li += 256)
    qt[li/112][li%112] = qr[(size_t)(s0 + li/112)*DIMC + h*HDIM + li%112];
  __syncthreads();
  const int ts = threadIdx.x >> 4, te = threadIdx.x & 15;
  float acc[4][7] = {};
  for (int d = 0; d < HDIM; ++d){
    float qv[4], sv[7];
    #pragma unroll
    for (int a = 0; a < 4; ++a) qv[a] = bf2f(qt[ts*4+a][d]);
    #pragma unroll
    for (int b = 0; b < 7; ++b) sv[b] = bf2f(sc[te*7+b][d]);
    #pragma unroll
    for (int a = 0; a < 4; ++a)
      #pragma unroll
      for (int b = 0; b < 7; ++b) acc[a][b] += qv[a]*sv[b];
  }
  #pragma unroll
  for (int a = 0; a < 4; ++a){
    int sl = s0 + ts*4 + a;
    float dn = 1.f / denom[(size_t)sl*NH + h];
    #pragma unroll
    for (int b = 0; b < 7; ++b)
      out[(size_t)sl*DIMC + h*HDIM + te*7+b] = f2bf(acc[a][b]*dn);
  }
}

// ---------------- fused cross-attention, MFMA (300 keys, head dim 112 padded to 128) ----
__global__ __launch_bounds__(256) void xattn_k(
    const unsigned short* __restrict__ q,   // S x DIM bf16 (rms-normed)
    const unsigned short* __restrict__ k2,  // ENCT x DIM bf16 (rms-normed)
    const unsigned short* __restrict__ v2,  // ENCT x DIM bf16
    unsigned short* __restrict__ outb)      // S x DIM bf16
{
  const int h = blockIdx.y;
  const int w = threadIdx.x >> 6, lane = threadIdx.x & 63;
  const int l16 = lane & 15, lk = lane >> 4;
  const float scale = 0.09449111825230679f;   // 1/sqrt(112)

  __shared__ __align__(16) unsigned short Kl[64][136];
  __shared__ __align__(16) unsigned short Vl[112][72];
  __shared__ __align__(16) unsigned short Pl[4][16][72];

  bf16x8 qf[4];
  const unsigned short* qbase = q + (size_t)(blockIdx.x*64 + w*16 + l16)*DIMC + h*HDIM;
  #pragma unroll
  for (int c = 0; c < 4; ++c){
    int d0 = c*32 + lk*8;
    bf16x8 z = {};
    qf[c] = (d0 < HDIM) ? *reinterpret_cast<const bf16x8*>(qbase + d0) : z;
  }

  f32x4 lg[5][4] = {};
  #pragma unroll
  for (int c = 0; c < 5; ++c){
    const int kbase = c*64;
    const int nk = (c == 4) ? (ENCT - 256) : 64;
    __syncthreads();
    #pragma unroll
    for (int it = 0; it < 4; ++it){
      int li = it*256 + threadIdx.x;
      int key = li >> 4, d0 = (li & 15) << 3;
      uint4 val = make_uint4(0u,0u,0u,0u);
      if (key < nk && d0 < HDIM)
        val = *reinterpret_cast<const uint4*>(k2 + (size_t)(kbase+key)*DIMC + h*HDIM + d0);
      *reinterpret_cast<uint4*>(&Kl[key][d0]) = val;
    }
    __syncthreads();
    #pragma unroll
    for (int nt = 0; nt < 4; ++nt){
      #pragma unroll
      for (int ks = 0; ks < 4; ++ks){
        bf16x8 kf = *reinterpret_cast<const bf16x8*>(&Kl[nt*16 + l16][ks*32 + lk*8]);
        lg[c][nt] = __builtin_amdgcn_mfma_f32_16x16x32_bf16(qf[ks], kf, lg[c][nt], 0, 0, 0);
      }
    }
  }

  float mx[4] = {-3e38f, -3e38f, -3e38f, -3e38f};
  #pragma unroll
  for (int c = 0; c < 5; ++c)
    #pragma unroll
    for (int nt = 0; nt < 4; ++nt){
      bool valid = (c*64 + nt*16 + l16) < ENCT;
      #pragma unroll
      for (int r = 0; r < 4; ++r){
        float v = valid ? lg[c][nt][r]*scale : -3e38f;
        lg[c][nt][r] = v;
        mx[r] = fmaxf(mx[r], v);
      }
    }
  #pragma unroll
  for (int o = 1; o < 16; o <<= 1)
    #pragma unroll
    for (int r = 0; r < 4; ++r) mx[r] = fmaxf(mx[r], __shfl_xor(mx[r], o));
  float sm[4] = {0.f, 0.f, 0.f, 0.f};
  #pragma unroll
  for (int c = 0; c < 5; ++c)
    #pragma unroll
    for (int nt = 0; nt < 4; ++nt)
      #pragma unroll
      for (int r = 0; r < 4; ++r){
        float e = __expf(lg[c][nt][r] - mx[r]);
        lg[c][nt][r] = e;
        sm[r] += e;
      }
  #pragma unroll
  for (int o = 1; o < 16; o <<= 1)
    #pragma unroll
    for (int r = 0; r < 4; ++r) sm[r] += __shfl_xor(sm[r], o);
  float inv[4];
  #pragma unroll
  for (int r = 0; r < 4; ++r) inv[r] = 1.f / sm[r];

  f32x4 oacc[7] = {};
  #pragma unroll
  for (int c = 0; c < 5; ++c){
    const int kbase = c*64;
    const int nk = (c == 4) ? (ENCT - 256) : 64;
    __syncthreads();
    #pragma unroll
    for (int it = 0; it < 4; ++it){
      int li = it*256 + threadIdx.x;
      if (li < 896){
        int key = li/14, d0 = (li%14)*8;
        if (key < nk){
          bf16x8 vv = *reinterpret_cast<const bf16x8*>(v2 + (size_t)(kbase+key)*DIMC + h*HDIM + d0);
          #pragma unroll
          for (int j = 0; j < 8; ++j) Vl[d0+j][key] = (unsigned short)vv[j];
        } else {
          #pragma unroll
          for (int j = 0; j < 8; ++j) Vl[d0+j][key] = 0;
        }
      }
    }
    #pragma unroll
    for (int nt = 0; nt < 4; ++nt)
      #pragma unroll
      for (int r = 0; r < 4; ++r)
        Pl[w][lk*4 + r][nt*16 + l16] = f2bf(lg[c][nt][r]);
    __syncthreads();
    #pragma unroll
    for (int ks = 0; ks < 2; ++ks){
      bf16x8 pf = *reinterpret_cast<const bf16x8*>(&Pl[w][l16][ks*32 + lk*8]);
      #pragma unroll
      for (int n = 0; n < 7; ++n){
        bf16x8 vf = *reinterpret_cast<const bf16x8*>(&Vl[n*16 + l16][ks*32 + lk*8]);
        oacc[n] = __builtin_amdgcn_mfma_f32_16x16x32_bf16(pf, vf, oacc[n], 0, 0, 0);
      }
    }
  }

  const int orow = blockIdx.x*64 + w*16 + lk*4;
  #pragma unroll
  for (int n = 0; n < 7; ++n)
    #pragma unroll
    for (int r = 0; r < 4; ++r)
      outb[(size_t)(orow + r)*DIMC + h*HDIM + n*16 + l16] = f2bf(oacc[n][r]*inv[r]);
}

// ---------------- depthwise 3x3 + bias + GLU(silu), 2 channels/thread ----------------
__global__ __launch_bounds__(256) void dw_k(const unsigned short* __restrict__ y1,
    const float* __restrict__ dw, const float* __restrict__ db, unsigned short* __restrict__ y2)
{
  int c = (blockIdx.y*256 + threadIdx.x)*2;
  if (c >= HID1) return;
  int pos = blockIdx.x;
  int f = pos/448, r = pos%448, hh = r/28, ww = r%28;
  float2 ba = *reinterpret_cast<const float2*>(db + c);
  float2 bg = *reinterpret_cast<const float2*>(db + c + HID1);
  float da0 = ba.x, da1 = ba.y, dg0 = bg.x, dg1 = bg.y;
  #pragma unroll
  for (int dy = 0; dy < 3; ++dy){
    int y = hh+dy-1; if ((unsigned)y >= 16u) continue;
    #pragma unroll
    for (int dx = 0; dx < 3; ++dx){
      int x = ww+dx-1; if ((unsigned)x >= 28u) continue;
      size_t base = ((size_t)(f*16+y)*28 + x)*HID2;
      int widx = (dy*3+dx)*HID2;
      unsigned int a01 = *reinterpret_cast<const unsigned int*>(y1 + base + c);
      unsigned int g01 = *reinterpret_cast<const unsigned int*>(y1 + base + c + HID1);
      float2 wa = *reinterpret_cast<const float2*>(dw + widx + c);
      float2 wg = *reinterpret_cast<const float2*>(dw + widx + c + HID1);
      da0 += bf2f((unsigned short)(a01 & 0xffffu))*wa.x;
      da1 += bf2f((unsigned short)(a01 >> 16))*wa.y;
      dg0 += bf2f((unsigned short)(g01 & 0xffffu))*wg.x;
      dg1 += bf2f((unsigned short)(g01 >> 16))*wg.y;
    }
  }
  float s0 = dg0 / (1.f + __expf(-dg0));
  float s1 = dg1 / (1.f + __expf(-dg1));
  unsigned int o = (unsigned int)f2bf(da0*s0) | ((unsigned int)f2bf(da1*s1) << 16);
  *reinterpret_cast<unsigned int*>(y2 + (size_t)pos*HID1 + c) = o;
}

// ---------------- final: out = x2 + g_mlp*(y3 + tc) ----------------
__global__ void final_k(const float* __restrict__ x2, const unsigned short* __restrict__ y3,
    const float* __restrict__ tc, const float* __restrict__ mods, float* __restrict__ out)
{
  int i = blockIdx.x*256 + threadIdx.x;
  if (i >= SD) return;
  int d = i % DIMC;
  out[i] = x2[i] + mods[5*DIMC + d]*(bf2f(y3[i]) + tc[i]);
}

extern "C" void kernel_launch(void* const* d_in, const int* in_sizes, int n_in,
                              void* d_out, int out_size, void* d_ws, size_t ws_size,
                              hipStream_t stream)
{
  const float* hid   = (const float*)d_in[0];
  const float* enc   = (const float*)d_in[1];
  const float* tstep = (const float*)d_in[2];
  const float* fcos  = (const float*)d_in[3];
  const float* fsin  = (const float*)d_in[4];
  const float* sst   = (const float*)d_in[5];
  const float *a1_qw=(const float*)d_in[6],  *a1_qb=(const float*)d_in[7];
  const float *a1_kw=(const float*)d_in[8],  *a1_kb=(const float*)d_in[9];
  const float *a1_vw=(const float*)d_in[10], *a1_vb=(const float*)d_in[11];
  const float *a1_nq=(const float*)d_in[12], *a1_nk=(const float*)d_in[13];
  const float *a1_ow=(const float*)d_in[14], *a1_ob=(const float*)d_in[15];
  const float *a2_qw=(const float*)d_in[16], *a2_qb=(const float*)d_in[17];
  const float *a2_kw=(const float*)d_in[18], *a2_kb=(const float*)d_in[19];
  const float *a2_vw=(const float*)d_in[20], *a2_vb=(const float*)d_in[21];
  const float *a2_nq=(const float*)d_in[22], *a2_nk=(const float*)d_in[23];
  const float *a2_ow=(const float*)d_in[24], *a2_ob=(const float*)d_in[25];
  const float *ff_inv_w=(const float*)d_in[26], *ff_inv_b=(const float*)d_in[27];
  const float *ff_dw=(const float*)d_in[28], *ff_db=(const float*)d_in[29];
  const float *ff_pw=(const float*)d_in[30];
  const float *ff_tw=(const float*)d_in[31];
  float* out = (float*)d_out;

  // ---- workspace plan (~211 MB total; all sizes 256-multiple) ----
  const size_t SLOTB = (size_t)SD*2;        // 16,056,320 B  (one bf16 S x DIM slot)
  char* ws = (char*)d_ws;
  size_t off = 0;
  auto alloc = [&](size_t n){ void* p = ws + off; off += (n + 255) & ~(size_t)255; return p; };

  char* P = (char*)alloc(7*SLOTB);          // 7 bf16 activation slots (112.4 MB)
  float* x1    = (float*)alloc((size_t)SD*4);     // fp32 residual (32.1 MB)
  unsigned short* nh2b = (unsigned short*)alloc(SLOTB); // MUST follow x1 (y2b spans both)
  float* x2    = (float*)alloc((size_t)SD*4);
  float* k2lin = (float*)alloc((size_t)ENCT*DIMC*4);
  unsigned short* k2b = (unsigned short*)alloc((size_t)ENCT*DIMC*2);
  unsigned short* v2b = (unsigned short*)alloc((size_t)ENCT*DIMC*2);
  unsigned short* encb = (unsigned short*)alloc((size_t)ENCT*DIMC*2);
  float* modsb = (float*)alloc(6*DIMC*4);
  float* ksum  = (float*)alloc(DIMC*4);
  float* kpart = (float*)alloc((size_t)28*DIMC*4);
  float* denom = (float*)alloc((size_t)STOK*NH*4);
  float* spart = (float*)alloc((size_t)8*NH*HDIM*HDIM*4);
  unsigned short* scorb = (unsigned short*)alloc((size_t)NH*HDIM*HDIM*2);

  // P-slot aliases (lifetimes verified disjoint)
  unsigned short* P0 = (unsigned short*)P;                 // nhb | y1b[0:] | y3b
  unsigned short* P1 = (unsigned short*)(P + 1*SLOTB);     // qb | lob | y1b | tc[0:]
  unsigned short* P2 = (unsigned short*)(P + 2*SLOTB);     // kb | x1b | y1b | tc[1:]
  unsigned short* P3 = (unsigned short*)(P + 3*SLOTB);     // vb | q2b | y1b
  unsigned short* P4 = (unsigned short*)(P + 4*SLOTB);     // qrb | crb | y1b
  unsigned short* P5 = (unsigned short*)(P + 5*SLOTB);     // krb | y1b
  unsigned short* W  = (unsigned short*)(P + 6*SLOTB);     // serial Bt staging (16 MB)
  unsigned short* nhb = P0;
  unsigned short* y1b = P0;                                // 96.34 MB = slots 0..5 exactly
  unsigned short* y2b = (unsigned short*)x1;               // 48.17 MB = x1 + nh2b exactly
  unsigned short* y3b = P0;
  float* tc = (float*)(P + 1*SLOTB);                       // 32.1 MB = slots 1..2

  auto cvt = [&](const float* s, unsigned short* d, size_t n){
    int n4 = (int)(n/4);
    cvt_k<<<dim3((n4+255)/256), 256, 0, stream>>>((const float4*)s, (ushort4*)d, n4);
  };
  // transpose-convert: [rows x nc slice] fp32 -> [ncPad x rows] bf16 (zero pad)
  auto cvtT = [&](const float* s, int rows, int ldsrc, int c0, int nc, int ncPad){
    cvt_t_k<<<dim3(ncPad/32, rows/32), 256, 0, stream>>>(s, W, rows, ldsrc, c0, nc);
  };
  auto gemm_grid = [&](int M, int Npad){ return dim3(Npad/128, (M+127)/128); };

  mods_k<<<dim3((6*DIMC+255)/256), 256, 0, stream>>>(sst, tstep, modsb);
  cvt(enc, encb, (size_t)ENCT*DIMC);

  // ---- attn1 ----
  ln_mod_k<<<dim3(STOK), 256, 0, stream>>>(hid, modsb, 0, 1, nhb);
  dim3 gMN = gemm_grid(STOK, 2304);
  cvtT(a1_qw, DIMC, DIMC, 0, DIMC, 2304);
  gemm_bt<2><<<gMN, 256, 0, stream>>>(nhb, W, a1_qb, nullptr, P1, nullptr, nullptr, STOK, DIMC, DIMC, DIMC);
  cvtT(a1_kw, DIMC, DIMC, 0, DIMC, 2304);
  gemm_bt<2><<<gMN, 256, 0, stream>>>(nhb, W, a1_kb, nullptr, P2, nullptr, nullptr, STOK, DIMC, DIMC, DIMC);
  cvtT(a1_vw, DIMC, DIMC, 0, DIMC, 2304);
  gemm_bt<2><<<gMN, 256, 0, stream>>>(nhb, W, a1_vb, nullptr, P3, nullptr, nullptr, STOK, DIMC, DIMC, DIMC);
  rms_bf_k<1,1><<<dim3(STOK), 256, 0, stream>>>(P1, a1_nq, fcos, fsin, P4);
  rms_bf_k<1,1><<<dim3(STOK), 256, 0, stream>>>(P2, a1_nk, fcos, fsin, P5);
  colsum_k<<<dim3(9, 28), 256, 0, stream>>>(P2, kpart);
  ksumred_k<<<dim3(9), 256, 0, stream>>>(kpart, ksum);
  denom_k<<<dim3(STOK), 256, 0, stream>>>(P1, ksum, denom);
  scores_k<<<dim3(NH, 8), 256, 0, stream>>>(P3, P5, spart);
  scred_k<<<dim3((NH*HDIM*HDIM+255)/256), 256, 0, stream>>>(spart, scorb);
  linout_k<<<dim3(56, NH), 256, 0, stream>>>(P4, scorb, denom, P1);   // lob -> P1
  cvtT(a1_ow, DIMC, DIMC, 0, DIMC, 2304);
  gemm_bt<3><<<gMN, 256, 0, stream>>>(P1, W, a1_ob, x1, P2, hid, modsb + 2*DIMC, STOK, DIMC, DIMC, DIMC);

  // ---- cross attn ----
  cvtT(a2_qw, DIMC, DIMC, 0, DIMC, 2304);
  gemm_bt<2><<<gMN, 256, 0, stream>>>(P2, W, a2_qb, nullptr, P3, nullptr, nullptr, STOK, DIMC, DIMC, DIMC);
  dim3 gENC = gemm_grid(ENCT, 2304);
  cvtT(a2_kw, DIMC, DIMC, 0, DIMC, 2304);
  gemm_bt<0><<<gENC, 256, 0, stream>>>(encb, W, a2_kb, k2lin, nullptr, nullptr, nullptr, ENCT, DIMC, DIMC, DIMC);
  cvtT(a2_vw, DIMC, DIMC, 0, DIMC, 2304);
  gemm_bt<2><<<gENC, 256, 0, stream>>>(encb, W, a2_vb, nullptr, v2b, nullptr, nullptr, ENCT, DIMC, DIMC, DIMC);
  rms_bf_k<0,0><<<dim3(STOK), 256, 0, stream>>>(P3, a2_nq, nullptr, nullptr, nullptr);
  rms_f32_k<<<dim3(ENCT), 256, 0, stream>>>(k2lin, a2_nk);
  cvt(k2lin, k2b, (size_t)ENCT*DIMC);
  xattn_k<<<dim3(STOK/64, NH), 256, 0, stream>>>(P3, k2b, v2b, P4);   // crb -> P4
  cvtT(a2_ow, DIMC, DIMC, 0, DIMC, 2304);
  gemm_bt<4><<<gMN, 256, 0, stream>>>(P4, W, a2_ob, x2, nullptr, x1, nullptr, STOK, DIMC, DIMC, DIMC);

  // ---- FF ----
  ln_mod_k<<<dim3(STOK), 256, 0, stream>>>(x2, modsb, 3, 4, nh2b);
  for (int q = 0; q < 4; ++q){                 // ff_inv in 4 column slices of 3360
    int c0 = q*3360;
    cvtT(ff_inv_w, DIMC, HID2, c0, 3360, 3456);
    gemm_bt<1><<<gemm_grid(STOK, 3456), 256, 0, stream>>>(nh2b, W, ff_inv_b + c0, nullptr, y1b + c0,
                                                          nullptr, nullptr, STOK, 3360, DIMC, HID2);
  }
  dw_k<<<dim3(STOK, 14), 256, 0, stream>>>(y1b, ff_dw, ff_db, y2b);
  for (int hh = 0; hh < 2; ++hh){              // point conv in 2 column slices of 1120
    int c0 = hh*1120;
    cvtT(ff_pw, HID1, DIMC, c0, 1120, 1152);
    gemm_bt<2><<<gemm_grid(STOK, 1152), 256, 0, stream>>>(y2b, W, nullptr, nullptr, y3b + c0,
                                                          nullptr, nullptr, STOK, 1120, HID1, DIMC);
  }
  // temporal conv: tc = y3 @ W1 (center) then shifted accumulates
  cvtT(ff_tw + (size_t)DD, DIMC, DIMC, 0, DIMC, 2304);
  gemm_bt<0><<<gMN, 256, 0, stream>>>(y3b, W, nullptr, tc, nullptr, nullptr, nullptr, STOK, DIMC, DIMC, DIMC);
  dim3 gT = gemm_grid(3136, 2304);
  cvtT(ff_tw, DIMC, DIMC, 0, DIMC, 2304);
  gemm_bt<5><<<gT, 256, 0, stream>>>(y3b, W, nullptr, tc + (size_t)448*DIMC, nullptr, nullptr, nullptr, 3136, DIMC, DIMC, DIMC);
  cvtT(ff_tw + (size_t)2*DD, DIMC, DIMC, 0, DIMC, 2304);
  gemm_bt<5><<<gT, 256, 0, stream>>>(y3b + (size_t)448*DIMC, W, nullptr, tc, nullptr, nullptr, nullptr, 3136, DIMC, DIMC, DIMC);

  // out = x2 + g_mlp*(y3 + tc)
  final_k<<<dim3((SD+255)/256), 256, 0, stream>>>(x2, y3b, tc, modsb, out);
}

// Round 5
// 2039.771 us; speedup vs baseline: 6.9080x; 1.1157x over previous
//
#include <hip/hip_runtime.h>

#define DIMC 2240
#define STOK 3584
#define ENCT 300
#define NH   20
#define HDIM 112
#define HID1 6720
#define HID2 13440
#define DD   (2240*2240)
#define SD   (3584*2240)

typedef short bf16x8 __attribute__((ext_vector_type(8)));   // guide-verified operand type
typedef float f32x4  __attribute__((ext_vector_type(4)));

__device__ __forceinline__ unsigned short f2bf(float f){
  unsigned int u = __float_as_uint(f);
  u += 0x7fffu + ((u >> 16) & 1u);          // RNE
  return (unsigned short)(u >> 16);
}
__device__ __forceinline__ float bf2f(unsigned short h){
  return __uint_as_float(((unsigned int)h) << 16);
}
__device__ __forceinline__ void gl_lds16(const unsigned short* g, unsigned short* l){
  __builtin_amdgcn_global_load_lds(
      (const __attribute__((address_space(1))) unsigned int*)(const void*)g,
      (__attribute__((address_space(3))) unsigned int*)(void*)l, 16, 0, 0);
}

// ---------------- fp32 -> bf16 convert (flat) ----------------
__global__ void cvt_k(const float4* __restrict__ src, ushort4* __restrict__ dst, int n4){
  int i = blockIdx.x*256 + threadIdx.x;
  if (i < n4){
    float4 v = src[i];
    ushort4 o; o.x = f2bf(v.x); o.y = f2bf(v.y); o.z = f2bf(v.z); o.w = f2bf(v.w);
    dst[i] = o;
  }
}

// ------- fp32 (rows x cols slice) -> bf16 TRANSPOSED [ncPad][rows], zero-padded -------
__global__ __launch_bounds__(256) void cvt_t_k(const float* __restrict__ src,
    unsigned short* __restrict__ dst, int rows, int ldsrc, int c0, int nc){
  __shared__ float tile[32][33];
  const int tx = threadIdx.x & 31, ty = threadIdx.x >> 5;   // ty 0..7
  const int colBase = blockIdx.x*32;
  #pragma unroll
  for (int i = 0; i < 4; ++i){
    int rr = blockIdx.y*32 + ty + i*8;
    int cc = colBase + tx;
    tile[ty + i*8][tx] = (cc < nc) ? src[(size_t)rr*ldsrc + c0 + cc] : 0.f;
  }
  __syncthreads();
  #pragma unroll
  for (int i = 0; i < 4; ++i){
    int n = colBase + ty + i*8;          // < ncPad by grid
    int k = blockIdx.y*32 + tx;
    dst[(size_t)n*rows + k] = f2bf(tile[tx][ty + i*8]);
  }
}

// ---------------- mods = scale_shift_table + timestep ----------------
__global__ void mods_k(const float* __restrict__ sst, const float* __restrict__ ts, float* __restrict__ mods){
  int i = blockIdx.x*256 + threadIdx.x;
  if (i < 6*DIMC) mods[i] = sst[i] + ts[i];
}

// ---------------- LayerNorm * (1+sc) + sh -> bf16 ----------------
__global__ __launch_bounds__(256) void ln_mod_k(const float* __restrict__ x,
    const float* __restrict__ mods, int shj, int scj, unsigned short* __restrict__ out)
{
  const int s = blockIdx.x;
  const float* row = x + (size_t)s*DIMC;
  const float* sh = mods + shj*DIMC;
  const float* sc = mods + scj*DIMC;
  float sum = 0.f, sq = 0.f;
  for (int d = threadIdx.x; d < DIMC; d += 256){ float v = row[d]; sum += v; sq += v*v; }
  #pragma unroll
  for (int o = 32; o; o >>= 1){ sum += __shfl_down(sum, o); sq += __shfl_down(sq, o); }
  __shared__ float sA[4], sB[4];
  int w = threadIdx.x >> 6, l = threadIdx.x & 63;
  if (!l){ sA[w] = sum; sB[w] = sq; }
  __syncthreads();
  sum = sA[0]+sA[1]+sA[2]+sA[3];
  sq  = sB[0]+sB[1]+sB[2]+sB[3];
  float mean = sum * (1.f/DIMC);
  float rs = rsqrtf(sq*(1.f/DIMC) - mean*mean + 1e-6f);
  unsigned short* orow = out + (size_t)s*DIMC;
  for (int d = threadIdx.x; d < DIMC; d += 256){
    float v = (row[d]-mean)*rs*(1.f + sc[d]) + sh[d];
    orow[d] = f2bf(v);
  }
}

// ---------------- RMS on bf16 rows (optional ReLU / RoPE) ----------------
template<int RELU, int ROPE>
__global__ __launch_bounds__(256) void rms_bf_k(unsigned short* __restrict__ x, const float* __restrict__ nw,
    const float* __restrict__ cosb, const float* __restrict__ sinb, unsigned short* __restrict__ xr)
{
  const int s = blockIdx.x;
  unsigned short* row = x + (size_t)s*DIMC;
  float sq = 0.f;
  for (int d = threadIdx.x; d < DIMC; d += 256){ float v = bf2f(row[d]); sq += v*v; }
  #pragma unroll
  for (int o = 32; o; o >>= 1) sq += __shfl_down(sq, o);
  __shared__ float sB[4];
  int w = threadIdx.x >> 6, l = threadIdx.x & 63;
  if (!l) sB[w] = sq;
  __syncthreads();
  sq = sB[0]+sB[1]+sB[2]+sB[3];
  float rs = rsqrtf(sq*(1.f/DIMC) + 1e-5f);
  if constexpr (!ROPE){
    for (int d = threadIdx.x; d < DIMC; d += 256){
      float v = bf2f(row[d])*rs*nw[d];
      if (RELU) v = fmaxf(v, 0.f);
      row[d] = f2bf(v);
    }
  } else {
    for (int p = threadIdx.x; p < DIMC/2; p += 256){
      int d0 = 2*p, d1 = d0+1;
      float v0 = bf2f(row[d0])*rs*nw[d0];
      float v1 = bf2f(row[d1])*rs*nw[d1];
      if (RELU){ v0 = fmaxf(v0,0.f); v1 = fmaxf(v1,0.f); }
      row[d0] = f2bf(v0); row[d1] = f2bf(v1);
      int j0 = d0 % HDIM;                       // pairs stay within a head (112 even)
      float c  = cosb[(size_t)s*HDIM + j0];     // cos[0::2]
      float sn = sinb[(size_t)s*HDIM + j0 + 1]; // sin[1::2]
      xr[(size_t)s*DIMC + d0] = f2bf(v0*c - v1*sn);
      xr[(size_t)s*DIMC + d1] = f2bf(v0*sn + v1*c);
    }
  }
}
// ---------------- RMS on fp32 rows (in place, no relu/rope) ----------------
__global__ __launch_bounds__(256) void rms_f32_k(float* __restrict__ x, const float* __restrict__ nw)
{
  const int s = blockIdx.x;
  float* row = x + (size_t)s*DIMC;
  float sq = 0.f;
  for (int d = threadIdx.x; d < DIMC; d += 256){ float v = row[d]; sq += v*v; }
  #pragma unroll
  for (int o = 32; o; o >>= 1) sq += __shfl_down(sq, o);
  __shared__ float sB[4];
  int w = threadIdx.x >> 6, l = threadIdx.x & 63;
  if (!l) sB[w] = sq;
  __syncthreads();
  sq = sB[0]+sB[1]+sB[2]+sB[3];
  float rs = rsqrtf(sq*(1.f/DIMC) + 1e-5f);
  for (int d = threadIdx.x; d < DIMC; d += 256) row[d] = row[d]*rs*nw[d];
}

// ------- m97-structure bf16 MFMA GEMM: C = A(MxK) @ Bt^T, Bt is [Npad][K] (N-major) -----
template<int EPI>
__global__ __launch_bounds__(256) void gemm_bt(
  const unsigned short* __restrict__ A, const unsigned short* __restrict__ Bt,
  const float* __restrict__ bias, float* __restrict__ Cf, unsigned short* __restrict__ Cb,
  const float* __restrict__ res, const float* __restrict__ gate,
  int M, int N, int K, int ldc)
{
  __shared__ __align__(16) unsigned short Al[128*32];
  __shared__ __align__(16) unsigned short Bl[128*32];
  // bijective XCD-aware swizzle (m204)
  const int gx = gridDim.x;
  const int nwg = gx*gridDim.y;
  const int orig = blockIdx.y*gx + blockIdx.x;
  const int qq = nwg >> 3, rr = nwg & 7;
  const int xcd = orig & 7, li = orig >> 3;
  const int wg = (xcd < rr ? xcd*(qq+1) : rr*(qq+1) + (xcd-rr)*qq) + li;
  const int m0 = (wg / gx)*128, n0 = (wg % gx)*128;

  const int t = threadIdx.x;
  const int lane = t & 63, w = t >> 6;
  const int wr = w >> 1, wc = w & 1;
  const int l16 = lane & 15, lk = lane >> 4;

  const int lrow = lane >> 2;          // 0..15
  const int lcol = (lane & 3) << 3;    // 0,8,16,24
  const int arow0 = m0 + w*32 + lrow;
  const int brow0 = n0 + w*32 + lrow;
  const unsigned short* Ap0 = A + (size_t)min(arow0,      M-1)*K + lcol;
  const unsigned short* Ap1 = A + (size_t)min(arow0 + 16, M-1)*K + lcol;
  const unsigned short* Bp0 = Bt + (size_t)(brow0     )*K + lcol;
  const unsigned short* Bp1 = Bt + (size_t)(brow0 + 16)*K + lcol;
  unsigned short* Ad0 = Al + (w*2+0)*512;
  unsigned short* Ad1 = Al + (w*2+1)*512;
  unsigned short* Bd0 = Bl + (w*2+0)*512;
  unsigned short* Bd1 = Bl + (w*2+1)*512;

  f32x4 acc[4][4] = {};
  for (int k0 = 0; k0 < K; k0 += 32){
    __syncthreads();
    gl_lds16(Ap0 + k0, Ad0);
    gl_lds16(Ap1 + k0, Ad1);
    gl_lds16(Bp0 + k0, Bd0);
    gl_lds16(Bp1 + k0, Bd1);
    __syncthreads();
    bf16x8 af[4], bfr[4];
    #pragma unroll
    for (int m = 0; m < 4; ++m)
      af[m] = *reinterpret_cast<const bf16x8*>(Al + (wr*64 + m*16 + l16)*32 + lk*8);
    #pragma unroll
    for (int n = 0; n < 4; ++n)
      bfr[n] = *reinterpret_cast<const bf16x8*>(Bl + (wc*64 + n*16 + l16)*32 + lk*8);
    #pragma unroll
    for (int m = 0; m < 4; ++m)
      #pragma unroll
      for (int n = 0; n < 4; ++n)
        acc[m][n] = __builtin_amdgcn_mfma_f32_16x16x32_bf16(af[m], bfr[n], acc[m][n], 0, 0, 0);
  }

  const int rb = m0 + wr*64 + lk*4;   // C/D: col = lane&15, row = (lane>>4)*4 + reg
  const int cb = n0 + wc*64 + l16;
  #pragma unroll
  for (int m = 0; m < 4; ++m){
    #pragma unroll
    for (int r = 0; r < 4; ++r){
      int row = rb + m*16 + r;
      if (row >= M) continue;
      #pragma unroll
      for (int n = 0; n < 4; ++n){
        int col = cb + n*16;
        if (col >= N) continue;
        float v = acc[m][n][r];
        size_t idx = (size_t)row*ldc + col;
        float bv = bias ? bias[col] : 0.f;
        if constexpr (EPI == 0){ Cf[idx] = v + bv; }
        else if constexpr (EPI == 1){ float u = v + bv; Cb[idx] = f2bf(u / (1.f + __expf(-u))); }
        else if constexpr (EPI == 2){ Cb[idx] = f2bf(v + bv); }
        else if constexpr (EPI == 3){ float u = res[idx] + gate[col]*(v + bv); Cf[idx] = u; Cb[idx] = f2bf(u); }
        else if constexpr (EPI == 4){ Cf[idx] = res[idx] + v + bv; }
        else { Cf[idx] += v; }
      }
    }
  }
}

// ---------------- linear attention helpers ----------------
__global__ void colsum_k(const unsigned short* __restrict__ k, float* __restrict__ kpart){
  int d = blockIdx.x*256 + threadIdx.x;
  if (d >= DIMC) return;
  int ch = blockIdx.y, s0 = ch*128;
  float acc = 0.f;
  for (int s = s0; s < s0+128; ++s) acc += bf2f(k[(size_t)s*DIMC + d]);
  kpart[(size_t)ch*DIMC + d] = acc;
}
__global__ void ksumred_k(const float* __restrict__ kpart, float* __restrict__ ksum){
  int d = blockIdx.x*256 + threadIdx.x;
  if (d >= DIMC) return;
  float a = 0.f;
  for (int c = 0; c < 28; ++c) a += kpart[(size_t)c*DIMC + d];
  ksum[d] = a;
}
__global__ __launch_bounds__(256) void denom_k(const unsigned short* __restrict__ q,
    const float* __restrict__ ksum, float* __restrict__ denom)
{
  int s = blockIdx.x; int w = threadIdx.x >> 6, l = threadIdx.x & 63;
  for (int h = w; h < NH; h += 4){
    const unsigned short* qb = q + (size_t)s*DIMC + h*HDIM;
    const float* kb = ksum + h*HDIM;
    float v = bf2f(qb[l])*kb[l];
    if (l < 48) v += bf2f(qb[64+l])*kb[64+l];
    #pragma unroll
    for (int o = 32; o; o >>= 1) v += __shfl_down(v, o);
    if (!l) denom[s*NH + h] = v + 1e-15f;
  }
}

// -------- MFMA scores: part[ch][h][e][d] = sum_{s in 128-chunk} V[s,h,e]*Kr[s,h,d] -----
// grid (NH, 28), 256 thr. LDS: transposed [dim][token] tiles, XOR-swizzled token idx.
#define SLSC 136
__device__ __forceinline__ int sc_idx(int e, int s){
  return e*SLSC + (s ^ (((e >> 3) & 7) << 3));
}
__global__ __launch_bounds__(256) void scores_k(const unsigned short* __restrict__ v,
    const unsigned short* __restrict__ kr, float* __restrict__ part)
{
  const int h = blockIdx.x, ch = blockIdx.y;
  __shared__ __align__(16) unsigned short Vt[112*SLSC];
  __shared__ __align__(16) unsigned short Kt[112*SLSC];
  const int t = threadIdx.x, lane = t & 63, w = t >> 6;
  const int l16 = lane & 15, lk = lane >> 4;
  const int sbase = ch*128;

  for (int p = t; p < 1792; p += 256){       // 128 tokens x 14 dim-octets
    int s = p / 14, oc = (p % 14) * 8;
    bf16x8 vv = *reinterpret_cast<const bf16x8*>(v  + (size_t)(sbase+s)*DIMC + h*HDIM + oc);
    bf16x8 kk = *reinterpret_cast<const bf16x8*>(kr + (size_t)(sbase+s)*DIMC + h*HDIM + oc);
    #pragma unroll
    for (int j = 0; j < 8; ++j){
      Vt[sc_idx(oc+j, s)] = (unsigned short)vv[j];
      Kt[sc_idx(oc+j, s)] = (unsigned short)kk[j];
    }
  }
  __syncthreads();

  f32x4 acc[2][7] = {};                      // wave w owns m-tiles {w, w+4}
  #pragma unroll
  for (int ks = 0; ks < 4; ++ks){
    const int sf = ks*32 + lk*8;
    bf16x8 bfrg[7];
    #pragma unroll
    for (int nt = 0; nt < 7; ++nt){
      int d = nt*16 + l16;
      bfrg[nt] = *reinterpret_cast<const bf16x8*>(&Kt[d*SLSC + (sf ^ (((d >> 3) & 7) << 3))]);
    }
    #pragma unroll
    for (int mi = 0; mi < 2; ++mi){
      int mt = w + mi*4;
      if (mt < 7){
        int e = mt*16 + l16;
        bf16x8 afrg = *reinterpret_cast<const bf16x8*>(&Vt[e*SLSC + (sf ^ (((e >> 3) & 7) << 3))]);
        #pragma unroll
        for (int nt = 0; nt < 7; ++nt)
          acc[mi][nt] = __builtin_amdgcn_mfma_f32_16x16x32_bf16(afrg, bfrg[nt], acc[mi][nt], 0, 0, 0);
      }
    }
  }

  float* pout = part + ((size_t)ch*NH + h)*12544;
  #pragma unroll
  for (int mi = 0; mi < 2; ++mi){
    int mt = w + mi*4;
    if (mt >= 7) continue;
    #pragma unroll
    for (int nt = 0; nt < 7; ++nt)
      #pragma unroll
      for (int r = 0; r < 4; ++r)
        pout[(size_t)(mt*16 + lk*4 + r)*HDIM + nt*16 + l16] = acc[mi][nt][r];
  }
}
__global__ void scred_k(const float* __restrict__ part, unsigned short* __restrict__ sc){
  int i = blockIdx.x*256 + threadIdx.x;
  if (i >= NH*HDIM*HDIM) return;
  float a = 0.f;
  #pragma unroll
  for (int c = 0; c < 28; ++c) a += part[(size_t)c*(NH*HDIM*HDIM) + i];
  sc[i] = f2bf(a);
}

// -------- MFMA linout: out[s,h*112+e] = (sum_d scores[h,e,d]*qr[s,h,d]) / denom[s,h] ---
// grid (STOK/64, NH), 256 thr = 4 waves; zero LDS, direct global b128 fragments.
__global__ __launch_bounds__(256) void linout_k(const unsigned short* __restrict__ qr,
    const unsigned short* __restrict__ scores, const float* __restrict__ denom,
    unsigned short* __restrict__ out)
{
  const int h = blockIdx.y;
  const int t = threadIdx.x, lane = t & 63, w = t >> 6;
  const int l16 = lane & 15, lk = lane >> 4;
  const int s0 = blockIdx.x*64 + w*16;
  const unsigned short* qrow = qr + (size_t)(s0 + l16)*DIMC + h*HDIM;
  const unsigned short* sb = scores + (size_t)h*12544;
  f32x4 acc[7] = {};
  #pragma unroll
  for (int ks = 0; ks < 4; ++ks){
    int d0 = ks*32 + lk*8;
    bf16x8 a = {};
    if (d0 < HDIM) a = *reinterpret_cast<const bf16x8*>(qrow + d0);
    #pragma unroll
    for (int nt = 0; nt < 7; ++nt){
      bf16x8 b = {};
      if (d0 < HDIM) b = *reinterpret_cast<const bf16x8*>(sb + (size_t)(nt*16 + l16)*HDIM + d0);
      acc[nt] = __builtin_amdgcn_mfma_f32_16x16x32_bf16(a, b, acc[nt], 0, 0, 0);
    }
  }
  #pragma unroll
  for (int r = 0; r < 4; ++r){
    int s = s0 + lk*4 + r;
    float dn = 1.f / denom[(size_t)s*NH + h];
    #pragma unroll
    for (int nt = 0; nt < 7; ++nt)
      out[(size_t)s*DIMC + h*HDIM + nt*16 + l16] = f2bf(acc[nt][r]*dn);
  }
}

// ---------------- fused cross-attention, MFMA (300 keys, head dim 112 padded to 128) ----
__global__ __launch_bounds__(256) void xattn_k(
    const unsigned short* __restrict__ q,   // S x DIM bf16 (rms-normed)
    const unsigned short* __restrict__ k2,  // ENCT x DIM bf16 (rms-normed)
    const unsigned short* __restrict__ v2,  // ENCT x DIM bf16
    unsigned short* __restrict__ outb)      // S x DIM bf16
{
  const int h = blockIdx.y;
  const int w = threadIdx.x >> 6, lane = threadIdx.x & 63;
  const int l16 = lane & 15, lk = lane >> 4;
  const float scale = 0.09449111825230679f;   // 1/sqrt(112)

  __shared__ __align__(16) unsigned short Kl[64][136];
  __shared__ __align__(16) unsigned short Vl[112][72];
  __shared__ __align__(16) unsigned short Pl[4][16][72];

  bf16x8 qf[4];
  const unsigned short* qbase = q + (size_t)(blockIdx.x*64 + w*16 + l16)*DIMC + h*HDIM;
  #pragma unroll
  for (int c = 0; c < 4; ++c){
    int d0 = c*32 + lk*8;
    bf16x8 z = {};
    qf[c] = (d0 < HDIM) ? *reinterpret_cast<const bf16x8*>(qbase + d0) : z;
  }

  f32x4 lg[5][4] = {};
  #pragma unroll
  for (int c = 0; c < 5; ++c){
    const int kbase = c*64;
    const int nk = (c == 4) ? (ENCT - 256) : 64;
    __syncthreads();
    #pragma unroll
    for (int it = 0; it < 4; ++it){
      int li = it*256 + threadIdx.x;
      int key = li >> 4, d0 = (li & 15) << 3;
      uint4 val = make_uint4(0u,0u,0u,0u);
      if (key < nk && d0 < HDIM)
        val = *reinterpret_cast<const uint4*>(k2 + (size_t)(kbase+key)*DIMC + h*HDIM + d0);
      *reinterpret_cast<uint4*>(&Kl[key][d0]) = val;
    }
    __syncthreads();
    #pragma unroll
    for (int nt = 0; nt < 4; ++nt){
      #pragma unroll
      for (int ks = 0; ks < 4; ++ks){
        bf16x8 kf = *reinterpret_cast<const bf16x8*>(&Kl[nt*16 + l16][ks*32 + lk*8]);
        lg[c][nt] = __builtin_amdgcn_mfma_f32_16x16x32_bf16(qf[ks], kf, lg[c][nt], 0, 0, 0);
      }
    }
  }

  float mx[4] = {-3e38f, -3e38f, -3e38f, -3e38f};
  #pragma unroll
  for (int c = 0; c < 5; ++c)
    #pragma unroll
    for (int nt = 0; nt < 4; ++nt){
      bool valid = (c*64 + nt*16 + l16) < ENCT;
      #pragma unroll
      for (int r = 0; r < 4; ++r){
        float v = valid ? lg[c][nt][r]*scale : -3e38f;
        lg[c][nt][r] = v;
        mx[r] = fmaxf(mx[r], v);
      }
    }
  #pragma unroll
  for (int o = 1; o < 16; o <<= 1)
    #pragma unroll
    for (int r = 0; r < 4; ++r) mx[r] = fmaxf(mx[r], __shfl_xor(mx[r], o));
  float sm[4] = {0.f, 0.f, 0.f, 0.f};
  #pragma unroll
  for (int c = 0; c < 5; ++c)
    #pragma unroll
    for (int nt = 0; nt < 4; ++nt)
      #pragma unroll
      for (int r = 0; r < 4; ++r){
        float e = __expf(lg[c][nt][r] - mx[r]);
        lg[c][nt][r] = e;
        sm[r] += e;
      }
  #pragma unroll
  for (int o = 1; o < 16; o <<= 1)
    #pragma unroll
    for (int r = 0; r < 4; ++r) sm[r] += __shfl_xor(sm[r], o);
  float inv[4];
  #pragma unroll
  for (int r = 0; r < 4; ++r) inv[r] = 1.f / sm[r];

  f32x4 oacc[7] = {};
  #pragma unroll
  for (int c = 0; c < 5; ++c){
    const int kbase = c*64;
    const int nk = (c == 4) ? (ENCT - 256) : 64;
    __syncthreads();
    #pragma unroll
    for (int it = 0; it < 4; ++it){
      int li = it*256 + threadIdx.x;
      if (li < 896){
        int key = li/14, d0 = (li%14)*8;
        if (key < nk){
          bf16x8 vv = *reinterpret_cast<const bf16x8*>(v2 + (size_t)(kbase+key)*DIMC + h*HDIM + d0);
          #pragma unroll
          for (int j = 0; j < 8; ++j) Vl[d0+j][key] = (unsigned short)vv[j];
        } else {
          #pragma unroll
          for (int j = 0; j < 8; ++j) Vl[d0+j][key] = 0;
        }
      }
    }
    #pragma unroll
    for (int nt = 0; nt < 4; ++nt)
      #pragma unroll
      for (int r = 0; r < 4; ++r)
        Pl[w][lk*4 + r][nt*16 + l16] = f2bf(lg[c][nt][r]);
    __syncthreads();
    #pragma unroll
    for (int ks = 0; ks < 2; ++ks){
      bf16x8 pf = *reinterpret_cast<const bf16x8*>(&Pl[w][l16][ks*32 + lk*8]);
      #pragma unroll
      for (int n = 0; n < 7; ++n){
        bf16x8 vf = *reinterpret_cast<const bf16x8*>(&Vl[n*16 + l16][ks*32 + lk*8]);
        oacc[n] = __builtin_amdgcn_mfma_f32_16x16x32_bf16(pf, vf, oacc[n], 0, 0, 0);
      }
    }
  }

  const int orow = blockIdx.x*64 + w*16 + lk*4;
  #pragma unroll
  for (int n = 0; n < 7; ++n)
    #pragma unroll
    for (int r = 0; r < 4; ++r)
      outb[(size_t)(orow + r)*DIMC + h*HDIM + n*16 + l16] = f2bf(oacc[n][r]*inv[r]);
}

// ---------------- depthwise 3x3 + bias + GLU(silu), 2 channels/thread ----------------
__global__ __launch_bounds__(256) void dw_k(const unsigned short* __restrict__ y1,
    const float* __restrict__ dw, const float* __restrict__ db, unsigned short* __restrict__ y2)
{
  int c = (blockIdx.y*256 + threadIdx.x)*2;
  if (c >= HID1) return;
  int pos = blockIdx.x;
  int f = pos/448, r = pos%448, hh = r/28, ww = r%28;
  float2 ba = *reinterpret_cast<const float2*>(db + c);
  float2 bg = *reinterpret_cast<const float2*>(db + c + HID1);
  float da0 = ba.x, da1 = ba.y, dg0 = bg.x, dg1 = bg.y;
  #pragma unroll
  for (int dy = 0; dy < 3; ++dy){
    int y = hh+dy-1; if ((unsigned)y >= 16u) continue;
    #pragma unroll
    for (int dx = 0; dx < 3; ++dx){
      int x = ww+dx-1; if ((unsigned)x >= 28u) continue;
      size_t base = ((size_t)(f*16+y)*28 + x)*HID2;
      int widx = (dy*3+dx)*HID2;
      unsigned int a01 = *reinterpret_cast<const unsigned int*>(y1 + base + c);
      unsigned int g01 = *reinterpret_cast<const unsigned int*>(y1 + base + c + HID1);
      float2 wa = *reinterpret_cast<const float2*>(dw + widx + c);
      float2 wg = *reinterpret_cast<const float2*>(dw + widx + c + HID1);
      da0 += bf2f((unsigned short)(a01 & 0xffffu))*wa.x;
      da1 += bf2f((unsigned short)(a01 >> 16))*wa.y;
      dg0 += bf2f((unsigned short)(g01 & 0xffffu))*wg.x;
      dg1 += bf2f((unsigned short)(g01 >> 16))*wg.y;
    }
  }
  float s0 = dg0 / (1.f + __expf(-dg0));
  float s1 = dg1 / (1.f + __expf(-dg1));
  unsigned int o = (unsigned int)f2bf(da0*s0) | ((unsigned int)f2bf(da1*s1) << 16);
  *reinterpret_cast<unsigned int*>(y2 + (size_t)pos*HID1 + c) = o;
}

// ---------------- final: out = x2 + g_mlp*(y3 + tc) ----------------
__global__ void final_k(const float* __restrict__ x2, const unsigned short* __restrict__ y3,
    const float* __restrict__ tc, const float* __restrict__ mods, float* __restrict__ out)
{
  int i = blockIdx.x*256 + threadIdx.x;
  if (i >= SD) return;
  int d = i % DIMC;
  out[i] = x2[i] + mods[5*DIMC + d]*(bf2f(y3[i]) + tc[i]);
}

extern "C" void kernel_launch(void* const* d_in, const int* in_sizes, int n_in,
                              void* d_out, int out_size, void* d_ws, size_t ws_size,
                              hipStream_t stream)
{
  const float* hid   = (const float*)d_in[0];
  const float* enc   = (const float*)d_in[1];
  const float* tstep = (const float*)d_in[2];
  const float* fcos  = (const float*)d_in[3];
  const float* fsin  = (const float*)d_in[4];
  const float* sst   = (const float*)d_in[5];
  const float *a1_qw=(const float*)d_in[6],  *a1_qb=(const float*)d_in[7];
  const float *a1_kw=(const float*)d_in[8],  *a1_kb=(const float*)d_in[9];
  const float *a1_vw=(const float*)d_in[10], *a1_vb=(const float*)d_in[11];
  const float *a1_nq=(const float*)d_in[12], *a1_nk=(const float*)d_in[13];
  const float *a1_ow=(const float*)d_in[14], *a1_ob=(const float*)d_in[15];
  const float *a2_qw=(const float*)d_in[16], *a2_qb=(const float*)d_in[17];
  const float *a2_kw=(const float*)d_in[18], *a2_kb=(const float*)d_in[19];
  const float *a2_vw=(const float*)d_in[20], *a2_vb=(const float*)d_in[21];
  const float *a2_nq=(const float*)d_in[22], *a2_nk=(const float*)d_in[23];
  const float *a2_ow=(const float*)d_in[24], *a2_ob=(const float*)d_in[25];
  const float *ff_inv_w=(const float*)d_in[26], *ff_inv_b=(const float*)d_in[27];
  const float *ff_dw=(const float*)d_in[28], *ff_db=(const float*)d_in[29];
  const float *ff_pw=(const float*)d_in[30];
  const float *ff_tw=(const float*)d_in[31];
  float* out = (float*)d_out;

  // ---- workspace plan (~203 MB total; all sizes 256-multiple) ----
  const size_t SLOTB = (size_t)SD*2;        // 16,056,320 B  (one bf16 S x DIM slot)
  char* ws = (char*)d_ws;
  size_t off = 0;
  auto alloc = [&](size_t n){ void* p = ws + off; off += (n + 255) & ~(size_t)255; return p; };

  char* P = (char*)alloc(7*SLOTB);          // 7 bf16 activation slots (112.4 MB)
  float* x1    = (float*)alloc((size_t)SD*4);     // fp32 residual (32.1 MB)
  unsigned short* nh2b = (unsigned short*)alloc(SLOTB); // MUST follow x1 (y2b spans both)
  float* x2    = (float*)alloc((size_t)SD*4);
  float* k2lin = (float*)alloc((size_t)ENCT*DIMC*4);
  unsigned short* k2b = (unsigned short*)alloc((size_t)ENCT*DIMC*2);
  unsigned short* v2b = (unsigned short*)alloc((size_t)ENCT*DIMC*2);
  unsigned short* encb = (unsigned short*)alloc((size_t)ENCT*DIMC*2);
  float* modsb = (float*)alloc(6*DIMC*4);
  float* ksum  = (float*)alloc(DIMC*4);
  float* kpart = (float*)alloc((size_t)28*DIMC*4);
  float* denom = (float*)alloc((size_t)STOK*NH*4);
  unsigned short* scorb = (unsigned short*)alloc((size_t)NH*HDIM*HDIM*2);

  // P-slot aliases (lifetimes verified disjoint)
  unsigned short* P0 = (unsigned short*)P;                 // nhb | y1b[0:] | y3b
  unsigned short* P1 = (unsigned short*)(P + 1*SLOTB);     // qb | spart | lob | y1b | tc[0:]
  unsigned short* P2 = (unsigned short*)(P + 2*SLOTB);     // kb | spart | x1b | y1b | tc[1:]
  unsigned short* P3 = (unsigned short*)(P + 3*SLOTB);     // vb | q2b | y1b
  unsigned short* P4 = (unsigned short*)(P + 4*SLOTB);     // qrb | crb | y1b
  unsigned short* P5 = (unsigned short*)(P + 5*SLOTB);     // krb | y1b
  unsigned short* W  = (unsigned short*)(P + 6*SLOTB);     // serial Bt staging (16 MB)
  unsigned short* nhb = P0;
  unsigned short* y1b = P0;                                // 96.34 MB = slots 0..5 exactly
  unsigned short* y2b = (unsigned short*)x1;               // 48.17 MB = x1 + nh2b exactly
  unsigned short* y3b = P0;
  float* tc = (float*)(P + 1*SLOTB);                       // 32.1 MB = slots 1..2
  float* spart = (float*)P1;   // 28 x NH x 112 x 112 fp32 = 28.1 MB, q/k dead by then

  auto cvt = [&](const float* s, unsigned short* d, size_t n){
    int n4 = (int)(n/4);
    cvt_k<<<dim3((n4+255)/256), 256, 0, stream>>>((const float4*)s, (ushort4*)d, n4);
  };
  auto cvtT = [&](const float* s, int rows, int ldsrc, int c0, int nc, int ncPad){
    cvt_t_k<<<dim3(ncPad/32, rows/32), 256, 0, stream>>>(s, W, rows, ldsrc, c0, nc);
  };
  auto gemm_grid = [&](int M, int Npad){ return dim3(Npad/128, (M+127)/128); };

  mods_k<<<dim3((6*DIMC+255)/256), 256, 0, stream>>>(sst, tstep, modsb);
  cvt(enc, encb, (size_t)ENCT*DIMC);

  // ---- attn1 ----
  ln_mod_k<<<dim3(STOK), 256, 0, stream>>>(hid, modsb, 0, 1, nhb);
  dim3 gMN = gemm_grid(STOK, 2304);
  cvtT(a1_qw, DIMC, DIMC, 0, DIMC, 2304);
  gemm_bt<2><<<gMN, 256, 0, stream>>>(nhb, W, a1_qb, nullptr, P1, nullptr, nullptr, STOK, DIMC, DIMC, DIMC);
  cvtT(a1_kw, DIMC, DIMC, 0, DIMC, 2304);
  gemm_bt<2><<<gMN, 256, 0, stream>>>(nhb, W, a1_kb, nullptr, P2, nullptr, nullptr, STOK, DIMC, DIMC, DIMC);
  cvtT(a1_vw, DIMC, DIMC, 0, DIMC, 2304);
  gemm_bt<2><<<gMN, 256, 0, stream>>>(nhb, W, a1_vb, nullptr, P3, nullptr, nullptr, STOK, DIMC, DIMC, DIMC);
  rms_bf_k<1,1><<<dim3(STOK), 256, 0, stream>>>(P1, a1_nq, fcos, fsin, P4);
  rms_bf_k<1,1><<<dim3(STOK), 256, 0, stream>>>(P2, a1_nk, fcos, fsin, P5);
  colsum_k<<<dim3(9, 28), 256, 0, stream>>>(P2, kpart);
  ksumred_k<<<dim3(9), 256, 0, stream>>>(kpart, ksum);
  denom_k<<<dim3(STOK), 256, 0, stream>>>(P1, ksum, denom);
  // q (P1) and k (P2) are dead now -> spart may overwrite them
  scores_k<<<dim3(NH, 28), 256, 0, stream>>>(P3, P5, spart);
  scred_k<<<dim3((NH*HDIM*HDIM+255)/256), 256, 0, stream>>>(spart, scorb);
  linout_k<<<dim3(STOK/64, NH), 256, 0, stream>>>(P4, scorb, denom, P1);   // lob -> P1
  cvtT(a1_ow, DIMC, DIMC, 0, DIMC, 2304);
  gemm_bt<3><<<gMN, 256, 0, stream>>>(P1, W, a1_ob, x1, P2, hid, modsb + 2*DIMC, STOK, DIMC, DIMC, DIMC);

  // ---- cross attn ----
  cvtT(a2_qw, DIMC, DIMC, 0, DIMC, 2304);
  gemm_bt<2><<<gMN, 256, 0, stream>>>(P2, W, a2_qb, nullptr, P3, nullptr, nullptr, STOK, DIMC, DIMC, DIMC);
  dim3 gENC = gemm_grid(ENCT, 2304);
  cvtT(a2_kw, DIMC, DIMC, 0, DIMC, 2304);
  gemm_bt<0><<<gENC, 256, 0, stream>>>(encb, W, a2_kb, k2lin, nullptr, nullptr, nullptr, ENCT, DIMC, DIMC, DIMC);
  cvtT(a2_vw, DIMC, DIMC, 0, DIMC, 2304);
  gemm_bt<2><<<gENC, 256, 0, stream>>>(encb, W, a2_vb, nullptr, v2b, nullptr, nullptr, ENCT, DIMC, DIMC, DIMC);
  rms_bf_k<0,0><<<dim3(STOK), 256, 0, stream>>>(P3, a2_nq, nullptr, nullptr, nullptr);
  rms_f32_k<<<dim3(ENCT), 256, 0, stream>>>(k2lin, a2_nk);
  cvt(k2lin, k2b, (size_t)ENCT*DIMC);
  xattn_k<<<dim3(STOK/64, NH), 256, 0, stream>>>(P3, k2b, v2b, P4);   // crb -> P4
  cvtT(a2_ow, DIMC, DIMC, 0, DIMC, 2304);
  gemm_bt<4><<<gMN, 256, 0, stream>>>(P4, W, a2_ob, x2, nullptr, x1, nullptr, STOK, DIMC, DIMC, DIMC);

  // ---- FF ----
  ln_mod_k<<<dim3(STOK), 256, 0, stream>>>(x2, modsb, 3, 4, nh2b);
  for (int q = 0; q < 4; ++q){                 // ff_inv in 4 column slices of 3360
    int c0 = q*3360;
    cvtT(ff_inv_w, DIMC, HID2, c0, 3360, 3456);
    gemm_bt<1><<<gemm_grid(STOK, 3456), 256, 0, stream>>>(nh2b, W, ff_inv_b + c0, nullptr, y1b + c0,
                                                          nullptr, nullptr, STOK, 3360, DIMC, HID2);
  }
  dw_k<<<dim3(STOK, 14), 256, 0, stream>>>(y1b, ff_dw, ff_db, y2b);
  for (int hh = 0; hh < 2; ++hh){              // point conv in 2 column slices of 1120
    int c0 = hh*1120;
    cvtT(ff_pw, HID1, DIMC, c0, 1120, 1152);
    gemm_bt<2><<<gemm_grid(STOK, 1152), 256, 0, stream>>>(y2b, W, nullptr, nullptr, y3b + c0,
                                                          nullptr, nullptr, STOK, 1120, HID1, DIMC);
  }
  // temporal conv: tc = y3 @ W1 (center) then shifted accumulates
  cvtT(ff_tw + (size_t)DD, DIMC, DIMC, 0, DIMC, 2304);
  gemm_bt<0><<<gMN, 256, 0, stream>>>(y3b, W, nullptr, tc, nullptr, nullptr, nullptr, STOK, DIMC, DIMC, DIMC);
  dim3 gT = gemm_grid(3136, 2304);
  cvtT(ff_tw, DIMC, DIMC, 0, DIMC, 2304);
  gemm_bt<5><<<gT, 256, 0, stream>>>(y3b, W, nullptr, tc + (size_t)448*DIMC, nullptr, nullptr, nullptr, 3136, DIMC, DIMC, DIMC);
  cvtT(ff_tw + (size_t)2*DD, DIMC, DIMC, 0, DIMC, 2304);
  gemm_bt<5><<<gT, 256, 0, stream>>>(y3b + (size_t)448*DIMC, W, nullptr, tc, nullptr, nullptr, nullptr, 3136, DIMC, DIMC, DIMC);

  // out = x2 + g_mlp*(y3 + tc)
  final_k<<<dim3((SD+255)/256), 256, 0, stream>>>(x2, y3b, tc, modsb, out);
}

// Round 6
// 1721.699 us; speedup vs baseline: 8.1842x; 1.1847x over previous
//
#include <hip/hip_runtime.h>

#define DIMC 2240
#define STOK 3584
#define ENCT 300
#define NH   20
#define HDIM 112
#define HID1 6720
#define HID2 13440
#define DD   (2240*2240)
#define SD   (3584*2240)

typedef short bf16x8 __attribute__((ext_vector_type(8)));   // guide-verified operand type
typedef float f32x4  __attribute__((ext_vector_type(4)));

__device__ __forceinline__ unsigned short f2bf(float f){
  unsigned int u = __float_as_uint(f);
  u += 0x7fffu + ((u >> 16) & 1u);          // RNE
  return (unsigned short)(u >> 16);
}
__device__ __forceinline__ float bf2f(unsigned short h){
  return __uint_as_float(((unsigned int)h) << 16);
}
__device__ __forceinline__ void gl_lds16(const unsigned short* g, unsigned short* l){
  __builtin_amdgcn_global_load_lds(
      (const __attribute__((address_space(1))) unsigned int*)(const void*)g,
      (__attribute__((address_space(3))) unsigned int*)(void*)l, 16, 0, 0);
}

// ---------------- fp32 -> bf16 convert (flat) ----------------
__global__ void cvt_k(const float4* __restrict__ src, ushort4* __restrict__ dst, int n4){
  int i = blockIdx.x*256 + threadIdx.x;
  if (i < n4){
    float4 v = src[i];
    ushort4 o; o.x = f2bf(v.x); o.y = f2bf(v.y); o.z = f2bf(v.z); o.w = f2bf(v.w);
    dst[i] = o;
  }
}

// ------- fp32 (rows x cols slice) -> bf16 TRANSPOSED [ncPad][rows], zero-padded -------
__global__ __launch_bounds__(256) void cvt_t_k(const float* __restrict__ src,
    unsigned short* __restrict__ dst, int rows, int ldsrc, int c0, int nc){
  __shared__ float tile[32][33];
  const int tx = threadIdx.x & 31, ty = threadIdx.x >> 5;   // ty 0..7
  const int colBase = blockIdx.x*32;
  #pragma unroll
  for (int i = 0; i < 4; ++i){
    int rr = blockIdx.y*32 + ty + i*8;
    int cc = colBase + tx;
    tile[ty + i*8][tx] = (cc < nc) ? src[(size_t)rr*ldsrc + c0 + cc] : 0.f;
  }
  __syncthreads();
  #pragma unroll
  for (int i = 0; i < 4; ++i){
    int n = colBase + ty + i*8;          // < ncPad by grid
    int k = blockIdx.y*32 + tx;
    dst[(size_t)n*rows + k] = f2bf(tile[tx][ty + i*8]);
  }
}

// ---------------- pack up to 3 biases into [nslots][2304] (zero pad) ----------------
__global__ void pack3_k(float* __restrict__ dst, const float* __restrict__ b0,
    const float* __restrict__ b1, const float* __restrict__ b2, int nslots){
  int i = blockIdx.x*256 + threadIdx.x;
  if (i >= nslots*2304) return;
  int slot = i / 2304, d = i - slot*2304;
  const float* src = (slot == 0) ? b0 : ((slot == 1) ? b1 : b2);
  dst[i] = (d < 2240) ? src[d] : 0.f;
}

// ---------------- mods = scale_shift_table + timestep ----------------
__global__ void mods_k(const float* __restrict__ sst, const float* __restrict__ ts, float* __restrict__ mods){
  int i = blockIdx.x*256 + threadIdx.x;
  if (i < 6*DIMC) mods[i] = sst[i] + ts[i];
}

// ---------------- LayerNorm * (1+sc) + sh -> bf16 ----------------
__global__ __launch_bounds__(256) void ln_mod_k(const float* __restrict__ x,
    const float* __restrict__ mods, int shj, int scj, unsigned short* __restrict__ out)
{
  const int s = blockIdx.x;
  const float* row = x + (size_t)s*DIMC;
  const float* sh = mods + shj*DIMC;
  const float* sc = mods + scj*DIMC;
  float sum = 0.f, sq = 0.f;
  for (int d = threadIdx.x; d < DIMC; d += 256){ float v = row[d]; sum += v; sq += v*v; }
  #pragma unroll
  for (int o = 32; o; o >>= 1){ sum += __shfl_down(sum, o); sq += __shfl_down(sq, o); }
  __shared__ float sA[4], sB[4];
  int w = threadIdx.x >> 6, l = threadIdx.x & 63;
  if (!l){ sA[w] = sum; sB[w] = sq; }
  __syncthreads();
  sum = sA[0]+sA[1]+sA[2]+sA[3];
  sq  = sB[0]+sB[1]+sB[2]+sB[3];
  float mean = sum * (1.f/DIMC);
  float rs = rsqrtf(sq*(1.f/DIMC) - mean*mean + 1e-6f);
  unsigned short* orow = out + (size_t)s*DIMC;
  for (int d = threadIdx.x; d < DIMC; d += 256){
    float v = (row[d]-mean)*rs*(1.f + sc[d]) + sh[d];
    orow[d] = f2bf(v);
  }
}

// ---------------- RMS on bf16 rows (optional ReLU / RoPE) ----------------
template<int RELU, int ROPE>
__global__ __launch_bounds__(256) void rms_bf_k(unsigned short* __restrict__ x, const float* __restrict__ nw,
    const float* __restrict__ cosb, const float* __restrict__ sinb, unsigned short* __restrict__ xr)
{
  const int s = blockIdx.x;
  unsigned short* row = x + (size_t)s*DIMC;
  float sq = 0.f;
  for (int d = threadIdx.x; d < DIMC; d += 256){ float v = bf2f(row[d]); sq += v*v; }
  #pragma unroll
  for (int o = 32; o; o >>= 1) sq += __shfl_down(sq, o);
  __shared__ float sB[4];
  int w = threadIdx.x >> 6, l = threadIdx.x & 63;
  if (!l) sB[w] = sq;
  __syncthreads();
  sq = sB[0]+sB[1]+sB[2]+sB[3];
  float rs = rsqrtf(sq*(1.f/DIMC) + 1e-5f);
  if constexpr (!ROPE){
    for (int d = threadIdx.x; d < DIMC; d += 256){
      float v = bf2f(row[d])*rs*nw[d];
      if (RELU) v = fmaxf(v, 0.f);
      row[d] = f2bf(v);
    }
  } else {
    for (int p = threadIdx.x; p < DIMC/2; p += 256){
      int d0 = 2*p, d1 = d0+1;
      float v0 = bf2f(row[d0])*rs*nw[d0];
      float v1 = bf2f(row[d1])*rs*nw[d1];
      if (RELU){ v0 = fmaxf(v0,0.f); v1 = fmaxf(v1,0.f); }
      row[d0] = f2bf(v0); row[d1] = f2bf(v1);
      int j0 = d0 % HDIM;                       // pairs stay within a head (112 even)
      float c  = cosb[(size_t)s*HDIM + j0];     // cos[0::2]
      float sn = sinb[(size_t)s*HDIM + j0 + 1]; // sin[1::2]
      xr[(size_t)s*DIMC + d0] = f2bf(v0*c - v1*sn);
      xr[(size_t)s*DIMC + d1] = f2bf(v0*sn + v1*c);
    }
  }
}

// ------- m97-structure bf16 MFMA GEMM: C = A(MxK) @ Bt^T, Bt is [Npad][K] (N-major) -----
// EPI: 0 Cf=acc+bias | 1 Cb=bf16(silu(acc+bias)) | 2 Cb=bf16(acc+bias)
//      3 u=res+gate*(acc+bias); Cf=u; Cb=bf16(u) | 4 Cf=res+acc+bias | 5 Cf+=acc
//      6 slot-split: slot=col/2304, d=col%2304; if d<2240: Cb[slot*ldc + row*2240 + d]
template<int EPI>
__global__ __launch_bounds__(256) void gemm_bt(
  const unsigned short* __restrict__ A, const unsigned short* __restrict__ Bt,
  const float* __restrict__ bias, float* __restrict__ Cf, unsigned short* __restrict__ Cb,
  const float* __restrict__ res, const float* __restrict__ gate,
  int M, int N, int K, int ldc)
{
  __shared__ __align__(16) unsigned short Al[128*32];
  __shared__ __align__(16) unsigned short Bl[128*32];
  // bijective XCD-aware swizzle (m204)
  const int gx = gridDim.x;
  const int nwg = gx*gridDim.y;
  const int orig = blockIdx.y*gx + blockIdx.x;
  const int qq = nwg >> 3, rr = nwg & 7;
  const int xcd = orig & 7, li = orig >> 3;
  const int wg = (xcd < rr ? xcd*(qq+1) : rr*(qq+1) + (xcd-rr)*qq) + li;
  const int m0 = (wg / gx)*128, n0 = (wg % gx)*128;

  const int t = threadIdx.x;
  const int lane = t & 63, w = t >> 6;
  const int wr = w >> 1, wc = w & 1;
  const int l16 = lane & 15, lk = lane >> 4;

  const int lrow = lane >> 2;          // 0..15
  const int lcol = (lane & 3) << 3;    // 0,8,16,24
  const int arow0 = m0 + w*32 + lrow;
  const int brow0 = n0 + w*32 + lrow;
  const unsigned short* Ap0 = A + (size_t)min(arow0,      M-1)*K + lcol;
  const unsigned short* Ap1 = A + (size_t)min(arow0 + 16, M-1)*K + lcol;
  const unsigned short* Bp0 = Bt + (size_t)(brow0     )*K + lcol;
  const unsigned short* Bp1 = Bt + (size_t)(brow0 + 16)*K + lcol;
  unsigned short* Ad0 = Al + (w*2+0)*512;
  unsigned short* Ad1 = Al + (w*2+1)*512;
  unsigned short* Bd0 = Bl + (w*2+0)*512;
  unsigned short* Bd1 = Bl + (w*2+1)*512;

  f32x4 acc[4][4] = {};
  for (int k0 = 0; k0 < K; k0 += 32){
    __syncthreads();
    gl_lds16(Ap0 + k0, Ad0);
    gl_lds16(Ap1 + k0, Ad1);
    gl_lds16(Bp0 + k0, Bd0);
    gl_lds16(Bp1 + k0, Bd1);
    __syncthreads();
    bf16x8 af[4], bfr[4];
    #pragma unroll
    for (int m = 0; m < 4; ++m)
      af[m] = *reinterpret_cast<const bf16x8*>(Al + (wr*64 + m*16 + l16)*32 + lk*8);
    #pragma unroll
    for (int n = 0; n < 4; ++n)
      bfr[n] = *reinterpret_cast<const bf16x8*>(Bl + (wc*64 + n*16 + l16)*32 + lk*8);
    #pragma unroll
    for (int m = 0; m < 4; ++m)
      #pragma unroll
      for (int n = 0; n < 4; ++n)
        acc[m][n] = __builtin_amdgcn_mfma_f32_16x16x32_bf16(af[m], bfr[n], acc[m][n], 0, 0, 0);
  }

  const int rb = m0 + wr*64 + lk*4;   // C/D: col = lane&15, row = (lane>>4)*4 + reg
  const int cb = n0 + wc*64 + l16;
  #pragma unroll
  for (int m = 0; m < 4; ++m){
    #pragma unroll
    for (int r = 0; r < 4; ++r){
      int row = rb + m*16 + r;
      if (row >= M) continue;
      #pragma unroll
      for (int n = 0; n < 4; ++n){
        int col = cb + n*16;
        if (col >= N) continue;
        float v = acc[m][n][r];
        float bv = bias ? bias[col] : 0.f;
        if constexpr (EPI == 6){
          int slot = col / 2304;
          int d = col - slot*2304;
          if (d < 2240)
            Cb[(size_t)slot*ldc + (size_t)row*2240 + d] = f2bf(v + bv);
        } else {
          size_t idx = (size_t)row*ldc + col;
          if constexpr (EPI == 0){ Cf[idx] = v + bv; }
          else if constexpr (EPI == 1){ float u = v + bv; Cb[idx] = f2bf(u / (1.f + __expf(-u))); }
          else if constexpr (EPI == 2){ Cb[idx] = f2bf(v + bv); }
          else if constexpr (EPI == 3){ float u = res[idx] + gate[col]*(v + bv); Cf[idx] = u; Cb[idx] = f2bf(u); }
          else if constexpr (EPI == 4){ Cf[idx] = res[idx] + v + bv; }
          else { Cf[idx] += v; }
        }
      }
    }
  }
}

// ---------------- linear attention helpers ----------------
__global__ void colsum_k(const unsigned short* __restrict__ k, float* __restrict__ kpart){
  int d = blockIdx.x*256 + threadIdx.x;
  if (d >= DIMC) return;
  int ch = blockIdx.y, s0 = ch*128;
  float acc = 0.f;
  for (int s = s0; s < s0+128; ++s) acc += bf2f(k[(size_t)s*DIMC + d]);
  kpart[(size_t)ch*DIMC + d] = acc;
}
__global__ void ksumred_k(const float* __restrict__ kpart, float* __restrict__ ksum){
  int d = blockIdx.x*256 + threadIdx.x;
  if (d >= DIMC) return;
  float a = 0.f;
  for (int c = 0; c < 28; ++c) a += kpart[(size_t)c*DIMC + d];
  ksum[d] = a;
}
__global__ __launch_bounds__(256) void denom_k(const unsigned short* __restrict__ q,
    const float* __restrict__ ksum, float* __restrict__ denom)
{
  int s = blockIdx.x; int w = threadIdx.x >> 6, l = threadIdx.x & 63;
  for (int h = w; h < NH; h += 4){
    const unsigned short* qb = q + (size_t)s*DIMC + h*HDIM;
    const float* kb = ksum + h*HDIM;
    float v = bf2f(qb[l])*kb[l];
    if (l < 48) v += bf2f(qb[64+l])*kb[64+l];
    #pragma unroll
    for (int o = 32; o; o >>= 1) v += __shfl_down(v, o);
    if (!l) denom[s*NH + h] = v + 1e-15f;
  }
}

// -------- MFMA scores: part[ch][h][e][d] = sum_{s in 128-chunk} V[s,h,e]*Kr[s,h,d] -----
#define SLSC 136
__device__ __forceinline__ int sc_idx(int e, int s){
  return e*SLSC + (s ^ (((e >> 3) & 7) << 3));
}
__global__ __launch_bounds__(256) void scores_k(const unsigned short* __restrict__ v,
    const unsigned short* __restrict__ kr, float* __restrict__ part)
{
  const int h = blockIdx.x, ch = blockIdx.y;
  __shared__ __align__(16) unsigned short Vt[112*SLSC];
  __shared__ __align__(16) unsigned short Kt[112*SLSC];
  const int t = threadIdx.x, lane = t & 63, w = t >> 6;
  const int l16 = lane & 15, lk = lane >> 4;
  const int sbase = ch*128;

  for (int p = t; p < 1792; p += 256){       // 128 tokens x 14 dim-octets
    int s = p / 14, oc = (p % 14) * 8;
    bf16x8 vv = *reinterpret_cast<const bf16x8*>(v  + (size_t)(sbase+s)*DIMC + h*HDIM + oc);
    bf16x8 kk = *reinterpret_cast<const bf16x8*>(kr + (size_t)(sbase+s)*DIMC + h*HDIM + oc);
    #pragma unroll
    for (int j = 0; j < 8; ++j){
      Vt[sc_idx(oc+j, s)] = (unsigned short)vv[j];
      Kt[sc_idx(oc+j, s)] = (unsigned short)kk[j];
    }
  }
  __syncthreads();

  f32x4 acc[2][7] = {};                      // wave w owns m-tiles {w, w+4}
  #pragma unroll
  for (int ks = 0; ks < 4; ++ks){
    const int sf = ks*32 + lk*8;
    bf16x8 bfrg[7];
    #pragma unroll
    for (int nt = 0; nt < 7; ++nt){
      int d = nt*16 + l16;
      bfrg[nt] = *reinterpret_cast<const bf16x8*>(&Kt[d*SLSC + (sf ^ (((d >> 3) & 7) << 3))]);
    }
    #pragma unroll
    for (int mi = 0; mi < 2; ++mi){
      int mt = w + mi*4;
      if (mt < 7){
        int e = mt*16 + l16;
        bf16x8 afrg = *reinterpret_cast<const bf16x8*>(&Vt[e*SLSC + (sf ^ (((e >> 3) & 7) << 3))]);
        #pragma unroll
        for (int nt = 0; nt < 7; ++nt)
          acc[mi][nt] = __builtin_amdgcn_mfma_f32_16x16x32_bf16(afrg, bfrg[nt], acc[mi][nt], 0, 0, 0);
      }
    }
  }

  float* pout = part + ((size_t)ch*NH + h)*12544;
  #pragma unroll
  for (int mi = 0; mi < 2; ++mi){
    int mt = w + mi*4;
    if (mt >= 7) continue;
    #pragma unroll
    for (int nt = 0; nt < 7; ++nt)
      #pragma unroll
      for (int r = 0; r < 4; ++r)
        pout[(size_t)(mt*16 + lk*4 + r)*HDIM + nt*16 + l16] = acc[mi][nt][r];
  }
}
__global__ void scred_k(const float* __restrict__ part, unsigned short* __restrict__ sc){
  int i = blockIdx.x*256 + threadIdx.x;
  if (i >= NH*HDIM*HDIM) return;
  float a = 0.f;
  #pragma unroll
  for (int c = 0; c < 28; ++c) a += part[(size_t)c*(NH*HDIM*HDIM) + i];
  sc[i] = f2bf(a);
}

// -------- MFMA linout: out[s,h*112+e] = (sum_d scores[h,e,d]*qr[s,h,d]) / denom[s,h] ---
__global__ __launch_bounds__(256) void linout_k(const unsigned short* __restrict__ qr,
    const unsigned short* __restrict__ scores, const float* __restrict__ denom,
    unsigned short* __restrict__ out)
{
  const int h = blockIdx.y;
  const int t = threadIdx.x, lane = t & 63, w = t >> 6;
  const int l16 = lane & 15, lk = lane >> 4;
  const int s0 = blockIdx.x*64 + w*16;
  const unsigned short* qrow = qr + (size_t)(s0 + l16)*DIMC + h*HDIM;
  const unsigned short* sb = scores + (size_t)h*12544;
  f32x4 acc[7] = {};
  #pragma unroll
  for (int ks = 0; ks < 4; ++ks){
    int d0 = ks*32 + lk*8;
    bf16x8 a = {};
    if (d0 < HDIM) a = *reinterpret_cast<const bf16x8*>(qrow + d0);
    #pragma unroll
    for (int nt = 0; nt < 7; ++nt){
      bf16x8 b = {};
      if (d0 < HDIM) b = *reinterpret_cast<const bf16x8*>(sb + (size_t)(nt*16 + l16)*HDIM + d0);
      acc[nt] = __builtin_amdgcn_mfma_f32_16x16x32_bf16(a, b, acc[nt], 0, 0, 0);
    }
  }
  #pragma unroll
  for (int r = 0; r < 4; ++r){
    int s = s0 + lk*4 + r;
    float dn = 1.f / denom[(size_t)s*NH + h];
    #pragma unroll
    for (int nt = 0; nt < 7; ++nt)
      out[(size_t)s*DIMC + h*HDIM + nt*16 + l16] = f2bf(acc[nt][r]*dn);
  }
}

// ---------------- fused cross-attention, MFMA (300 keys, head dim 112 padded to 128) ----
__global__ __launch_bounds__(256) void xattn_k(
    const unsigned short* __restrict__ q,   // S x DIM bf16 (rms-normed)
    const unsigned short* __restrict__ k2,  // ENCT x DIM bf16 (rms-normed)
    const unsigned short* __restrict__ v2,  // ENCT x DIM bf16
    unsigned short* __restrict__ outb)      // S x DIM bf16
{
  const int h = blockIdx.y;
  const int w = threadIdx.x >> 6, lane = threadIdx.x & 63;
  const int l16 = lane & 15, lk = lane >> 4;
  const float scale = 0.09449111825230679f;   // 1/sqrt(112)

  __shared__ __align__(16) unsigned short Kl[64][136];
  __shared__ __align__(16) unsigned short Vl[112][72];
  __shared__ __align__(16) unsigned short Pl[4][16][72];

  bf16x8 qf[4];
  const unsigned short* qbase = q + (size_t)(blockIdx.x*64 + w*16 + l16)*DIMC + h*HDIM;
  #pragma unroll
  for (int c = 0; c < 4; ++c){
    int d0 = c*32 + lk*8;
    bf16x8 z = {};
    qf[c] = (d0 < HDIM) ? *reinterpret_cast<const bf16x8*>(qbase + d0) : z;
  }

  f32x4 lg[5][4] = {};
  #pragma unroll
  for (int c = 0; c < 5; ++c){
    const int kbase = c*64;
    const int nk = (c == 4) ? (ENCT - 256) : 64;
    __syncthreads();
    #pragma unroll
    for (int it = 0; it < 4; ++it){
      int li = it*256 + threadIdx.x;
      int key = li >> 4, d0 = (li & 15) << 3;
      uint4 val = make_uint4(0u,0u,0u,0u);
      if (key < nk && d0 < HDIM)
        val = *reinterpret_cast<const uint4*>(k2 + (size_t)(kbase+key)*DIMC + h*HDIM + d0);
      *reinterpret_cast<uint4*>(&Kl[key][d0]) = val;
    }
    __syncthreads();
    #pragma unroll
    for (int nt = 0; nt < 4; ++nt){
      #pragma unroll
      for (int ks = 0; ks < 4; ++ks){
        bf16x8 kf = *reinterpret_cast<const bf16x8*>(&Kl[nt*16 + l16][ks*32 + lk*8]);
        lg[c][nt] = __builtin_amdgcn_mfma_f32_16x16x32_bf16(qf[ks], kf, lg[c][nt], 0, 0, 0);
      }
    }
  }

  float mx[4] = {-3e38f, -3e38f, -3e38f, -3e38f};
  #pragma unroll
  for (int c = 0; c < 5; ++c)
    #pragma unroll
    for (int nt = 0; nt < 4; ++nt){
      bool valid = (c*64 + nt*16 + l16) < ENCT;
      #pragma unroll
      for (int r = 0; r < 4; ++r){
        float v = valid ? lg[c][nt][r]*scale : -3e38f;
        lg[c][nt][r] = v;
        mx[r] = fmaxf(mx[r], v);
      }
    }
  #pragma unroll
  for (int o = 1; o < 16; o <<= 1)
    #pragma unroll
    for (int r = 0; r < 4; ++r) mx[r] = fmaxf(mx[r], __shfl_xor(mx[r], o));
  float sm[4] = {0.f, 0.f, 0.f, 0.f};
  #pragma unroll
  for (int c = 0; c < 5; ++c)
    #pragma unroll
    for (int nt = 0; nt < 4; ++nt)
      #pragma unroll
      for (int r = 0; r < 4; ++r){
        float e = __expf(lg[c][nt][r] - mx[r]);
        lg[c][nt][r] = e;
        sm[r] += e;
      }
  #pragma unroll
  for (int o = 1; o < 16; o <<= 1)
    #pragma unroll
    for (int r = 0; r < 4; ++r) sm[r] += __shfl_xor(sm[r], o);
  float inv[4];
  #pragma unroll
  for (int r = 0; r < 4; ++r) inv[r] = 1.f / sm[r];

  f32x4 oacc[7] = {};
  #pragma unroll
  for (int c = 0; c < 5; ++c){
    const int kbase = c*64;
    const int nk = (c == 4) ? (ENCT - 256) : 64;
    __syncthreads();
    #pragma unroll
    for (int it = 0; it < 4; ++it){
      int li = it*256 + threadIdx.x;
      if (li < 896){
        int key = li/14, d0 = (li%14)*8;
        if (key < nk){
          bf16x8 vv = *reinterpret_cast<const bf16x8*>(v2 + (size_t)(kbase+key)*DIMC + h*HDIM + d0);
          #pragma unroll
          for (int j = 0; j < 8; ++j) Vl[d0+j][key] = (unsigned short)vv[j];
        } else {
          #pragma unroll
          for (int j = 0; j < 8; ++j) Vl[d0+j][key] = 0;
        }
      }
    }
    #pragma unroll
    for (int nt = 0; nt < 4; ++nt)
      #pragma unroll
      for (int r = 0; r < 4; ++r)
        Pl[w][lk*4 + r][nt*16 + l16] = f2bf(lg[c][nt][r]);
    __syncthreads();
    #pragma unroll
    for (int ks = 0; ks < 2; ++ks){
      bf16x8 pf = *reinterpret_cast<const bf16x8*>(&Pl[w][l16][ks*32 + lk*8]);
      #pragma unroll
      for (int n = 0; n < 7; ++n){
        bf16x8 vf = *reinterpret_cast<const bf16x8*>(&Vl[n*16 + l16][ks*32 + lk*8]);
        oacc[n] = __builtin_amdgcn_mfma_f32_16x16x32_bf16(pf, vf, oacc[n], 0, 0, 0);
      }
    }
  }

  const int orow = blockIdx.x*64 + w*16 + lk*4;
  #pragma unroll
  for (int n = 0; n < 7; ++n)
    #pragma unroll
    for (int r = 0; r < 4; ++r)
      outb[(size_t)(orow + r)*DIMC + h*HDIM + n*16 + l16] = f2bf(oacc[n][r]*inv[r]);
}

// ------- depthwise 3x3 + bias + GLU(silu): 2 channels x 4 vertical outputs/thread -----
// grid.x = f(8) x ytile(4) x w(28) = 896, grid.y = 14 (512-ch chunks)
__global__ __launch_bounds__(256) void dw_k(const unsigned short* __restrict__ y1,
    const float* __restrict__ dw, const float* __restrict__ db, unsigned short* __restrict__ y2)
{
  int c = (blockIdx.y*256 + threadIdx.x)*2;
  if (c >= HID1) return;
  int bx = blockIdx.x;
  int ww = bx % 28;
  int yt = (bx / 28) & 3;
  int f  = bx / 112;
  int y0 = yt*4;

  float wa[9][2], wg[9][2];
  #pragma unroll
  for (int tp = 0; tp < 9; ++tp){
    float2 va = *reinterpret_cast<const float2*>(dw + tp*HID2 + c);
    float2 vg = *reinterpret_cast<const float2*>(dw + tp*HID2 + c + HID1);
    wa[tp][0] = va.x; wa[tp][1] = va.y;
    wg[tp][0] = vg.x; wg[tp][1] = vg.y;
  }
  float2 ba = *reinterpret_cast<const float2*>(db + c);
  float2 bg = *reinterpret_cast<const float2*>(db + c + HID1);
  float a0[4], a1[4], g0[4], g1[4];
  #pragma unroll
  for (int r = 0; r < 4; ++r){ a0[r] = ba.x; a1[r] = ba.y; g0[r] = bg.x; g1[r] = bg.y; }

  #pragma unroll
  for (int dy6 = 0; dy6 < 6; ++dy6){
    int y = y0 - 1 + dy6;
    if ((unsigned)y >= 16u) continue;
    #pragma unroll
    for (int dx = 0; dx < 3; ++dx){
      int x = ww + dx - 1;
      if ((unsigned)x >= 28u) continue;
      size_t base = ((size_t)(f*16 + y)*28 + x)*HID2;
      unsigned int a01 = *reinterpret_cast<const unsigned int*>(y1 + base + c);
      unsigned int g01 = *reinterpret_cast<const unsigned int*>(y1 + base + c + HID1);
      float fa0 = bf2f((unsigned short)(a01 & 0xffffu));
      float fa1 = bf2f((unsigned short)(a01 >> 16));
      float fg0 = bf2f((unsigned short)(g01 & 0xffffu));
      float fg1 = bf2f((unsigned short)(g01 >> 16));
      #pragma unroll
      for (int r = 0; r < 4; ++r){
        int kdy = dy6 - r;                    // compile-time after unroll
        if (kdy < 0 || kdy > 2) continue;
        int tp = kdy*3 + dx;
        a0[r] += fa0*wa[tp][0]; a1[r] += fa1*wa[tp][1];
        g0[r] += fg0*wg[tp][0]; g1[r] += fg1*wg[tp][1];
      }
    }
  }
  #pragma unroll
  for (int r = 0; r < 4; ++r){
    float s0 = g0[r] / (1.f + __expf(-g0[r]));
    float s1 = g1[r] / (1.f + __expf(-g1[r]));
    int pos = (f*16 + y0 + r)*28 + ww;
    unsigned int o = (unsigned int)f2bf(a0[r]*s0) | ((unsigned int)f2bf(a1[r]*s1) << 16);
    *reinterpret_cast<unsigned int*>(y2 + (size_t)pos*HID1 + c) = o;
  }
}

// ---------------- final: out = x2 + g_mlp*(y3 + tc) ----------------
__global__ void final_k(const float* __restrict__ x2, const unsigned short* __restrict__ y3,
    const float* __restrict__ tc, const float* __restrict__ mods, float* __restrict__ out)
{
  int i = blockIdx.x*256 + threadIdx.x;
  if (i >= SD) return;
  int d = i % DIMC;
  out[i] = x2[i] + mods[5*DIMC + d]*(bf2f(y3[i]) + tc[i]);
}

extern "C" void kernel_launch(void* const* d_in, const int* in_sizes, int n_in,
                              void* d_out, int out_size, void* d_ws, size_t ws_size,
                              hipStream_t stream)
{
  const float* hid   = (const float*)d_in[0];
  const float* enc   = (const float*)d_in[1];
  const float* tstep = (const float*)d_in[2];
  const float* fcos  = (const float*)d_in[3];
  const float* fsin  = (const float*)d_in[4];
  const float* sst   = (const float*)d_in[5];
  const float *a1_qw=(const float*)d_in[6],  *a1_qb=(const float*)d_in[7];
  const float *a1_kw=(const float*)d_in[8],  *a1_kb=(const float*)d_in[9];
  const float *a1_vw=(const float*)d_in[10], *a1_vb=(const float*)d_in[11];
  const float *a1_nq=(const float*)d_in[12], *a1_nk=(const float*)d_in[13];
  const float *a1_ow=(const float*)d_in[14], *a1_ob=(const float*)d_in[15];
  const float *a2_qw=(const float*)d_in[16], *a2_qb=(const float*)d_in[17];
  const float *a2_kw=(const float*)d_in[18], *a2_kb=(const float*)d_in[19];
  const float *a2_vw=(const float*)d_in[20], *a2_vb=(const float*)d_in[21];
  const float *a2_nq=(const float*)d_in[22], *a2_nk=(const float*)d_in[23];
  const float *a2_ow=(const float*)d_in[24], *a2_ob=(const float*)d_in[25];
  const float *ff_inv_w=(const float*)d_in[26], *ff_inv_b=(const float*)d_in[27];
  const float *ff_dw=(const float*)d_in[28], *ff_db=(const float*)d_in[29];
  const float *ff_pw=(const float*)d_in[30];
  const float *ff_tw=(const float*)d_in[31];
  float* out = (float*)d_out;

  // ---- workspace plan (~213 MB total; all sizes 256-multiple) ----
  const size_t SLOTB = (size_t)SD*2;        // 16,056,320 B  (one bf16 S x DIM slot)
  char* ws = (char*)d_ws;
  size_t off = 0;
  auto alloc = [&](size_t n){ void* p = ws + off; off += (n + 255) & ~(size_t)255; return p; };

  char* P = (char*)alloc(6*SLOTB);          // 6 bf16 activation slots (96.3 MB)
  float* x1    = (float*)alloc((size_t)SD*4);     // fp32 residual (32.1 MB)
  unsigned short* nh2b = (unsigned short*)alloc(SLOTB); // MUST follow x1 (y2b spans both)
  float* x2    = (float*)alloc((size_t)SD*4);
  unsigned short* k2b = (unsigned short*)alloc((size_t)ENCT*DIMC*2);  // k2b+v2b contiguous
  unsigned short* v2b = (unsigned short*)alloc((size_t)ENCT*DIMC*2);
  unsigned short* encb = (unsigned short*)alloc((size_t)ENCT*DIMC*2);
  float* modsb = (float*)alloc(6*DIMC*4);
  float* ksum  = (float*)alloc(DIMC*4);
  float* kpart = (float*)alloc((size_t)28*DIMC*4);
  float* denom = (float*)alloc((size_t)STOK*NH*4);
  unsigned short* scorb = (unsigned short*)alloc((size_t)NH*HDIM*HDIM*2);
  float* bias3 = (float*)alloc(3*2304*4);
  unsigned short* Wbig = (unsigned short*)alloc((size_t)3*2304*DIMC*2);  // 31 MB weight staging

  // P-slot aliases (lifetimes verified disjoint)
  unsigned short* P0 = (unsigned short*)P;                 // nhb | y1b[0:] | y3b
  unsigned short* P1 = (unsigned short*)(P + 1*SLOTB);     // qb | spart | lob | y1b | tc[0:]
  unsigned short* P2 = (unsigned short*)(P + 2*SLOTB);     // kb | spart | x1b | y1b | tc[1:]
  unsigned short* P3 = (unsigned short*)(P + 3*SLOTB);     // vb | q2b | y1b
  unsigned short* P4 = (unsigned short*)(P + 4*SLOTB);     // qrb | crb | y1b
  unsigned short* P5 = (unsigned short*)(P + 5*SLOTB);     // krb | y1b
  unsigned short* nhb = P0;
  unsigned short* y1b = P0;                                // 96.34 MB = slots 0..5 exactly
  unsigned short* y2b = (unsigned short*)x1;               // 48.17 MB = x1 + nh2b exactly
  unsigned short* y3b = P0;
  float* tc = (float*)(P + 1*SLOTB);                       // 32.1 MB = slots 1..2
  float* spart = (float*)P1;   // 28 x NH x 112 x 112 fp32 = 28.1 MB, q/k dead by then

  auto cvt = [&](const float* s, unsigned short* d, size_t n){
    int n4 = (int)(n/4);
    cvt_k<<<dim3((n4+255)/256), 256, 0, stream>>>((const float4*)s, (ushort4*)d, n4);
  };
  auto cvtT = [&](const float* s, unsigned short* d, int rows, int ldsrc, int c0, int nc, int ncPad){
    cvt_t_k<<<dim3(ncPad/32, rows/32), 256, 0, stream>>>(s, d, rows, ldsrc, c0, nc);
  };
  auto gemm_grid = [&](int M, int Npad){ return dim3(Npad/128, (M+127)/128); };

  mods_k<<<dim3((6*DIMC+255)/256), 256, 0, stream>>>(sst, tstep, modsb);
  cvt(enc, encb, (size_t)ENCT*DIMC);

  // ---- attn1: fused QKV ----
  ln_mod_k<<<dim3(STOK), 256, 0, stream>>>(hid, modsb, 0, 1, nhb);
  pack3_k<<<dim3((3*2304+255)/256), 256, 0, stream>>>(bias3, a1_qb, a1_kb, a1_vb, 3);
  cvtT(a1_qw, Wbig + (size_t)0*2304*DIMC, DIMC, DIMC, 0, DIMC, 2304);
  cvtT(a1_kw, Wbig + (size_t)1*2304*DIMC, DIMC, DIMC, 0, DIMC, 2304);
  cvtT(a1_vw, Wbig + (size_t)2*2304*DIMC, DIMC, DIMC, 0, DIMC, 2304);
  gemm_bt<6><<<gemm_grid(STOK, 6912), 256, 0, stream>>>(nhb, Wbig, bias3, nullptr, P1,
                                                        nullptr, nullptr, STOK, 6912, DIMC, SD);
  rms_bf_k<1,1><<<dim3(STOK), 256, 0, stream>>>(P1, a1_nq, fcos, fsin, P4);
  rms_bf_k<1,1><<<dim3(STOK), 256, 0, stream>>>(P2, a1_nk, fcos, fsin, P5);
  colsum_k<<<dim3(9, 28), 256, 0, stream>>>(P2, kpart);
  ksumred_k<<<dim3(9), 256, 0, stream>>>(kpart, ksum);
  denom_k<<<dim3(STOK), 256, 0, stream>>>(P1, ksum, denom);
  // q (P1) and k (P2) are dead now -> spart may overwrite them
  scores_k<<<dim3(NH, 28), 256, 0, stream>>>(P3, P5, spart);
  scred_k<<<dim3((NH*HDIM*HDIM+255)/256), 256, 0, stream>>>(spart, scorb);
  linout_k<<<dim3(STOK/64, NH), 256, 0, stream>>>(P4, scorb, denom, P1);   // lob -> P1
  dim3 gMN = gemm_grid(STOK, 2304);
  cvtT(a1_ow, Wbig, DIMC, DIMC, 0, DIMC, 2304);
  gemm_bt<3><<<gMN, 256, 0, stream>>>(P1, Wbig, a1_ob, x1, P2, hid, modsb + 2*DIMC, STOK, DIMC, DIMC, DIMC);

  // ---- cross attn ----
  cvtT(a2_qw, Wbig, DIMC, DIMC, 0, DIMC, 2304);
  gemm_bt<2><<<gMN, 256, 0, stream>>>(P2, Wbig, a2_qb, nullptr, P3, nullptr, nullptr, STOK, DIMC, DIMC, DIMC);
  pack3_k<<<dim3((2*2304+255)/256), 256, 0, stream>>>(bias3, a2_kb, a2_vb, a2_vb, 2);
  cvtT(a2_kw, Wbig + (size_t)0*2304*DIMC, DIMC, DIMC, 0, DIMC, 2304);
  cvtT(a2_vw, Wbig + (size_t)1*2304*DIMC, DIMC, DIMC, 0, DIMC, 2304);
  gemm_bt<6><<<gemm_grid(ENCT, 4608), 256, 0, stream>>>(encb, Wbig, bias3, nullptr, k2b,
                                                        nullptr, nullptr, ENCT, 4608, DIMC, ENCT*DIMC);
  rms_bf_k<0,0><<<dim3(STOK), 256, 0, stream>>>(P3, a2_nq, nullptr, nullptr, nullptr);
  rms_bf_k<0,0><<<dim3(ENCT), 256, 0, stream>>>(k2b, a2_nk, nullptr, nullptr, nullptr);
  xattn_k<<<dim3(STOK/64, NH), 256, 0, stream>>>(P3, k2b, v2b, P4);   // crb -> P4
  cvtT(a2_ow, Wbig, DIMC, DIMC, 0, DIMC, 2304);
  gemm_bt<4><<<gMN, 256, 0, stream>>>(P4, Wbig, a2_ob, x2, nullptr, x1, nullptr, STOK, DIMC, DIMC, DIMC);

  // ---- FF ----
  ln_mod_k<<<dim3(STOK), 256, 0, stream>>>(x2, modsb, 3, 4, nh2b);
  for (int q = 0; q < 2; ++q){                 // ff_inv in 2 column slices of 6720
    int c0 = q*6720;
    cvtT(ff_inv_w, Wbig, DIMC, HID2, c0, 6720, 6784);
    gemm_bt<1><<<gemm_grid(STOK, 6784), 256, 0, stream>>>(nh2b, Wbig, ff_inv_b + c0, nullptr, y1b + c0,
                                                          nullptr, nullptr, STOK, 6720, DIMC, HID2);
  }
  dw_k<<<dim3(896, 14), 256, 0, stream>>>(y1b, ff_dw, ff_db, y2b);
  cvtT(ff_pw, Wbig, HID1, DIMC, 0, DIMC, 2304);   // point conv in one GEMM (K=6720)
  gemm_bt<2><<<gMN, 256, 0, stream>>>(y2b, Wbig, nullptr, nullptr, y3b,
                                      nullptr, nullptr, STOK, DIMC, HID1, DIMC);
  // temporal conv: tc = y3 @ W1 (center) then shifted accumulates
  cvtT(ff_tw + (size_t)DD, Wbig, DIMC, DIMC, 0, DIMC, 2304);
  gemm_bt<0><<<gMN, 256, 0, stream>>>(y3b, Wbig, nullptr, tc, nullptr, nullptr, nullptr, STOK, DIMC, DIMC, DIMC);
  dim3 gT = gemm_grid(3136, 2304);
  cvtT(ff_tw, Wbig, DIMC, DIMC, 0, DIMC, 2304);
  gemm_bt<5><<<gT, 256, 0, stream>>>(y3b, Wbig, nullptr, tc + (size_t)448*DIMC, nullptr, nullptr, nullptr, 3136, DIMC, DIMC, DIMC);
  cvtT(ff_tw + (size_t)2*DD, Wbig, DIMC, DIMC, 0, DIMC, 2304);
  gemm_bt<5><<<gT, 256, 0, stream>>>(y3b + (size_t)448*DIMC, Wbig, nullptr, tc, nullptr, nullptr, nullptr, 3136, DIMC, DIMC, DIMC);

  // out = x2 + g_mlp*(y3 + tc)
  final_k<<<dim3((SD+255)/256), 256, 0, stream>>>(x2, y3b, tc, modsb, out);
}

// Round 7
// 1533.304 us; speedup vs baseline: 9.1898x; 1.1229x over previous
//
#include <hip/hip_runtime.h>

#define DIMC 2240
#define STOK 3584
#define ENCT 300
#define NH   20
#define HDIM 112
#define HID1 6720
#define HID2 13440
#define DD   (2240*2240)
#define SD   (3584*2240)

typedef short bf16x8 __attribute__((ext_vector_type(8)));   // guide-verified operand type
typedef float f32x4  __attribute__((ext_vector_type(4)));

__device__ __forceinline__ unsigned short f2bf(float f){
  unsigned int u = __float_as_uint(f);
  u += 0x7fffu + ((u >> 16) & 1u);          // RNE
  return (unsigned short)(u >> 16);
}
__device__ __forceinline__ float bf2f(unsigned short h){
  return __uint_as_float(((unsigned int)h) << 16);
}
__device__ __forceinline__ void gl_lds16(const unsigned short* g, unsigned short* l){
  __builtin_amdgcn_global_load_lds(
      (const __attribute__((address_space(1))) unsigned int*)(const void*)g,
      (__attribute__((address_space(3))) unsigned int*)(void*)l, 16, 0, 0);
}

// ---------------- fp32 -> bf16 convert (flat) ----------------
__global__ void cvt_k(const float4* __restrict__ src, ushort4* __restrict__ dst, int n4){
  int i = blockIdx.x*256 + threadIdx.x;
  if (i < n4){
    float4 v = src[i];
    ushort4 o; o.x = f2bf(v.x); o.y = f2bf(v.y); o.z = f2bf(v.z); o.w = f2bf(v.w);
    dst[i] = o;
  }
}

// ------- fp32 (rows x cols slice) -> bf16 TRANSPOSED [ncPad][rows], zero-padded -------
__global__ __launch_bounds__(256) void cvt_t_k(const float* __restrict__ src,
    unsigned short* __restrict__ dst, int rows, int ldsrc, int c0, int nc){
  __shared__ float tile[32][33];
  const int tx = threadIdx.x & 31, ty = threadIdx.x >> 5;   // ty 0..7
  const int colBase = blockIdx.x*32;
  #pragma unroll
  for (int i = 0; i < 4; ++i){
    int rr = blockIdx.y*32 + ty + i*8;
    int cc = colBase + tx;
    tile[ty + i*8][tx] = (cc < nc) ? src[(size_t)rr*ldsrc + c0 + cc] : 0.f;
  }
  __syncthreads();
  #pragma unroll
  for (int i = 0; i < 4; ++i){
    int n = colBase + ty + i*8;          // < ncPad by grid
    int k = blockIdx.y*32 + tx;
    dst[(size_t)n*rows + k] = f2bf(tile[tx][ty + i*8]);
  }
}

// ---------------- pack up to 3 biases into [nslots][2304] (zero pad) ----------------
__global__ void pack3_k(float* __restrict__ dst, const float* __restrict__ b0,
    const float* __restrict__ b1, const float* __restrict__ b2, int nslots){
  int i = blockIdx.x*256 + threadIdx.x;
  if (i >= nslots*2304) return;
  int slot = i / 2304, d = i - slot*2304;
  const float* src = (slot == 0) ? b0 : ((slot == 1) ? b1 : b2);
  dst[i] = (d < 2240) ? src[d] : 0.f;
}

// ---------------- mods = scale_shift_table + timestep ----------------
__global__ void mods_k(const float* __restrict__ sst, const float* __restrict__ ts, float* __restrict__ mods){
  int i = blockIdx.x*256 + threadIdx.x;
  if (i < 6*DIMC) mods[i] = sst[i] + ts[i];
}

// ---------------- LayerNorm * (1+sc) + sh -> bf16 ----------------
__global__ __launch_bounds__(256) void ln_mod_k(const float* __restrict__ x,
    const float* __restrict__ mods, int shj, int scj, unsigned short* __restrict__ out)
{
  const int s = blockIdx.x;
  const float* row = x + (size_t)s*DIMC;
  const float* sh = mods + shj*DIMC;
  const float* sc = mods + scj*DIMC;
  float sum = 0.f, sq = 0.f;
  for (int d = threadIdx.x; d < DIMC; d += 256){ float v = row[d]; sum += v; sq += v*v; }
  #pragma unroll
  for (int o = 32; o; o >>= 1){ sum += __shfl_down(sum, o); sq += __shfl_down(sq, o); }
  __shared__ float sA[4], sB[4];
  int w = threadIdx.x >> 6, l = threadIdx.x & 63;
  if (!l){ sA[w] = sum; sB[w] = sq; }
  __syncthreads();
  sum = sA[0]+sA[1]+sA[2]+sA[3];
  sq  = sB[0]+sB[1]+sB[2]+sB[3];
  float mean = sum * (1.f/DIMC);
  float rs = rsqrtf(sq*(1.f/DIMC) - mean*mean + 1e-6f);
  unsigned short* orow = out + (size_t)s*DIMC;
  for (int d = threadIdx.x; d < DIMC; d += 256){
    float v = (row[d]-mean)*rs*(1.f + sc[d]) + sh[d];
    orow[d] = f2bf(v);
  }
}

// ---------------- RMS on bf16 rows (optional ReLU / RoPE) ----------------
template<int RELU, int ROPE>
__global__ __launch_bounds__(256) void rms_bf_k(unsigned short* __restrict__ x, const float* __restrict__ nw,
    const float* __restrict__ cosb, const float* __restrict__ sinb, unsigned short* __restrict__ xr)
{
  const int s = blockIdx.x;
  unsigned short* row = x + (size_t)s*DIMC;
  float sq = 0.f;
  for (int d = threadIdx.x; d < DIMC; d += 256){ float v = bf2f(row[d]); sq += v*v; }
  #pragma unroll
  for (int o = 32; o; o >>= 1) sq += __shfl_down(sq, o);
  __shared__ float sB[4];
  int w = threadIdx.x >> 6, l = threadIdx.x & 63;
  if (!l) sB[w] = sq;
  __syncthreads();
  sq = sB[0]+sB[1]+sB[2]+sB[3];
  float rs = rsqrtf(sq*(1.f/DIMC) + 1e-5f);
  if constexpr (!ROPE){
    for (int d = threadIdx.x; d < DIMC; d += 256){
      float v = bf2f(row[d])*rs*nw[d];
      if (RELU) v = fmaxf(v, 0.f);
      row[d] = f2bf(v);
    }
  } else {
    for (int p = threadIdx.x; p < DIMC/2; p += 256){
      int d0 = 2*p, d1 = d0+1;
      float v0 = bf2f(row[d0])*rs*nw[d0];
      float v1 = bf2f(row[d1])*rs*nw[d1];
      if (RELU){ v0 = fmaxf(v0,0.f); v1 = fmaxf(v1,0.f); }
      row[d0] = f2bf(v0); row[d1] = f2bf(v1);
      int j0 = d0 % HDIM;                       // pairs stay within a head (112 even)
      float c  = cosb[(size_t)s*HDIM + j0];     // cos[0::2]
      float sn = sinb[(size_t)s*HDIM + j0 + 1]; // sin[1::2]
      xr[(size_t)s*DIMC + d0] = f2bf(v0*c - v1*sn);
      xr[(size_t)s*DIMC + d1] = f2bf(v0*sn + v1*c);
    }
  }
}

// ------- bf16 MFMA GEMM: C = A(MxK) @ Bt^T, Bt is [Npad][K] (N-major), BK=64 ---------
// Both-sides swizzle (rule #21): staging pre-swizzles GLOBAL source chunk, LDS linear,
// ds_read applies matching XOR. K % 64 == 0 required. PW must divide gridDim.x.
// EPI: 0 Cf=acc+bias | 1 Cb=bf16(silu(acc+bias)) | 2 Cb=bf16(acc+bias)
//      3 u=res+gate*(acc+bias); Cf=u; Cb=bf16(u) | 4 Cf=res+acc+bias | 5 Cf+=acc
//      6 slot-split: slot=col/2304, d=col%2304; if d<2240: Cb[slot*ldc + row*2240 + d]
template<int EPI>
__global__ __launch_bounds__(256) void gemm_bt(
  const unsigned short* __restrict__ A, const unsigned short* __restrict__ Bt,
  const float* __restrict__ bias, float* __restrict__ Cf, unsigned short* __restrict__ Cb,
  const float* __restrict__ res, const float* __restrict__ gate,
  int M, int N, int K, int ldc, int PW)
{
  __shared__ __align__(16) unsigned short Al[128*64];
  __shared__ __align__(16) unsigned short Bl[128*64];
  const int gx = gridDim.x, gy = gridDim.y;
  const int nwg = gx*gy;
  const int orig = blockIdx.y*gx + blockIdx.x;
  // bijective XCD-aware remap (m204)
  const int qq = nwg >> 3, rr = nwg & 7;
  const int xcd = orig & 7, li = orig >> 3;
  const int wg = (xcd < rr ? xcd*(qq+1) : rr*(qq+1) + (xcd-rr)*qq) + li;
  // N-panel rasterization: panel of PW n-tiles covers all gy m-rows before advancing
  const int ppw = gy*PW;
  const int panel = wg / ppw, rm = wg - panel*ppw;
  const int mrow = rm / PW;
  const int m0 = mrow*128;
  const int n0 = (panel*PW + (rm - mrow*PW))*128;

  const int t = threadIdx.x, lane = t & 63, w = t >> 6;
  const int wr = w >> 1, wc = w & 1;
  const int l16 = lane & 15, lk = lane >> 4;

  // staging: per wave 4 A-chunks + 4 B-chunks (each 1KB = 8 rows x 128B), swizzled src
  const int lr8 = lane >> 3;           // row within 8-row block (== row&7)
  const int sc  = (lane & 7) ^ lr8;    // pre-swizzled source chunk
  const unsigned short* Aps[4];
  const unsigned short* Bps[4];
  #pragma unroll
  for (int i = 0; i < 4; ++i){
    int ar = m0 + w*32 + i*8 + lr8;
    int br = n0 + w*32 + i*8 + lr8;
    Aps[i] = A  + (size_t)min(ar, M-1)*K + sc*8;
    Bps[i] = Bt + (size_t)br*K + sc*8;
  }
  unsigned short* Ad = Al + w*2048;
  unsigned short* Bd = Bl + w*2048;

  f32x4 acc[4][4] = {};
  for (int k0 = 0; k0 < K; k0 += 64){
    __syncthreads();
    #pragma unroll
    for (int i = 0; i < 4; ++i){
      gl_lds16(Aps[i] + k0, Ad + i*512);
      gl_lds16(Bps[i] + k0, Bd + i*512);
    }
    __syncthreads();
    #pragma unroll
    for (int kk = 0; kk < 2; ++kk){
      bf16x8 af[4], bfr[4];
      const int chb = (kk*4 + lk) ^ (l16 & 7);   // swizzled read chunk
      #pragma unroll
      for (int m = 0; m < 4; ++m)
        af[m] = *reinterpret_cast<const bf16x8*>(Al + (wr*64 + m*16 + l16)*64 + chb*8);
      #pragma unroll
      for (int n = 0; n < 4; ++n)
        bfr[n] = *reinterpret_cast<const bf16x8*>(Bl + (wc*64 + n*16 + l16)*64 + chb*8);
      #pragma unroll
      for (int m = 0; m < 4; ++m)
        #pragma unroll
        for (int n = 0; n < 4; ++n)
          acc[m][n] = __builtin_amdgcn_mfma_f32_16x16x32_bf16(af[m], bfr[n], acc[m][n], 0, 0, 0);
    }
  }

  const int rb = m0 + wr*64 + lk*4;   // C/D: col = lane&15, row = (lane>>4)*4 + reg
  const int cb = n0 + wc*64 + l16;
  #pragma unroll
  for (int m = 0; m < 4; ++m){
    #pragma unroll
    for (int r = 0; r < 4; ++r){
      int row = rb + m*16 + r;
      if (row >= M) continue;
      #pragma unroll
      for (int n = 0; n < 4; ++n){
        int col = cb + n*16;
        if (col >= N) continue;
        float v = acc[m][n][r];
        float bv = bias ? bias[col] : 0.f;
        if constexpr (EPI == 6){
          int slot = col / 2304;
          int d = col - slot*2304;
          if (d < 2240)
            Cb[(size_t)slot*ldc + (size_t)row*2240 + d] = f2bf(v + bv);
        } else {
          size_t idx = (size_t)row*ldc + col;
          if constexpr (EPI == 0){ Cf[idx] = v + bv; }
          else if constexpr (EPI == 1){ float u = v + bv; Cb[idx] = f2bf(u / (1.f + __expf(-u))); }
          else if constexpr (EPI == 2){ Cb[idx] = f2bf(v + bv); }
          else if constexpr (EPI == 3){ float u = res[idx] + gate[col]*(v + bv); Cf[idx] = u; Cb[idx] = f2bf(u); }
          else if constexpr (EPI == 4){ Cf[idx] = res[idx] + v + bv; }
          else { Cf[idx] += v; }
        }
      }
    }
  }
}

// ---------------- linear attention helpers ----------------
__global__ void colsum_k(const unsigned short* __restrict__ k, float* __restrict__ kpart){
  int d = blockIdx.x*256 + threadIdx.x;
  if (d >= DIMC) return;
  int ch = blockIdx.y, s0 = ch*128;
  float acc = 0.f;
  for (int s = s0; s < s0+128; ++s) acc += bf2f(k[(size_t)s*DIMC + d]);
  kpart[(size_t)ch*DIMC + d] = acc;
}
__global__ void ksumred_k(const float* __restrict__ kpart, float* __restrict__ ksum){
  int d = blockIdx.x*256 + threadIdx.x;
  if (d >= DIMC) return;
  float a = 0.f;
  for (int c = 0; c < 28; ++c) a += kpart[(size_t)c*DIMC + d];
  ksum[d] = a;
}
__global__ __launch_bounds__(256) void denom_k(const unsigned short* __restrict__ q,
    const float* __restrict__ ksum, float* __restrict__ denom)
{
  int s = blockIdx.x; int w = threadIdx.x >> 6, l = threadIdx.x & 63;
  for (int h = w; h < NH; h += 4){
    const unsigned short* qb = q + (size_t)s*DIMC + h*HDIM;
    const float* kb = ksum + h*HDIM;
    float v = bf2f(qb[l])*kb[l];
    if (l < 48) v += bf2f(qb[64+l])*kb[64+l];
    #pragma unroll
    for (int o = 32; o; o >>= 1) v += __shfl_down(v, o);
    if (!l) denom[s*NH + h] = v + 1e-15f;
  }
}

// -------- MFMA scores: part[ch][h][e][d] = sum_{s in 128-chunk} V[s,h,e]*Kr[s,h,d] -----
#define SLSC 136
__device__ __forceinline__ int sc_idx(int e, int s){
  return e*SLSC + (s ^ (((e >> 3) & 7) << 3));
}
__global__ __launch_bounds__(256) void scores_k(const unsigned short* __restrict__ v,
    const unsigned short* __restrict__ kr, float* __restrict__ part)
{
  const int h = blockIdx.x, ch = blockIdx.y;
  __shared__ __align__(16) unsigned short Vt[112*SLSC];
  __shared__ __align__(16) unsigned short Kt[112*SLSC];
  const int t = threadIdx.x, lane = t & 63, w = t >> 6;
  const int l16 = lane & 15, lk = lane >> 4;
  const int sbase = ch*128;

  for (int p = t; p < 1792; p += 256){       // 128 tokens x 14 dim-octets
    int s = p / 14, oc = (p % 14) * 8;
    bf16x8 vv = *reinterpret_cast<const bf16x8*>(v  + (size_t)(sbase+s)*DIMC + h*HDIM + oc);
    bf16x8 kk = *reinterpret_cast<const bf16x8*>(kr + (size_t)(sbase+s)*DIMC + h*HDIM + oc);
    #pragma unroll
    for (int j = 0; j < 8; ++j){
      Vt[sc_idx(oc+j, s)] = (unsigned short)vv[j];
      Kt[sc_idx(oc+j, s)] = (unsigned short)kk[j];
    }
  }
  __syncthreads();

  f32x4 acc[2][7] = {};                      // wave w owns m-tiles {w, w+4}
  #pragma unroll
  for (int ks = 0; ks < 4; ++ks){
    const int sf = ks*32 + lk*8;
    bf16x8 bfrg[7];
    #pragma unroll
    for (int nt = 0; nt < 7; ++nt){
      int d = nt*16 + l16;
      bfrg[nt] = *reinterpret_cast<const bf16x8*>(&Kt[d*SLSC + (sf ^ (((d >> 3) & 7) << 3))]);
    }
    #pragma unroll
    for (int mi = 0; mi < 2; ++mi){
      int mt = w + mi*4;
      if (mt < 7){
        int e = mt*16 + l16;
        bf16x8 afrg = *reinterpret_cast<const bf16x8*>(&Vt[e*SLSC + (sf ^ (((e >> 3) & 7) << 3))]);
        #pragma unroll
        for (int nt = 0; nt < 7; ++nt)
          acc[mi][nt] = __builtin_amdgcn_mfma_f32_16x16x32_bf16(afrg, bfrg[nt], acc[mi][nt], 0, 0, 0);
      }
    }
  }

  float* pout = part + ((size_t)ch*NH + h)*12544;
  #pragma unroll
  for (int mi = 0; mi < 2; ++mi){
    int mt = w + mi*4;
    if (mt >= 7) continue;
    #pragma unroll
    for (int nt = 0; nt < 7; ++nt)
      #pragma unroll
      for (int r = 0; r < 4; ++r)
        pout[(size_t)(mt*16 + lk*4 + r)*HDIM + nt*16 + l16] = acc[mi][nt][r];
  }
}
__global__ void scred_k(const float* __restrict__ part, unsigned short* __restrict__ sc){
  int i = blockIdx.x*256 + threadIdx.x;
  if (i >= NH*HDIM*HDIM) return;
  float a = 0.f;
  #pragma unroll
  for (int c = 0; c < 28; ++c) a += part[(size_t)c*(NH*HDIM*HDIM) + i];
  sc[i] = f2bf(a);
}

// -------- MFMA linout: out[s,h*112+e] = (sum_d scores[h,e,d]*qr[s,h,d]) / denom[s,h] ---
__global__ __launch_bounds__(256) void linout_k(const unsigned short* __restrict__ qr,
    const unsigned short* __restrict__ scores, const float* __restrict__ denom,
    unsigned short* __restrict__ out)
{
  const int h = blockIdx.y;
  const int t = threadIdx.x, lane = t & 63, w = t >> 6;
  const int l16 = lane & 15, lk = lane >> 4;
  const int s0 = blockIdx.x*64 + w*16;
  const unsigned short* qrow = qr + (size_t)(s0 + l16)*DIMC + h*HDIM;
  const unsigned short* sb = scores + (size_t)h*12544;
  f32x4 acc[7] = {};
  #pragma unroll
  for (int ks = 0; ks < 4; ++ks){
    int d0 = ks*32 + lk*8;
    bf16x8 a = {};
    if (d0 < HDIM) a = *reinterpret_cast<const bf16x8*>(qrow + d0);
    #pragma unroll
    for (int nt = 0; nt < 7; ++nt){
      bf16x8 b = {};
      if (d0 < HDIM) b = *reinterpret_cast<const bf16x8*>(sb + (size_t)(nt*16 + l16)*HDIM + d0);
      acc[nt] = __builtin_amdgcn_mfma_f32_16x16x32_bf16(a, b, acc[nt], 0, 0, 0);
    }
  }
  #pragma unroll
  for (int r = 0; r < 4; ++r){
    int s = s0 + lk*4 + r;
    float dn = 1.f / denom[(size_t)s*NH + h];
    #pragma unroll
    for (int nt = 0; nt < 7; ++nt)
      out[(size_t)s*DIMC + h*HDIM + nt*16 + l16] = f2bf(acc[nt][r]*dn);
  }
}

// ---------------- fused cross-attention, MFMA (300 keys, head dim 112 padded to 128) ----
__global__ __launch_bounds__(256) void xattn_k(
    const unsigned short* __restrict__ q,   // S x DIM bf16 (rms-normed)
    const unsigned short* __restrict__ k2,  // ENCT x DIM bf16 (rms-normed)
    const unsigned short* __restrict__ v2,  // ENCT x DIM bf16
    unsigned short* __restrict__ outb)      // S x DIM bf16
{
  const int h = blockIdx.y;
  const int w = threadIdx.x >> 6, lane = threadIdx.x & 63;
  const int l16 = lane & 15, lk = lane >> 4;
  const float scale = 0.09449111825230679f;   // 1/sqrt(112)

  __shared__ __align__(16) unsigned short Kl[64][136];
  __shared__ __align__(16) unsigned short Vl[112][72];
  __shared__ __align__(16) unsigned short Pl[4][16][72];

  bf16x8 qf[4];
  const unsigned short* qbase = q + (size_t)(blockIdx.x*64 + w*16 + l16)*DIMC + h*HDIM;
  #pragma unroll
  for (int c = 0; c < 4; ++c){
    int d0 = c*32 + lk*8;
    bf16x8 z = {};
    qf[c] = (d0 < HDIM) ? *reinterpret_cast<const bf16x8*>(qbase + d0) : z;
  }

  f32x4 lg[5][4] = {};
  #pragma unroll
  for (int c = 0; c < 5; ++c){
    const int kbase = c*64;
    const int nk = (c == 4) ? (ENCT - 256) : 64;
    __syncthreads();
    #pragma unroll
    for (int it = 0; it < 4; ++it){
      int li = it*256 + threadIdx.x;
      int key = li >> 4, d0 = (li & 15) << 3;
      uint4 val = make_uint4(0u,0u,0u,0u);
      if (key < nk && d0 < HDIM)
        val = *reinterpret_cast<const uint4*>(k2 + (size_t)(kbase+key)*DIMC + h*HDIM + d0);
      *reinterpret_cast<uint4*>(&Kl[key][d0]) = val;
    }
    __syncthreads();
    #pragma unroll
    for (int nt = 0; nt < 4; ++nt){
      #pragma unroll
      for (int ks = 0; ks < 4; ++ks){
        bf16x8 kf = *reinterpret_cast<const bf16x8*>(&Kl[nt*16 + l16][ks*32 + lk*8]);
        lg[c][nt] = __builtin_amdgcn_mfma_f32_16x16x32_bf16(qf[ks], kf, lg[c][nt], 0, 0, 0);
      }
    }
  }

  float mx[4] = {-3e38f, -3e38f, -3e38f, -3e38f};
  #pragma unroll
  for (int c = 0; c < 5; ++c)
    #pragma unroll
    for (int nt = 0; nt < 4; ++nt){
      bool valid = (c*64 + nt*16 + l16) < ENCT;
      #pragma unroll
      for (int r = 0; r < 4; ++r){
        float v = valid ? lg[c][nt][r]*scale : -3e38f;
        lg[c][nt][r] = v;
        mx[r] = fmaxf(mx[r], v);
      }
    }
  #pragma unroll
  for (int o = 1; o < 16; o <<= 1)
    #pragma unroll
    for (int r = 0; r < 4; ++r) mx[r] = fmaxf(mx[r], __shfl_xor(mx[r], o));
  float sm[4] = {0.f, 0.f, 0.f, 0.f};
  #pragma unroll
  for (int c = 0; c < 5; ++c)
    #pragma unroll
    for (int nt = 0; nt < 4; ++nt)
      #pragma unroll
      for (int r = 0; r < 4; ++r){
        float e = __expf(lg[c][nt][r] - mx[r]);
        lg[c][nt][r] = e;
        sm[r] += e;
      }
  #pragma unroll
  for (int o = 1; o < 16; o <<= 1)
    #pragma unroll
    for (int r = 0; r < 4; ++r) sm[r] += __shfl_xor(sm[r], o);
  float inv[4];
  #pragma unroll
  for (int r = 0; r < 4; ++r) inv[r] = 1.f / sm[r];

  f32x4 oacc[7] = {};
  #pragma unroll
  for (int c = 0; c < 5; ++c){
    const int kbase = c*64;
    const int nk = (c == 4) ? (ENCT - 256) : 64;
    __syncthreads();
    #pragma unroll
    for (int it = 0; it < 4; ++it){
      int li = it*256 + threadIdx.x;
      if (li < 896){
        int key = li/14, d0 = (li%14)*8;
        if (key < nk){
          bf16x8 vv = *reinterpret_cast<const bf16x8*>(v2 + (size_t)(kbase+key)*DIMC + h*HDIM + d0);
          #pragma unroll
          for (int j = 0; j < 8; ++j) Vl[d0+j][key] = (unsigned short)vv[j];
        } else {
          #pragma unroll
          for (int j = 0; j < 8; ++j) Vl[d0+j][key] = 0;
        }
      }
    }
    #pragma unroll
    for (int nt = 0; nt < 4; ++nt)
      #pragma unroll
      for (int r = 0; r < 4; ++r)
        Pl[w][lk*4 + r][nt*16 + l16] = f2bf(lg[c][nt][r]);
    __syncthreads();
    #pragma unroll
    for (int ks = 0; ks < 2; ++ks){
      bf16x8 pf = *reinterpret_cast<const bf16x8*>(&Pl[w][l16][ks*32 + lk*8]);
      #pragma unroll
      for (int n = 0; n < 7; ++n){
        bf16x8 vf = *reinterpret_cast<const bf16x8*>(&Vl[n*16 + l16][ks*32 + lk*8]);
        oacc[n] = __builtin_amdgcn_mfma_f32_16x16x32_bf16(pf, vf, oacc[n], 0, 0, 0);
      }
    }
  }

  const int orow = blockIdx.x*64 + w*16 + lk*4;
  #pragma unroll
  for (int n = 0; n < 7; ++n)
    #pragma unroll
    for (int r = 0; r < 4; ++r)
      outb[(size_t)(orow + r)*DIMC + h*HDIM + n*16 + l16] = f2bf(oacc[n][r]*inv[r]);
}

// ------- depthwise 3x3 + bias + GLU(silu): 2 channels x 4 vertical outputs/thread -----
__global__ __launch_bounds__(256) void dw_k(const unsigned short* __restrict__ y1,
    const float* __restrict__ dw, const float* __restrict__ db, unsigned short* __restrict__ y2)
{
  int c = (blockIdx.y*256 + threadIdx.x)*2;
  if (c >= HID1) return;
  int bx = blockIdx.x;
  int ww = bx % 28;
  int yt = (bx / 28) & 3;
  int f  = bx / 112;
  int y0 = yt*4;

  float wa[9][2], wg[9][2];
  #pragma unroll
  for (int tp = 0; tp < 9; ++tp){
    float2 va = *reinterpret_cast<const float2*>(dw + tp*HID2 + c);
    float2 vg = *reinterpret_cast<const float2*>(dw + tp*HID2 + c + HID1);
    wa[tp][0] = va.x; wa[tp][1] = va.y;
    wg[tp][0] = vg.x; wg[tp][1] = vg.y;
  }
  float2 ba = *reinterpret_cast<const float2*>(db + c);
  float2 bg = *reinterpret_cast<const float2*>(db + c + HID1);
  float a0[4], a1[4], g0[4], g1[4];
  #pragma unroll
  for (int r = 0; r < 4; ++r){ a0[r] = ba.x; a1[r] = ba.y; g0[r] = bg.x; g1[r] = bg.y; }

  #pragma unroll
  for (int dy6 = 0; dy6 < 6; ++dy6){
    int y = y0 - 1 + dy6;
    if ((unsigned)y >= 16u) continue;
    #pragma unroll
    for (int dx = 0; dx < 3; ++dx){
      int x = ww + dx - 1;
      if ((unsigned)x >= 28u) continue;
      size_t base = ((size_t)(f*16 + y)*28 + x)*HID2;
      unsigned int a01 = *reinterpret_cast<const unsigned int*>(y1 + base + c);
      unsigned int g01 = *reinterpret_cast<const unsigned int*>(y1 + base + c + HID1);
      float fa0 = bf2f((unsigned short)(a01 & 0xffffu));
      float fa1 = bf2f((unsigned short)(a01 >> 16));
      float fg0 = bf2f((unsigned short)(g01 & 0xffffu));
      float fg1 = bf2f((unsigned short)(g01 >> 16));
      #pragma unroll
      for (int r = 0; r < 4; ++r){
        int kdy = dy6 - r;                    // compile-time after unroll
        if (kdy < 0 || kdy > 2) continue;
        int tp = kdy*3 + dx;
        a0[r] += fa0*wa[tp][0]; a1[r] += fa1*wa[tp][1];
        g0[r] += fg0*wg[tp][0]; g1[r] += fg1*wg[tp][1];
      }
    }
  }
  #pragma unroll
  for (int r = 0; r < 4; ++r){
    float s0 = g0[r] / (1.f + __expf(-g0[r]));
    float s1 = g1[r] / (1.f + __expf(-g1[r]));
    int pos = (f*16 + y0 + r)*28 + ww;
    unsigned int o = (unsigned int)f2bf(a0[r]*s0) | ((unsigned int)f2bf(a1[r]*s1) << 16);
    *reinterpret_cast<unsigned int*>(y2 + (size_t)pos*HID1 + c) = o;
  }
}

// ---------------- final: out = x2 + g_mlp*(y3 + tc) ----------------
__global__ void final_k(const float* __restrict__ x2, const unsigned short* __restrict__ y3,
    const float* __restrict__ tc, const float* __restrict__ mods, float* __restrict__ out)
{
  int i = blockIdx.x*256 + threadIdx.x;
  if (i >= SD) return;
  int d = i % DIMC;
  out[i] = x2[i] + mods[5*DIMC + d]*(bf2f(y3[i]) + tc[i]);
}

extern "C" void kernel_launch(void* const* d_in, const int* in_sizes, int n_in,
                              void* d_out, int out_size, void* d_ws, size_t ws_size,
                              hipStream_t stream)
{
  const float* hid   = (const float*)d_in[0];
  const float* enc   = (const float*)d_in[1];
  const float* tstep = (const float*)d_in[2];
  const float* fcos  = (const float*)d_in[3];
  const float* fsin  = (const float*)d_in[4];
  const float* sst   = (const float*)d_in[5];
  const float *a1_qw=(const float*)d_in[6],  *a1_qb=(const float*)d_in[7];
  const float *a1_kw=(const float*)d_in[8],  *a1_kb=(const float*)d_in[9];
  const float *a1_vw=(const float*)d_in[10], *a1_vb=(const float*)d_in[11];
  const float *a1_nq=(const float*)d_in[12], *a1_nk=(const float*)d_in[13];
  const float *a1_ow=(const float*)d_in[14], *a1_ob=(const float*)d_in[15];
  const float *a2_qw=(const float*)d_in[16], *a2_qb=(const float*)d_in[17];
  const float *a2_kw=(const float*)d_in[18], *a2_kb=(const float*)d_in[19];
  const float *a2_vw=(const float*)d_in[20], *a2_vb=(const float*)d_in[21];
  const float *a2_nq=(const float*)d_in[22], *a2_nk=(const float*)d_in[23];
  const float *a2_ow=(const float*)d_in[24], *a2_ob=(const float*)d_in[25];
  const float *ff_inv_w=(const float*)d_in[26], *ff_inv_b=(const float*)d_in[27];
  const float *ff_dw=(const float*)d_in[28], *ff_db=(const float*)d_in[29];
  const float *ff_pw=(const float*)d_in[30];
  const float *ff_tw=(const float*)d_in[31];
  float* out = (float*)d_out;

  // ---- workspace plan (~213 MB total; all sizes 256-multiple) ----
  const size_t SLOTB = (size_t)SD*2;        // 16,056,320 B  (one bf16 S x DIM slot)
  char* ws = (char*)d_ws;
  size_t off = 0;
  auto alloc = [&](size_t n){ void* p = ws + off; off += (n + 255) & ~(size_t)255; return p; };

  char* P = (char*)alloc(6*SLOTB);          // 6 bf16 activation slots (96.3 MB)
  float* x1    = (float*)alloc((size_t)SD*4);     // fp32 residual (32.1 MB)
  unsigned short* nh2b = (unsigned short*)alloc(SLOTB); // MUST follow x1 (y2b spans both)
  float* x2    = (float*)alloc((size_t)SD*4);
  unsigned short* k2b = (unsigned short*)alloc((size_t)ENCT*DIMC*2);  // k2b+v2b contiguous
  unsigned short* v2b = (unsigned short*)alloc((size_t)ENCT*DIMC*2);
  unsigned short* encb = (unsigned short*)alloc((size_t)ENCT*DIMC*2);
  float* modsb = (float*)alloc(6*DIMC*4);
  float* ksum  = (float*)alloc(DIMC*4);
  float* kpart = (float*)alloc((size_t)28*DIMC*4);
  float* denom = (float*)alloc((size_t)STOK*NH*4);
  unsigned short* scorb = (unsigned short*)alloc((size_t)NH*HDIM*HDIM*2);
  float* bias3 = (float*)alloc(3*2304*4);
  unsigned short* Wbig = (unsigned short*)alloc((size_t)6912*DIMC*2);  // 31 MB weight staging

  // P-slot aliases (lifetimes verified disjoint)
  unsigned short* P0 = (unsigned short*)P;                 // nhb | y1b[0:] | y3b
  unsigned short* P1 = (unsigned short*)(P + 1*SLOTB);     // qb | spart | lob | y1b | tc[0:]
  unsigned short* P2 = (unsigned short*)(P + 2*SLOTB);     // kb | spart | x1b | y1b | tc[1:]
  unsigned short* P3 = (unsigned short*)(P + 3*SLOTB);     // vb | q2b | y1b
  unsigned short* P4 = (unsigned short*)(P + 4*SLOTB);     // qrb | crb | y1b
  unsigned short* P5 = (unsigned short*)(P + 5*SLOTB);     // krb | y1b
  unsigned short* nhb = P0;
  unsigned short* y1b = P0;                                // 96.34 MB = slots 0..5 exactly
  unsigned short* y2b = (unsigned short*)x1;               // 48.17 MB = x1 + nh2b exactly
  unsigned short* y3b = P0;
  float* tc = (float*)(P + 1*SLOTB);                       // 32.1 MB = slots 1..2
  float* spart = (float*)P1;   // 28 x NH x 112 x 112 fp32 = 28.1 MB, q/k dead by then

  auto cvt = [&](const float* s, unsigned short* d, size_t n){
    int n4 = (int)(n/4);
    cvt_k<<<dim3((n4+255)/256), 256, 0, stream>>>((const float4*)s, (ushort4*)d, n4);
  };
  auto cvtT = [&](const float* s, unsigned short* d, int rows, int ldsrc, int c0, int nc, int ncPad){
    cvt_t_k<<<dim3(ncPad/32, rows/32), 256, 0, stream>>>(s, d, rows, ldsrc, c0, nc);
  };
  auto gemm_grid = [&](int M, int Npad){ return dim3(Npad/128, (M+127)/128); };

  mods_k<<<dim3((6*DIMC+255)/256), 256, 0, stream>>>(sst, tstep, modsb);
  cvt(enc, encb, (size_t)ENCT*DIMC);

  // ---- attn1: fused QKV ----
  ln_mod_k<<<dim3(STOK), 256, 0, stream>>>(hid, modsb, 0, 1, nhb);
  pack3_k<<<dim3((3*2304+255)/256), 256, 0, stream>>>(bias3, a1_qb, a1_kb, a1_vb, 3);
  cvtT(a1_qw, Wbig + (size_t)0*2304*DIMC, DIMC, DIMC, 0, DIMC, 2304);
  cvtT(a1_kw, Wbig + (size_t)1*2304*DIMC, DIMC, DIMC, 0, DIMC, 2304);
  cvtT(a1_vw, Wbig + (size_t)2*2304*DIMC, DIMC, DIMC, 0, DIMC, 2304);
  gemm_bt<6><<<gemm_grid(STOK, 6912), 256, 0, stream>>>(nhb, Wbig, bias3, nullptr, P1,
                                                        nullptr, nullptr, STOK, 6912, DIMC, SD, 6);
  rms_bf_k<1,1><<<dim3(STOK), 256, 0, stream>>>(P1, a1_nq, fcos, fsin, P4);
  rms_bf_k<1,1><<<dim3(STOK), 256, 0, stream>>>(P2, a1_nk, fcos, fsin, P5);
  colsum_k<<<dim3(9, 28), 256, 0, stream>>>(P2, kpart);
  ksumred_k<<<dim3(9), 256, 0, stream>>>(kpart, ksum);
  denom_k<<<dim3(STOK), 256, 0, stream>>>(P1, ksum, denom);
  // q (P1) and k (P2) are dead now -> spart may overwrite them
  scores_k<<<dim3(NH, 28), 256, 0, stream>>>(P3, P5, spart);
  scred_k<<<dim3((NH*HDIM*HDIM+255)/256), 256, 0, stream>>>(spart, scorb);
  linout_k<<<dim3(STOK/64, NH), 256, 0, stream>>>(P4, scorb, denom, P1);   // lob -> P1
  dim3 gMN = gemm_grid(STOK, 2304);
  cvtT(a1_ow, Wbig, DIMC, DIMC, 0, DIMC, 2304);
  gemm_bt<3><<<gMN, 256, 0, stream>>>(P1, Wbig, a1_ob, x1, P2, hid, modsb + 2*DIMC, STOK, DIMC, DIMC, DIMC, 6);

  // ---- cross attn ----
  cvtT(a2_qw, Wbig, DIMC, DIMC, 0, DIMC, 2304);
  gemm_bt<2><<<gMN, 256, 0, stream>>>(P2, Wbig, a2_qb, nullptr, P3, nullptr, nullptr, STOK, DIMC, DIMC, DIMC, 6);
  pack3_k<<<dim3((2*2304+255)/256), 256, 0, stream>>>(bias3, a2_kb, a2_vb, a2_vb, 2);
  cvtT(a2_kw, Wbig + (size_t)0*2304*DIMC, DIMC, DIMC, 0, DIMC, 2304);
  cvtT(a2_vw, Wbig + (size_t)1*2304*DIMC, DIMC, DIMC, 0, DIMC, 2304);
  gemm_bt<6><<<gemm_grid(ENCT, 4608), 256, 0, stream>>>(encb, Wbig, bias3, nullptr, k2b,
                                                        nullptr, nullptr, ENCT, 4608, DIMC, ENCT*DIMC, 6);
  rms_bf_k<0,0><<<dim3(STOK), 256, 0, stream>>>(P3, a2_nq, nullptr, nullptr, nullptr);
  rms_bf_k<0,0><<<dim3(ENCT), 256, 0, stream>>>(k2b, a2_nk, nullptr, nullptr, nullptr);
  xattn_k<<<dim3(STOK/64, NH), 256, 0, stream>>>(P3, k2b, v2b, P4);   // crb -> P4
  cvtT(a2_ow, Wbig, DIMC, DIMC, 0, DIMC, 2304);
  gemm_bt<4><<<gMN, 256, 0, stream>>>(P4, Wbig, a2_ob, x2, nullptr, x1, nullptr, STOK, DIMC, DIMC, DIMC, 6);

  // ---- FF ----
  ln_mod_k<<<dim3(STOK), 256, 0, stream>>>(x2, modsb, 3, 4, nh2b);
  for (int q = 0; q < 2; ++q){                 // ff_inv in 2 column slices of 6720
    int c0 = q*6720;
    cvtT(ff_inv_w, Wbig, DIMC, HID2, c0, 6720, 6912);
    gemm_bt<1><<<gemm_grid(STOK, 6912), 256, 0, stream>>>(nh2b, Wbig, ff_inv_b + c0, nullptr, y1b + c0,
                                                          nullptr, nullptr, STOK, 6720, DIMC, HID2, 6);
  }
  dw_k<<<dim3(896, 14), 256, 0, stream>>>(y1b, ff_dw, ff_db, y2b);
  cvtT(ff_pw, Wbig, HID1, DIMC, 0, DIMC, 2304);   // point conv in one GEMM (K=6720)
  gemm_bt<2><<<gMN, 256, 0, stream>>>(y2b, Wbig, nullptr, nullptr, y3b,
                                      nullptr, nullptr, STOK, DIMC, HID1, DIMC, 2);
  // temporal conv: tc = y3 @ W1 (center) then shifted accumulates
  cvtT(ff_tw + (size_t)DD, Wbig, DIMC, DIMC, 0, DIMC, 2304);
  gemm_bt<0><<<gMN, 256, 0, stream>>>(y3b, Wbig, nullptr, tc, nullptr, nullptr, nullptr, STOK, DIMC, DIMC, DIMC, 6);
  dim3 gT = gemm_grid(3136, 2304);
  cvtT(ff_tw, Wbig, DIMC, DIMC, 0, DIMC, 2304);
  gemm_bt<5><<<gT, 256, 0, stream>>>(y3b, Wbig, nullptr, tc + (size_t)448*DIMC, nullptr, nullptr, nullptr, 3136, DIMC, DIMC, DIMC, 6);
  cvtT(ff_tw + (size_t)2*DD, Wbig, DIMC, DIMC, 0, DIMC, 2304);
  gemm_bt<5><<<gT, 256, 0, stream>>>(y3b + (size_t)448*DIMC, Wbig, nullptr, tc, nullptr, nullptr, nullptr, 3136, DIMC, DIMC, DIMC, 6);

  // out = x2 + g_mlp*(y3 + tc)
  final_k<<<dim3((SD+255)/256), 256, 0, stream>>>(x2, y3b, tc, modsb, out);
}